// Round 11
// baseline (2110.528 us; speedup 1.0000x reference)
//
#include <hip/hip_runtime.h>
#include <hip/hip_bf16.h>

// B=8, N=2048, D=1024, C=1024, H=512 (fp32 in/out)
//  q = LNReLU(sgm@Wq^T+bq); k = LNReLU(velo@Wk^T+bk)
//  S = q k^T; P = softmax(S); v1 = LNReLU(velo@Wv1^T); v2 = LNReLU(sgm@Wv2^T)
//  out = concat(v2, P@v1)
//
// Round 11: identical to rounds 8/9/10 (all died on infra:
// UnresponsiveContainer, same wedged pod; source never ran).
// Round-8 deltas over the proven round-6 kernel (938us, absmax 0.03125):
//  (1) normalize fused into PV slab 3 (EPI=3: (c+acc)/l) — saves a 32 MiB RMW
//  (2) occupancy 4->5 blocks/CU (LDS 32KB x 5 = 160KiB exactly; VGPR 64)

#define BB 8
#define NN 2048
#define DD 1024
#define CC_ 1024
#define HH 512
#define RR (BB*NN)   // 16384 rows

typedef unsigned short ush;
typedef short bf16x8 __attribute__((ext_vector_type(8)));
typedef float f32x4  __attribute__((ext_vector_type(4)));

#define MiB (1024L*1024L)

// ---------- helpers ----------
__device__ __forceinline__ ush f2bf_rne(float x) {
    unsigned u = __float_as_uint(x);
    return (ush)((u + 0x7fffu + ((u >> 16) & 1u)) >> 16);
}
__device__ __forceinline__ float bf2f(ush h) {
    return __uint_as_float((unsigned)h << 16);
}
__device__ __forceinline__ float wave_sum(float v) {
    #pragma unroll
    for (int o = 32; o; o >>= 1) v += __shfl_down(v, o);
    return v;
}
__device__ __forceinline__ float wave_max(float v) {
    #pragma unroll
    for (int o = 32; o; o >>= 1) v = fmaxf(v, __shfl_down(v, o));
    return v;
}

// LDS tile [128 rows][32 bf16] = 64 B/row. Swizzle XORs byte bits 4..5 with
// (row>>1)&3 (involution; preserves 16B chunks).
__device__ __forceinline__ int swzb(int row, int kbyte) {
    return ((row << 6) | kbyte) ^ (((row >> 1) & 3) << 4);
}

// async global->LDS, 16B/lane. LDS dest wave-uniform base + lane*16;
// global src per-lane (pre-swizzled so linear LDS holds swizzled layout).
__device__ __forceinline__ void glds16(const void* g, void* l) {
    __builtin_amdgcn_global_load_lds(
        (const __attribute__((address_space(1))) unsigned*)g,
        (__attribute__((address_space(3))) unsigned*)l, 16, 0, 0);
}

// ---------- split-bf16 MFMA GEMM ----------
// C[M,N] = A[M,K] @ B[N,K]^T. Tile 128x128, BK=32, 4 waves -> 64x64 each.
// AM=1: A pre-split hi/lo, 3 passes (ah*bh, ah*bl, al*bh).
// AM=2: A single bf16,    2 passes (a*bh, a*bl).        B always hi/lo.
// EPI=0: store C fp32. EPI=1: p=exp(s-m), store P bf16 + atomicAdd l.
// EPI=2: C += acc. EPI=3: C = (C + acc) * (1/l)  [fused final normalize].
template<int AM, int EPI>
__global__ __launch_bounds__(256, 5)
void gemm3_kernel(const ush* __restrict__ A0, const ush* __restrict__ A1,
                  const ush* __restrict__ B0, const ush* __restrict__ B1,
                  float* __restrict__ C, ush* __restrict__ Pout,
                  float* __restrict__ ml,
                  int K, int lda, int ldb, int ldc,
                  long sAz, long sBz, long sCz, long sPz)
{
    __shared__ alignas(16) ush aHi[128*32];
    __shared__ alignas(16) ush aLo[128*32];
    __shared__ alignas(16) ush bHi[128*32];
    __shared__ alignas(16) ush bLo[128*32];

    // XCD-aware bijective swizzle (all grids here are multiples of 8):
    // blocks sharing an A-panel land on the same XCD L2.
    long wg  = (long)blockIdx.x +
               (long)gridDim.x * ((long)blockIdx.y + (long)gridDim.y * blockIdx.z);
    long nwg = (long)gridDim.x * gridDim.y * gridDim.z;
    long swz = (wg & 7) * (nwg >> 3) + (wg >> 3);
    const int bx = (int)(swz % gridDim.x);
    long rem = swz / gridDim.x;
    const int by = (int)(rem % gridDim.y);
    const long bz = rem / gridDim.y;

    const long mbase = (long)by << 7;
    const long nbase = (long)bx << 7;
    const int  t    = threadIdx.x;
    const int  wave = t >> 6, lane = t & 63;
    const int  wr = (wave >> 1) << 6;
    const int  wc = (wave & 1)  << 6;
    const int  fr = lane & 15;
    const int  kg = lane >> 4;

    const ush* Ah = A0 + bz * sAz;
    const ush* Bh = B0 + bz * sBz;
    const ush* Bl = B1 + bz * sBz;

    f32x4 acc[4][4] = {};

    for (int k0 = 0; k0 < K; k0 += 32) {
        #pragma unroll
        for (int i = 0; i < 2; ++i) {
            int rl = (wave << 5) + (i << 4) + (lane >> 2);
            int cs = ((lane & 3) ^ ((rl >> 1) & 3)) << 3;
            long goA = (mbase + rl) * (long)lda + k0 + cs;
            long goB = (nbase + rl) * (long)ldb + k0 + cs;
            glds16(Ah + goA, &aHi[(wave << 10) + (i << 9)]);
            if constexpr (AM == 1) {
                const ush* Al_ = A1 + bz * sAz;
                glds16(Al_ + goA, &aLo[(wave << 10) + (i << 9)]);
            }
            glds16(Bh + goB, &bHi[(wave << 10) + (i << 9)]);
            glds16(Bl + goB, &bLo[(wave << 10) + (i << 9)]);
        }
        __syncthreads();

        bf16x8 ah[4], al[4], bh[4], bl[4];
        #pragma unroll
        for (int i = 0; i < 4; ++i) {
            int ra = wr + (i << 4) + fr, rb = wc + (i << 4) + fr;
            ah[i] = *(const bf16x8*)(aHi + (swzb(ra, kg << 4) >> 1));
            if constexpr (AM == 1)
                al[i] = *(const bf16x8*)(aLo + (swzb(ra, kg << 4) >> 1));
            bh[i] = *(const bf16x8*)(bHi + (swzb(rb, kg << 4) >> 1));
            bl[i] = *(const bf16x8*)(bLo + (swzb(rb, kg << 4) >> 1));
        }
        #pragma unroll
        for (int i = 0; i < 4; ++i) {
            #pragma unroll
            for (int j = 0; j < 4; ++j) {
                acc[i][j] = __builtin_amdgcn_mfma_f32_16x16x32_bf16(ah[i], bh[j], acc[i][j], 0, 0, 0);
                acc[i][j] = __builtin_amdgcn_mfma_f32_16x16x32_bf16(ah[i], bl[j], acc[i][j], 0, 0, 0);
                if constexpr (AM == 1)
                    acc[i][j] = __builtin_amdgcn_mfma_f32_16x16x32_bf16(al[i], bh[j], acc[i][j], 0, 0, 0);
            }
        }
        __syncthreads();
    }

    // C/D layout (m89): col = lane&15, row = (lane>>4)*4 + reg
    if constexpr (EPI == 1) {
        ush*   Pb  = Pout + bz * sPz;
        float* mlb = ml + bz * 2048L * 1024;
        #pragma unroll
        for (int i = 0; i < 4; ++i) {
            #pragma unroll
            for (int q = 0; q < 4; ++q) {
                long grow = mbase + wr + (i << 4) + (kg << 2) + q;   // row in batch
                float m = mlb[grow * 1024];
                float rs = 0.f;
                #pragma unroll
                for (int j = 0; j < 4; ++j) {
                    float p = __expf(acc[i][j][q] - m);
                    rs += p;
                    Pb[grow * 512 + nbase + wc + (j << 4) + fr] = f2bf_rne(p);
                }
                rs += __shfl_xor(rs, 1); rs += __shfl_xor(rs, 2);
                rs += __shfl_xor(rs, 4); rs += __shfl_xor(rs, 8);
                if (fr == 0) atomicAdd(&mlb[grow * 1024 + 1], rs);
            }
        }
    } else {
        float* Cb = C + bz * sCz;
        #pragma unroll
        for (int i = 0; i < 4; ++i) {
            #pragma unroll
            for (int q = 0; q < 4; ++q) {
                long grow = mbase + wr + (i << 4) + (kg << 2) + q;
                float scale = 1.0f;
                if constexpr (EPI == 3)
                    scale = 1.0f / (ml + bz * 2048L * 1024)[grow * 1024 + 1];
                float* crow = Cb + grow * (long)ldc + nbase + wc + fr;
                #pragma unroll
                for (int j = 0; j < 4; ++j) {
                    if constexpr (EPI == 2)      crow[j << 4] = crow[j << 4] + acc[i][j][q];
                    else if constexpr (EPI == 3) crow[j << 4] = (crow[j << 4] + acc[i][j][q]) * scale;
                    else                         crow[j << 4] = acc[i][j][q];
                }
            }
        }
    }
}

// ---------- bias + LayerNorm + ReLU; optional hi/lo bf16 output ----------
template<int NC, bool HILO>
__global__ void ln_relu_kernel(const float* __restrict__ Y, int ldy,
                               const float* __restrict__ bias,
                               const float* __restrict__ g, const float* __restrict__ beta,
                               float* __restrict__ outf, ush* __restrict__ oh,
                               ush* __restrict__ ol, int ldo)
{
    constexpr int PER = NC / 256;
    long row = blockIdx.x;
    const float* yr = Y + row * (long)ldy;
    int t = threadIdx.x;
    float v[PER]; float s = 0.f, s2 = 0.f;
    #pragma unroll
    for (int i = 0; i < PER; ++i) {
        int c = t + (i << 8);
        float x = yr[c] + bias[c];
        v[i] = x; s += x; s2 += x * x;
    }
    s = wave_sum(s); s2 = wave_sum(s2);
    __shared__ float ra[4], rb[4];
    int w = t >> 6, l = t & 63;
    if (!l) { ra[w] = s; rb[w] = s2; }
    __syncthreads();
    s  = ra[0] + ra[1] + ra[2] + ra[3];
    s2 = rb[0] + rb[1] + rb[2] + rb[3];
    float mu  = s * (1.0f / NC);
    float var = s2 * (1.0f / NC) - mu * mu;
    float inv = rsqrtf(var + 1e-5f);
    #pragma unroll
    for (int i = 0; i < PER; ++i) {
        int c = t + (i << 8);
        float x = (v[i] - mu) * inv * g[c] + beta[c];
        x = fmaxf(x, 0.0f);
        if constexpr (HILO) {
            ush h = f2bf_rne(x);
            ush lo = f2bf_rne(x - __uint_as_float((unsigned)h << 16));
            oh[row * (long)ldo + c] = h;
            ol[row * (long)ldo + c] = lo;
        } else {
            outf[row * (long)ldo + c] = x;
        }
    }
}

// ---------- fp32 -> hi/lo bf16 split (flat) ----------
__global__ void split_kernel(const float* __restrict__ in, ush* __restrict__ h,
                             ush* __restrict__ l, long n)
{
    long i = ((long)blockIdx.x * 256 + threadIdx.x) * 4;
    if (i >= n) return;
    float4 v = *(const float4*)(in + i);
    ushort4 hh, ll;
    hh.x = f2bf_rne(v.x); ll.x = f2bf_rne(v.x - __uint_as_float((unsigned)hh.x << 16));
    hh.y = f2bf_rne(v.y); ll.y = f2bf_rne(v.y - __uint_as_float((unsigned)hh.y << 16));
    hh.z = f2bf_rne(v.z); ll.z = f2bf_rne(v.z - __uint_as_float((unsigned)hh.z << 16));
    hh.w = f2bf_rne(v.w); ll.w = f2bf_rne(v.w - __uint_as_float((unsigned)hh.w << 16));
    *(ushort4*)(h + i) = hh;
    *(ushort4*)(l + i) = ll;
}

// ---------- per-batch transpose [2048,512] -> [512,2048], hi/lo split ----------
__global__ void transpose_split_kernel(const float* __restrict__ in,
                                       ush* __restrict__ oh, ush* __restrict__ ol)
{
    __shared__ float tile[32][33];
    long bz = blockIdx.z;
    const float* I = in + bz * (long)NN * HH;
    ush* OH = oh + bz * (long)HH * NN;
    ush* OL = ol + bz * (long)HH * NN;
    int c0 = blockIdx.x << 5, r0 = blockIdx.y << 5;
    int tx = threadIdx.x & 31, ty = threadIdx.x >> 5;   // 32 x 8
    #pragma unroll
    for (int i = 0; i < 32; i += 8)
        tile[ty + i][tx] = I[(long)(r0 + ty + i) * HH + c0 + tx];
    __syncthreads();
    #pragma unroll
    for (int i = 0; i < 32; i += 8) {
        float x = tile[tx][ty + i];
        ush h = f2bf_rne(x);
        ush lo = f2bf_rne(x - __uint_as_float((unsigned)h << 16));
        long o = (long)(c0 + ty + i) * NN + r0 + tx;
        OH[o] = h; OL[o] = lo;
    }
}

// ---------- exp pass over slab-0 scores ----------
// S fp32 at ml[row*1024 + 0..511]; computes m=rowmax, P=exp(S-m) bf16,
// l=rowsum; stores m,l at ml[row*1024 + 0/1] (after S consumed).
__global__ void exp_pass_kernel(float* __restrict__ ml, ush* __restrict__ P)
{
    long row = blockIdx.x;               // 0..16383
    float* sr = ml + row * 1024;
    int t = threadIdx.x;
    float s0 = sr[t], s1 = sr[t + 256];
    float m = fmaxf(s0, s1);
    m = wave_max(m);
    __shared__ float ra[4], rb[4];
    int w = t >> 6, l = t & 63;
    if (!l) ra[w] = m;
    __syncthreads();
    m = fmaxf(fmaxf(ra[0], ra[1]), fmaxf(ra[2], ra[3]));
    float p0 = __expf(s0 - m), p1 = __expf(s1 - m);
    ush h0 = f2bf_rne(p0), h1 = f2bf_rne(p1);
    P[row * 512 + t] = h0;
    P[row * 512 + t + 256] = h1;
    float ls = bf2f(h0) + bf2f(h1);      // sum what PV will actually use
    ls = wave_sum(ls);
    if (!l) rb[w] = ls;
    __syncthreads();
    if (t == 0) {
        sr[0] = m;
        sr[1] = rb[0] + rb[1] + rb[2] + rb[3];
    }
}

// ---------- launch ----------
extern "C" void kernel_launch(void* const* d_in, const int* in_sizes, int n_in,
                              void* d_out, int out_size, void* d_ws, size_t ws_size,
                              hipStream_t stream)
{
    const float* sgm   = (const float*)d_in[0];
    const float* velo  = (const float*)d_in[1];
    const float* Wq    = (const float*)d_in[2];
    const float* bq    = (const float*)d_in[3];
    const float* gq    = (const float*)d_in[4];
    const float* betaq = (const float*)d_in[5];
    const float* Wk    = (const float*)d_in[6];
    const float* bk    = (const float*)d_in[7];
    const float* gk    = (const float*)d_in[8];
    const float* betak = (const float*)d_in[9];
    const float* Wv1   = (const float*)d_in[10];
    const float* bv1   = (const float*)d_in[11];
    const float* gv1   = (const float*)d_in[12];
    const float* betav1= (const float*)d_in[13];
    const float* Wv2   = (const float*)d_in[14];
    const float* bv2   = (const float*)d_in[15];
    const float* gv2   = (const float*)d_in[16];
    const float* betav2= (const float*)d_in[17];
    float* out = (float*)d_out;
    char*  wsb = (char*)d_ws;

    if (ws_size < 176 * MiB) return;   // proven >= 176 MiB in round 3

    // ws byte layout:
    // [0..64)    x hi/lo (velo, then sgm) -> then q hi/lo -> then x(sgm)
    // [64..128)  k hi/lo
    // [128..160) v1t hi/lo
    // [160..176) weight splits (12 MiB) -> P slab (16 MiB) -> Wv2 split
    ush* xh   = (ush*)wsb;
    ush* xl   = (ush*)(wsb + 32 * MiB);
    ush* kh   = (ush*)(wsb + 64 * MiB);
    ush* kl   = (ush*)(wsb + 96 * MiB);
    ush* v1th = (ush*)(wsb + 128 * MiB);
    ush* v1tl = (ush*)(wsb + 144 * MiB);
    ush* Wqh  = (ush*)(wsb + 160 * MiB);
    ush* Wql  = (ush*)(wsb + 162 * MiB);
    ush* Wkh  = (ush*)(wsb + 164 * MiB);
    ush* Wkl  = (ush*)(wsb + 166 * MiB);
    ush* Wv1h = (ush*)(wsb + 168 * MiB);
    ush* Wv1l = (ush*)(wsb + 169 * MiB);
    ush* P    = (ush*)(wsb + 160 * MiB);
    float* v1f = out + 8388608L;       // out bytes [32..64) MiB

    dim3 blk(256);

    // weight splits (Wv2 later; its region becomes P during attention)
    split_kernel<<<1024, blk, 0, stream>>>(Wq,  Wqh,  Wql,  (long)CC_*DD);
    split_kernel<<<1024, blk, 0, stream>>>(Wk,  Wkh,  Wkl,  (long)CC_*DD);
    split_kernel<<<512,  blk, 0, stream>>>(Wv1, Wv1h, Wv1l, (long)HH*DD);

    // --- velo-derived: k, v1 ---
    split_kernel<<<16384, blk, 0, stream>>>(velo, xh, xl, (long)RR*DD);
    gemm3_kernel<1,0><<<dim3(8,128,1), blk, 0, stream>>>(
        xh, xl, Wkh, Wkl, out, nullptr, nullptr, DD, DD, DD, CC_, 0, 0, 0, 0);
    ln_relu_kernel<1024,true><<<RR, blk, 0, stream>>>(out, CC_, bk, gk, betak, nullptr, kh, kl, CC_);
    gemm3_kernel<1,0><<<dim3(4,128,1), blk, 0, stream>>>(
        xh, xl, Wv1h, Wv1l, out, nullptr, nullptr, DD, DD, DD, HH, 0, 0, 0, 0);
    ln_relu_kernel<512,false><<<RR, blk, 0, stream>>>(out, HH, bv1, gv1, betav1, v1f, nullptr, nullptr, HH);
    transpose_split_kernel<<<dim3(16,64,BB), blk, 0, stream>>>(v1f, v1th, v1tl);

    // --- sgm-derived: q (x region reused; q overwrites x after Yq) ---
    split_kernel<<<16384, blk, 0, stream>>>(sgm, xh, xl, (long)RR*DD);
    gemm3_kernel<1,0><<<dim3(8,128,1), blk, 0, stream>>>(
        xh, xl, Wqh, Wql, out, nullptr, nullptr, DD, DD, DD, CC_, 0, 0, 0, 0);
    ln_relu_kernel<1024,true><<<RR, blk, 0, stream>>>(out, CC_, bq, gq, betaq, nullptr, xh, xl, CC_);

    // --- attention (4 key-slabs of 512) ---
    // slab 0: raw S fp32 -> out[:, 0:512]; exp_pass derives m, P, l
    gemm3_kernel<1,0><<<dim3(4,16,8), blk, 0, stream>>>(
        xh, xl, kh, kl, out, nullptr, nullptr,
        CC_, CC_, CC_, 1024, 2048L*1024, 2048L*1024, 2048L*1024, 0);
    exp_pass_kernel<<<RR, blk, 0, stream>>>(out, P);
    gemm3_kernel<2,0><<<dim3(4,16,8), blk, 0, stream>>>(
        P, nullptr, v1th, v1tl, out + HH, nullptr, nullptr,
        512, 512, NN, CC_, 2048L*512, 512L*2048, 2048L*1024, 0);
    for (int s = 1; s < 4; ++s) {
        gemm3_kernel<1,1><<<dim3(4,16,8), blk, 0, stream>>>(
            xh, xl, kh + (long)s*512*1024, kl + (long)s*512*1024,
            nullptr, P, out, CC_, CC_, CC_, 0,
            2048L*1024, 2048L*1024, 0, 2048L*512);
        if (s < 3)
            gemm3_kernel<2,2><<<dim3(4,16,8), blk, 0, stream>>>(
                P, nullptr, v1th + s*512, v1tl + s*512,
                out + HH, nullptr, nullptr, 512, 512, NN, CC_,
                2048L*512, 512L*2048, 2048L*1024, 0);
        else
            gemm3_kernel<2,3><<<dim3(4,16,8), blk, 0, stream>>>(
                P, nullptr, v1th + s*512, v1tl + s*512,
                out + HH, nullptr, out, 512, 512, NN, CC_,
                2048L*512, 512L*2048, 2048L*1024, 0);
    }

    // --- v2 last (out[:, :512] free now; q and P regions dead) ---
    split_kernel<<<16384, blk, 0, stream>>>(sgm, xh, xl, (long)RR*DD);
    ush* Wv2h = (ush*)(wsb + 160 * MiB);
    ush* Wv2l = (ush*)(wsb + 161 * MiB);
    split_kernel<<<512, blk, 0, stream>>>(Wv2, Wv2h, Wv2l, (long)HH*DD);
    gemm3_kernel<1,0><<<dim3(4,128,1), blk, 0, stream>>>(
        xh, xl, Wv2h, Wv2l, out, nullptr, nullptr, DD, DD, DD, CC_, 0, 0, 0, 0);
    ln_relu_kernel<512,false><<<RR, blk, 0, stream>>>(out, CC_, bv2, gv2, betav2, out, nullptr, nullptr, CC_);
}

// Round 15
// 926.131 us; speedup vs baseline: 2.2789x; 2.2789x over previous
//
#include <hip/hip_runtime.h>
#include <hip/hip_bf16.h>

// B=8, N=2048, D=1024, C=1024, H=512 (fp32 in/out)
//  q = LNReLU(sgm@Wq^T+bq); k = LNReLU(velo@Wk^T+bk)
//  S = q k^T; P = softmax(S); v1 = LNReLU(velo@Wv1^T); v2 = LNReLU(sgm@Wv2^T)
//  out = concat(v2, P@v1)
//
// Round 15: identical to rounds 12/13/14 (all died on infra:
// UnresponsiveContainer, same flapping pod; source never ran).
// Round-12 delta vs round 11: __launch_bounds__ back to (256,4) — (256,5)
// capped VGPR at 48 (<64 needed for acc[4][4]) -> accumulator scratch spills
// -> 1.5GB HBM/dispatch, 2110us. Keeps EPI=3 fused normalize.

#define BB 8
#define NN 2048
#define DD 1024
#define CC_ 1024
#define HH 512
#define RR (BB*NN)   // 16384 rows

typedef unsigned short ush;
typedef short bf16x8 __attribute__((ext_vector_type(8)));
typedef float f32x4  __attribute__((ext_vector_type(4)));

#define MiB (1024L*1024L)

// ---------- helpers ----------
__device__ __forceinline__ ush f2bf_rne(float x) {
    unsigned u = __float_as_uint(x);
    return (ush)((u + 0x7fffu + ((u >> 16) & 1u)) >> 16);
}
__device__ __forceinline__ float bf2f(ush h) {
    return __uint_as_float((unsigned)h << 16);
}
__device__ __forceinline__ float wave_sum(float v) {
    #pragma unroll
    for (int o = 32; o; o >>= 1) v += __shfl_down(v, o);
    return v;
}
__device__ __forceinline__ float wave_max(float v) {
    #pragma unroll
    for (int o = 32; o; o >>= 1) v = fmaxf(v, __shfl_down(v, o));
    return v;
}

// LDS tile [128 rows][32 bf16] = 64 B/row. Swizzle XORs byte bits 4..5 with
// (row>>1)&3 (involution; preserves 16B chunks).
__device__ __forceinline__ int swzb(int row, int kbyte) {
    return ((row << 6) | kbyte) ^ (((row >> 1) & 3) << 4);
}

// async global->LDS, 16B/lane. LDS dest wave-uniform base + lane*16;
// global src per-lane (pre-swizzled so linear LDS holds swizzled layout).
__device__ __forceinline__ void glds16(const void* g, void* l) {
    __builtin_amdgcn_global_load_lds(
        (const __attribute__((address_space(1))) unsigned*)g,
        (__attribute__((address_space(3))) unsigned*)l, 16, 0, 0);
}

// ---------- split-bf16 MFMA GEMM ----------
// C[M,N] = A[M,K] @ B[N,K]^T. Tile 128x128, BK=32, 4 waves -> 64x64 each.
// AM=1: A pre-split hi/lo, 3 passes (ah*bh, ah*bl, al*bh).
// AM=2: A single bf16,    2 passes (a*bh, a*bl).        B always hi/lo.
// EPI=0: store C fp32. EPI=1: p=exp(s-m), store P bf16 + atomicAdd l.
// EPI=2: C += acc. EPI=3: C = (C + acc) * (1/l)  [fused final normalize].
template<int AM, int EPI>
__global__ __launch_bounds__(256, 4)
void gemm3_kernel(const ush* __restrict__ A0, const ush* __restrict__ A1,
                  const ush* __restrict__ B0, const ush* __restrict__ B1,
                  float* __restrict__ C, ush* __restrict__ Pout,
                  float* __restrict__ ml,
                  int K, int lda, int ldb, int ldc,
                  long sAz, long sBz, long sCz, long sPz)
{
    __shared__ alignas(16) ush aHi[128*32];
    __shared__ alignas(16) ush aLo[128*32];
    __shared__ alignas(16) ush bHi[128*32];
    __shared__ alignas(16) ush bLo[128*32];

    // XCD-aware bijective swizzle (all grids here are multiples of 8):
    // blocks sharing an A-panel land on the same XCD L2.
    long wg  = (long)blockIdx.x +
               (long)gridDim.x * ((long)blockIdx.y + (long)gridDim.y * blockIdx.z);
    long nwg = (long)gridDim.x * gridDim.y * gridDim.z;
    long swz = (wg & 7) * (nwg >> 3) + (wg >> 3);
    const int bx = (int)(swz % gridDim.x);
    long rem = swz / gridDim.x;
    const int by = (int)(rem % gridDim.y);
    const long bz = rem / gridDim.y;

    const long mbase = (long)by << 7;
    const long nbase = (long)bx << 7;
    const int  t    = threadIdx.x;
    const int  wave = t >> 6, lane = t & 63;
    const int  wr = (wave >> 1) << 6;
    const int  wc = (wave & 1)  << 6;
    const int  fr = lane & 15;
    const int  kg = lane >> 4;

    const ush* Ah = A0 + bz * sAz;
    const ush* Bh = B0 + bz * sBz;
    const ush* Bl = B1 + bz * sBz;

    f32x4 acc[4][4] = {};

    for (int k0 = 0; k0 < K; k0 += 32) {
        #pragma unroll
        for (int i = 0; i < 2; ++i) {
            int rl = (wave << 5) + (i << 4) + (lane >> 2);
            int cs = ((lane & 3) ^ ((rl >> 1) & 3)) << 3;
            long goA = (mbase + rl) * (long)lda + k0 + cs;
            long goB = (nbase + rl) * (long)ldb + k0 + cs;
            glds16(Ah + goA, &aHi[(wave << 10) + (i << 9)]);
            if constexpr (AM == 1) {
                const ush* Al_ = A1 + bz * sAz;
                glds16(Al_ + goA, &aLo[(wave << 10) + (i << 9)]);
            }
            glds16(Bh + goB, &bHi[(wave << 10) + (i << 9)]);
            glds16(Bl + goB, &bLo[(wave << 10) + (i << 9)]);
        }
        __syncthreads();

        bf16x8 ah[4], al[4], bh[4], bl[4];
        #pragma unroll
        for (int i = 0; i < 4; ++i) {
            int ra = wr + (i << 4) + fr, rb = wc + (i << 4) + fr;
            ah[i] = *(const bf16x8*)(aHi + (swzb(ra, kg << 4) >> 1));
            if constexpr (AM == 1)
                al[i] = *(const bf16x8*)(aLo + (swzb(ra, kg << 4) >> 1));
            bh[i] = *(const bf16x8*)(bHi + (swzb(rb, kg << 4) >> 1));
            bl[i] = *(const bf16x8*)(bLo + (swzb(rb, kg << 4) >> 1));
        }
        #pragma unroll
        for (int i = 0; i < 4; ++i) {
            #pragma unroll
            for (int j = 0; j < 4; ++j) {
                acc[i][j] = __builtin_amdgcn_mfma_f32_16x16x32_bf16(ah[i], bh[j], acc[i][j], 0, 0, 0);
                acc[i][j] = __builtin_amdgcn_mfma_f32_16x16x32_bf16(ah[i], bl[j], acc[i][j], 0, 0, 0);
                if constexpr (AM == 1)
                    acc[i][j] = __builtin_amdgcn_mfma_f32_16x16x32_bf16(al[i], bh[j], acc[i][j], 0, 0, 0);
            }
        }
        __syncthreads();
    }

    // C/D layout (m89): col = lane&15, row = (lane>>4)*4 + reg
    if constexpr (EPI == 1) {
        ush*   Pb  = Pout + bz * sPz;
        float* mlb = ml + bz * 2048L * 1024;
        #pragma unroll
        for (int i = 0; i < 4; ++i) {
            #pragma unroll
            for (int q = 0; q < 4; ++q) {
                long grow = mbase + wr + (i << 4) + (kg << 2) + q;   // row in batch
                float m = mlb[grow * 1024];
                float rs = 0.f;
                #pragma unroll
                for (int j = 0; j < 4; ++j) {
                    float p = __expf(acc[i][j][q] - m);
                    rs += p;
                    Pb[grow * 512 + nbase + wc + (j << 4) + fr] = f2bf_rne(p);
                }
                rs += __shfl_xor(rs, 1); rs += __shfl_xor(rs, 2);
                rs += __shfl_xor(rs, 4); rs += __shfl_xor(rs, 8);
                if (fr == 0) atomicAdd(&mlb[grow * 1024 + 1], rs);
            }
        }
    } else {
        float* Cb = C + bz * sCz;
        #pragma unroll
        for (int i = 0; i < 4; ++i) {
            #pragma unroll
            for (int q = 0; q < 4; ++q) {
                long grow = mbase + wr + (i << 4) + (kg << 2) + q;
                float scale = 1.0f;
                if constexpr (EPI == 3)
                    scale = 1.0f / (ml + bz * 2048L * 1024)[grow * 1024 + 1];
                float* crow = Cb + grow * (long)ldc + nbase + wc + fr;
                #pragma unroll
                for (int j = 0; j < 4; ++j) {
                    if constexpr (EPI == 2)      crow[j << 4] = crow[j << 4] + acc[i][j][q];
                    else if constexpr (EPI == 3) crow[j << 4] = (crow[j << 4] + acc[i][j][q]) * scale;
                    else                         crow[j << 4] = acc[i][j][q];
                }
            }
        }
    }
}

// ---------- bias + LayerNorm + ReLU; optional hi/lo bf16 output ----------
template<int NC, bool HILO>
__global__ void ln_relu_kernel(const float* __restrict__ Y, int ldy,
                               const float* __restrict__ bias,
                               const float* __restrict__ g, const float* __restrict__ beta,
                               float* __restrict__ outf, ush* __restrict__ oh,
                               ush* __restrict__ ol, int ldo)
{
    constexpr int PER = NC / 256;
    long row = blockIdx.x;
    const float* yr = Y + row * (long)ldy;
    int t = threadIdx.x;
    float v[PER]; float s = 0.f, s2 = 0.f;
    #pragma unroll
    for (int i = 0; i < PER; ++i) {
        int c = t + (i << 8);
        float x = yr[c] + bias[c];
        v[i] = x; s += x; s2 += x * x;
    }
    s = wave_sum(s); s2 = wave_sum(s2);
    __shared__ float ra[4], rb[4];
    int w = t >> 6, l = t & 63;
    if (!l) { ra[w] = s; rb[w] = s2; }
    __syncthreads();
    s  = ra[0] + ra[1] + ra[2] + ra[3];
    s2 = rb[0] + rb[1] + rb[2] + rb[3];
    float mu  = s * (1.0f / NC);
    float var = s2 * (1.0f / NC) - mu * mu;
    float inv = rsqrtf(var + 1e-5f);
    #pragma unroll
    for (int i = 0; i < PER; ++i) {
        int c = t + (i << 8);
        float x = (v[i] - mu) * inv * g[c] + beta[c];
        x = fmaxf(x, 0.0f);
        if constexpr (HILO) {
            ush h = f2bf_rne(x);
            ush lo = f2bf_rne(x - __uint_as_float((unsigned)h << 16));
            oh[row * (long)ldo + c] = h;
            ol[row * (long)ldo + c] = lo;
        } else {
            outf[row * (long)ldo + c] = x;
        }
    }
}

// ---------- fp32 -> hi/lo bf16 split (flat) ----------
__global__ void split_kernel(const float* __restrict__ in, ush* __restrict__ h,
                             ush* __restrict__ l, long n)
{
    long i = ((long)blockIdx.x * 256 + threadIdx.x) * 4;
    if (i >= n) return;
    float4 v = *(const float4*)(in + i);
    ushort4 hh, ll;
    hh.x = f2bf_rne(v.x); ll.x = f2bf_rne(v.x - __uint_as_float((unsigned)hh.x << 16));
    hh.y = f2bf_rne(v.y); ll.y = f2bf_rne(v.y - __uint_as_float((unsigned)hh.y << 16));
    hh.z = f2bf_rne(v.z); ll.z = f2bf_rne(v.z - __uint_as_float((unsigned)hh.z << 16));
    hh.w = f2bf_rne(v.w); ll.w = f2bf_rne(v.w - __uint_as_float((unsigned)hh.w << 16));
    *(ushort4*)(h + i) = hh;
    *(ushort4*)(l + i) = ll;
}

// ---------- per-batch transpose [2048,512] -> [512,2048], hi/lo split ----------
__global__ void transpose_split_kernel(const float* __restrict__ in,
                                       ush* __restrict__ oh, ush* __restrict__ ol)
{
    __shared__ float tile[32][33];
    long bz = blockIdx.z;
    const float* I = in + bz * (long)NN * HH;
    ush* OH = oh + bz * (long)HH * NN;
    ush* OL = ol + bz * (long)HH * NN;
    int c0 = blockIdx.x << 5, r0 = blockIdx.y << 5;
    int tx = threadIdx.x & 31, ty = threadIdx.x >> 5;   // 32 x 8
    #pragma unroll
    for (int i = 0; i < 32; i += 8)
        tile[ty + i][tx] = I[(long)(r0 + ty + i) * HH + c0 + tx];
    __syncthreads();
    #pragma unroll
    for (int i = 0; i < 32; i += 8) {
        float x = tile[tx][ty + i];
        ush h = f2bf_rne(x);
        ush lo = f2bf_rne(x - __uint_as_float((unsigned)h << 16));
        long o = (long)(c0 + ty + i) * NN + r0 + tx;
        OH[o] = h; OL[o] = lo;
    }
}

// ---------- exp pass over slab-0 scores ----------
// S fp32 at ml[row*1024 + 0..511]; computes m=rowmax, P=exp(S-m) bf16,
// l=rowsum; stores m,l at ml[row*1024 + 0/1] (after S consumed).
__global__ void exp_pass_kernel(float* __restrict__ ml, ush* __restrict__ P)
{
    long row = blockIdx.x;               // 0..16383
    float* sr = ml + row * 1024;
    int t = threadIdx.x;
    float s0 = sr[t], s1 = sr[t + 256];
    float m = fmaxf(s0, s1);
    m = wave_max(m);
    __shared__ float ra[4], rb[4];
    int w = t >> 6, l = t & 63;
    if (!l) ra[w] = m;
    __syncthreads();
    m = fmaxf(fmaxf(ra[0], ra[1]), fmaxf(ra[2], ra[3]));
    float p0 = __expf(s0 - m), p1 = __expf(s1 - m);
    ush h0 = f2bf_rne(p0), h1 = f2bf_rne(p1);
    P[row * 512 + t] = h0;
    P[row * 512 + t + 256] = h1;
    float ls = bf2f(h0) + bf2f(h1);      // sum what PV will actually use
    ls = wave_sum(ls);
    if (!l) rb[w] = ls;
    __syncthreads();
    if (t == 0) {
        sr[0] = m;
        sr[1] = rb[0] + rb[1] + rb[2] + rb[3];
    }
}

// ---------- launch ----------
extern "C" void kernel_launch(void* const* d_in, const int* in_sizes, int n_in,
                              void* d_out, int out_size, void* d_ws, size_t ws_size,
                              hipStream_t stream)
{
    const float* sgm   = (const float*)d_in[0];
    const float* velo  = (const float*)d_in[1];
    const float* Wq    = (const float*)d_in[2];
    const float* bq    = (const float*)d_in[3];
    const float* gq    = (const float*)d_in[4];
    const float* betaq = (const float*)d_in[5];
    const float* Wk    = (const float*)d_in[6];
    const float* bk    = (const float*)d_in[7];
    const float* gk    = (const float*)d_in[8];
    const float* betak = (const float*)d_in[9];
    const float* Wv1   = (const float*)d_in[10];
    const float* bv1   = (const float*)d_in[11];
    const float* gv1   = (const float*)d_in[12];
    const float* betav1= (const float*)d_in[13];
    const float* Wv2   = (const float*)d_in[14];
    const float* bv2   = (const float*)d_in[15];
    const float* gv2   = (const float*)d_in[16];
    const float* betav2= (const float*)d_in[17];
    float* out = (float*)d_out;
    char*  wsb = (char*)d_ws;

    if (ws_size < 176 * MiB) return;   // proven >= 176 MiB in round 3

    // ws byte layout:
    // [0..64)    x hi/lo (velo, then sgm) -> then q hi/lo -> then x(sgm)
    // [64..128)  k hi/lo
    // [128..160) v1t hi/lo
    // [160..176) weight splits (12 MiB) -> P slab (16 MiB) -> Wv2 split
    ush* xh   = (ush*)wsb;
    ush* xl   = (ush*)(wsb + 32 * MiB);
    ush* kh   = (ush*)(wsb + 64 * MiB);
    ush* kl   = (ush*)(wsb + 96 * MiB);
    ush* v1th = (ush*)(wsb + 128 * MiB);
    ush* v1tl = (ush*)(wsb + 144 * MiB);
    ush* Wqh  = (ush*)(wsb + 160 * MiB);
    ush* Wql  = (ush*)(wsb + 162 * MiB);
    ush* Wkh  = (ush*)(wsb + 164 * MiB);
    ush* Wkl  = (ush*)(wsb + 166 * MiB);
    ush* Wv1h = (ush*)(wsb + 168 * MiB);
    ush* Wv1l = (ush*)(wsb + 169 * MiB);
    ush* P    = (ush*)(wsb + 160 * MiB);
    float* v1f = out + 8388608L;       // out bytes [32..64) MiB

    dim3 blk(256);

    // weight splits (Wv2 later; its region becomes P during attention)
    split_kernel<<<1024, blk, 0, stream>>>(Wq,  Wqh,  Wql,  (long)CC_*DD);
    split_kernel<<<1024, blk, 0, stream>>>(Wk,  Wkh,  Wkl,  (long)CC_*DD);
    split_kernel<<<512,  blk, 0, stream>>>(Wv1, Wv1h, Wv1l, (long)HH*DD);

    // --- velo-derived: k, v1 ---
    split_kernel<<<16384, blk, 0, stream>>>(velo, xh, xl, (long)RR*DD);
    gemm3_kernel<1,0><<<dim3(8,128,1), blk, 0, stream>>>(
        xh, xl, Wkh, Wkl, out, nullptr, nullptr, DD, DD, DD, CC_, 0, 0, 0, 0);
    ln_relu_kernel<1024,true><<<RR, blk, 0, stream>>>(out, CC_, bk, gk, betak, nullptr, kh, kl, CC_);
    gemm3_kernel<1,0><<<dim3(4,128,1), blk, 0, stream>>>(
        xh, xl, Wv1h, Wv1l, out, nullptr, nullptr, DD, DD, DD, HH, 0, 0, 0, 0);
    ln_relu_kernel<512,false><<<RR, blk, 0, stream>>>(out, HH, bv1, gv1, betav1, v1f, nullptr, nullptr, HH);
    transpose_split_kernel<<<dim3(16,64,BB), blk, 0, stream>>>(v1f, v1th, v1tl);

    // --- sgm-derived: q (x region reused; q overwrites x after Yq) ---
    split_kernel<<<16384, blk, 0, stream>>>(sgm, xh, xl, (long)RR*DD);
    gemm3_kernel<1,0><<<dim3(8,128,1), blk, 0, stream>>>(
        xh, xl, Wqh, Wql, out, nullptr, nullptr, DD, DD, DD, CC_, 0, 0, 0, 0);
    ln_relu_kernel<1024,true><<<RR, blk, 0, stream>>>(out, CC_, bq, gq, betaq, nullptr, xh, xl, CC_);

    // --- attention (4 key-slabs of 512) ---
    // slab 0: raw S fp32 -> out[:, 0:512]; exp_pass derives m, P, l
    gemm3_kernel<1,0><<<dim3(4,16,8), blk, 0, stream>>>(
        xh, xl, kh, kl, out, nullptr, nullptr,
        CC_, CC_, CC_, 1024, 2048L*1024, 2048L*1024, 2048L*1024, 0);
    exp_pass_kernel<<<RR, blk, 0, stream>>>(out, P);
    gemm3_kernel<2,0><<<dim3(4,16,8), blk, 0, stream>>>(
        P, nullptr, v1th, v1tl, out + HH, nullptr, nullptr,
        512, 512, NN, CC_, 2048L*512, 512L*2048, 2048L*1024, 0);
    for (int s = 1; s < 4; ++s) {
        gemm3_kernel<1,1><<<dim3(4,16,8), blk, 0, stream>>>(
            xh, xl, kh + (long)s*512*1024, kl + (long)s*512*1024,
            nullptr, P, out, CC_, CC_, CC_, 0,
            2048L*1024, 2048L*1024, 0, 2048L*512);
        if (s < 3)
            gemm3_kernel<2,2><<<dim3(4,16,8), blk, 0, stream>>>(
                P, nullptr, v1th + s*512, v1tl + s*512,
                out + HH, nullptr, nullptr, 512, 512, NN, CC_,
                2048L*512, 512L*2048, 2048L*1024, 0);
        else
            gemm3_kernel<2,3><<<dim3(4,16,8), blk, 0, stream>>>(
                P, nullptr, v1th + s*512, v1tl + s*512,
                out + HH, nullptr, out, 512, 512, NN, CC_,
                2048L*512, 512L*2048, 2048L*1024, 0);
    }

    // --- v2 last (out[:, :512] free now; q and P regions dead) ---
    split_kernel<<<16384, blk, 0, stream>>>(sgm, xh, xl, (long)RR*DD);
    ush* Wv2h = (ush*)(wsb + 160 * MiB);
    ush* Wv2l = (ush*)(wsb + 161 * MiB);
    split_kernel<<<512, blk, 0, stream>>>(Wv2, Wv2h, Wv2l, (long)HH*DD);
    gemm3_kernel<1,0><<<dim3(4,128,1), blk, 0, stream>>>(
        xh, xl, Wv2h, Wv2l, out, nullptr, nullptr, DD, DD, DD, CC_, 0, 0, 0, 0);
    ln_relu_kernel<512,false><<<RR, blk, 0, stream>>>(out, CC_, bv2, gv2, betav2, out, nullptr, nullptr, CC_);
}

// Round 16
// 894.384 us; speedup vs baseline: 2.3598x; 1.0355x over previous
//
#include <hip/hip_runtime.h>
#include <hip/hip_bf16.h>

// B=8, N=2048, D=1024, C=1024, H=512 (fp32 in/out)
//  q = LNReLU(sgm@Wq^T+bq); k = LNReLU(velo@Wk^T+bk)
//  S = q k^T; P = softmax(S); v1 = LNReLU(velo@Wv1^T); v2 = LNReLU(sgm@Wv2^T)
//  out = concat(v2, P@v1)
//
// Round 16: baseline re-established at 926us (absmax 0.03125). New: gemm8p —
// 8-phase 256x256 schedule (T2 subtiled st_16x32 LDS swizzle + T3/T4 counted
// vmcnt + T5 setprio) for the two N=1024 linears only. 3-pass split done as
// K'=3K source table (AhBh | AlBh | AhBl) -> exact same sum as gemm3<1,*>.
// All other kernels identical to round 15.

#define BB 8
#define NN 2048
#define DD 1024
#define CC_ 1024
#define HH 512
#define RR (BB*NN)   // 16384 rows

typedef unsigned short ush;
typedef short bf16x8 __attribute__((ext_vector_type(8)));
typedef float f32x4  __attribute__((ext_vector_type(4)));

#define MiB (1024L*1024L)

// ---------- helpers ----------
__device__ __forceinline__ ush f2bf_rne(float x) {
    unsigned u = __float_as_uint(x);
    return (ush)((u + 0x7fffu + ((u >> 16) & 1u)) >> 16);
}
__device__ __forceinline__ float bf2f(ush h) {
    return __uint_as_float((unsigned)h << 16);
}
__device__ __forceinline__ float wave_sum(float v) {
    #pragma unroll
    for (int o = 32; o; o >>= 1) v += __shfl_down(v, o);
    return v;
}
__device__ __forceinline__ float wave_max(float v) {
    #pragma unroll
    for (int o = 32; o; o >>= 1) v = fmaxf(v, __shfl_down(v, o));
    return v;
}

// LDS tile [128 rows][32 bf16] = 64 B/row (gemm3). Swizzle XORs byte bits 4..5
// with (row>>1)&3 (involution; preserves 16B chunks).
__device__ __forceinline__ int swzb(int row, int kbyte) {
    return ((row << 6) | kbyte) ^ (((row >> 1) & 3) << 4);
}

// async global->LDS, 16B/lane. LDS dest wave-uniform base + lane*16;
// global src per-lane (pre-swizzled so linear LDS holds swizzled layout).
__device__ __forceinline__ void glds16(const void* g, void* l) {
    __builtin_amdgcn_global_load_lds(
        (const __attribute__((address_space(1))) unsigned*)g,
        (__attribute__((address_space(3))) unsigned*)l, 16, 0, 0);
}

// ---------- 8-phase 256x256 bf16 GEMM (3-pass via K'=3K source table) ----------
// C[M,1024] = A[M,1024] @ B[1024,1024]^T with A,B pre-split hi/lo.
// kt 0-15: Ah*Bh, 16-31: Al*Bh, 32-47: Ah*Bl (== gemm3<1,*> 3-pass sum).
// Geometry: BM=BN=256, BK=64, 8 waves (2Mx4N), per-wave 128x64, LDS 128 KiB
// (2 buf x {A,B} x 2 half(128x64), subtiled 16x32 + bit5^bit9 swizzle).
// Ring: kt.p0 stages (kt+1).A0, p1: (kt+1).A1, p2: (kt+2).B0, p3: (kt+2).B1;
// vmcnt(4) at each p3 (2 half-tiles stay in flight; never 0 mid-loop).
__global__ __launch_bounds__(512, 2)
void gemm8p_kernel(const ush* __restrict__ Ah, const ush* __restrict__ Al,
                   const ush* __restrict__ Bh, const ush* __restrict__ Bl,
                   float* __restrict__ C, int ldc)
{
    __shared__ ush L[65536];   // 128 KiB
    constexpr int NT = 48;     // K' / 64

    int nwg = gridDim.x * gridDim.y;
    int wg  = blockIdx.x + gridDim.x * blockIdx.y;
    int sz  = (wg & 7) * (nwg >> 3) + (wg >> 3);
    int bx  = sz % gridDim.x, by = sz / gridDim.x;
    const long brow = (long)by << 8, bcol = (long)bx << 8;

    const int t = threadIdx.x, wid = t >> 6, lane = t & 63;
    const int wr = (wid >> 2) << 7;      // 0 / 128
    const int wc = (wid & 3) << 6;       // 0/64/128/192
    const int fr = lane & 15, kg = lane >> 4;

    // staging geometry: thread covers 16B of subtile s=(q*8+wid); element
    // (row = sr*16 + lane/4, col = sc*32 + ((lane%4)*8 ^ ((lane>=32)?16:0)))
    const int srow = ((wid >> 1) << 4) + (lane >> 2);
    const int scol = ((wid & 1) << 5) + ((((lane & 3) << 3)) ^ ((lane >> 5) << 4));
    const int sdst = wid << 9;           // + q*4096 + slot base (wave-uniform)

    // frag-read in-subtile term: fr*32 + (kg*8 ^ ((fr>=8)?16:0))
    const int cterm = (fr << 5) + ((kg << 3) ^ ((fr >> 3) << 4));
    const int ha13  = (wr >> 7) << 13;          // A half slot
    const int bbase = 16384 + ((wc >> 7) << 13);// B area + half slot
    const int sb0   = (wc & 64) >> 4;           // base subtile row in B half

    f32x4 acc[8][4] = {};
    bf16x8 bfrag[4][2];

    auto stage = [&](int X, int half) {   // half: 0=A0 1=A1 2=B0 3=B1
        if (X >= NT) return;
        int pI = X >> 4, kc = (X & 15) << 6;
        const ush* s; long rb;
        if (half < 2) { s = (pI == 1) ? Al : Ah; rb = brow + ((long)(half & 1) << 7); }
        else          { s = (pI == 2) ? Bl : Bh; rb = bcol + ((long)(half & 1) << 7); }
        int lb = ((X & 1) << 15) + ((half >> 1) << 14) + ((half & 1) << 13) + sdst;
        glds16(s + (rb + srow) * 1024 + kc + scol,      &L[lb]);
        glds16(s + (rb + srow + 64) * 1024 + kc + scol, &L[lb + 4096]);
    };

    // prologue: kt0 fully + kt1's B halves; leave 2 half-tiles in flight
    stage(0, 0); stage(0, 1); stage(0, 2); stage(0, 3);
    stage(1, 2); stage(1, 3);
    asm volatile("s_waitcnt vmcnt(4)");
    __builtin_amdgcn_sched_barrier(0);
    __builtin_amdgcn_s_barrier();

    for (int kt = 0; kt < NT; ++kt) {
        const int ab = (kt & 1) << 15;
        #pragma unroll
        for (int p = 0; p < 4; ++p) {
            bf16x8 afrag[2][2];
            #pragma unroll
            for (int ii = 0; ii < 2; ++ii)
                #pragma unroll
                for (int ks = 0; ks < 2; ++ks)
                    afrag[ii][ks] = *(const bf16x8*)&L[ab + ha13 +
                        ((((2 * p + ii) << 1) | ks) << 9) + cterm];
            if (p == 0) {
                #pragma unroll
                for (int fj = 0; fj < 4; ++fj)
                    #pragma unroll
                    for (int ks = 0; ks < 2; ++ks)
                        bfrag[fj][ks] = *(const bf16x8*)&L[ab + bbase +
                            ((((sb0 + fj) << 1) | ks) << 9) + cterm];
            }
            if      (p == 0) stage(kt + 1, 0);
            else if (p == 1) stage(kt + 1, 1);
            else if (p == 2) stage(kt + 2, 2);
            else             stage(kt + 2, 3);

            __builtin_amdgcn_s_barrier();
            asm volatile("s_waitcnt lgkmcnt(0)");
            __builtin_amdgcn_sched_barrier(0);
            __builtin_amdgcn_s_setprio(1);
            #pragma unroll
            for (int ii = 0; ii < 2; ++ii)
                #pragma unroll
                for (int fj = 0; fj < 4; ++fj)
                    #pragma unroll
                    for (int ks = 0; ks < 2; ++ks)
                        acc[2 * p + ii][fj] = __builtin_amdgcn_mfma_f32_16x16x32_bf16(
                            afrag[ii][ks], bfrag[fj][ks], acc[2 * p + ii][fj], 0, 0, 0);
            __builtin_amdgcn_s_setprio(0);
            if (p == 3) {
                if (kt < NT - 2) asm volatile("s_waitcnt vmcnt(4)");
                else             asm volatile("s_waitcnt vmcnt(0)");
                __builtin_amdgcn_sched_barrier(0);
            }
            __builtin_amdgcn_s_barrier();
        }
    }

    // C/D layout (m89): col = lane&15, row = (lane>>4)*4 + reg
    #pragma unroll
    for (int fi = 0; fi < 8; ++fi)
        #pragma unroll
        for (int q = 0; q < 4; ++q) {
            long grow = brow + wr + fi * 16 + (kg << 2) + q;
            float* cr = C + grow * (long)ldc + bcol + wc + fr;
            #pragma unroll
            for (int fj = 0; fj < 4; ++fj) cr[fj << 4] = acc[fi][fj][q];
        }
}

// ---------- split-bf16 MFMA GEMM (proven 2-barrier path) ----------
// C[M,N] = A[M,K] @ B[N,K]^T. Tile 128x128, BK=32, 4 waves -> 64x64 each.
// AM=1: A pre-split hi/lo, 3 passes. AM=2: A single bf16, 2 passes.
// EPI=0: store C fp32. EPI=1: p=exp(s-m), store P bf16 + atomicAdd l.
// EPI=2: C += acc. EPI=3: C = (C + acc) * (1/l).
template<int AM, int EPI>
__global__ __launch_bounds__(256, 4)
void gemm3_kernel(const ush* __restrict__ A0, const ush* __restrict__ A1,
                  const ush* __restrict__ B0, const ush* __restrict__ B1,
                  float* __restrict__ C, ush* __restrict__ Pout,
                  float* __restrict__ ml,
                  int K, int lda, int ldb, int ldc,
                  long sAz, long sBz, long sCz, long sPz)
{
    __shared__ alignas(16) ush aHi[128*32];
    __shared__ alignas(16) ush aLo[128*32];
    __shared__ alignas(16) ush bHi[128*32];
    __shared__ alignas(16) ush bLo[128*32];

    long wg  = (long)blockIdx.x +
               (long)gridDim.x * ((long)blockIdx.y + (long)gridDim.y * blockIdx.z);
    long nwg = (long)gridDim.x * gridDim.y * gridDim.z;
    long swz = (wg & 7) * (nwg >> 3) + (wg >> 3);
    const int bx = (int)(swz % gridDim.x);
    long rem = swz / gridDim.x;
    const int by = (int)(rem % gridDim.y);
    const long bz = rem / gridDim.y;

    const long mbase = (long)by << 7;
    const long nbase = (long)bx << 7;
    const int  t    = threadIdx.x;
    const int  wave = t >> 6, lane = t & 63;
    const int  wr = (wave >> 1) << 6;
    const int  wc = (wave & 1)  << 6;
    const int  fr = lane & 15;
    const int  kg = lane >> 4;

    const ush* Ah = A0 + bz * sAz;
    const ush* Bh = B0 + bz * sBz;
    const ush* Bl = B1 + bz * sBz;

    f32x4 acc[4][4] = {};

    for (int k0 = 0; k0 < K; k0 += 32) {
        #pragma unroll
        for (int i = 0; i < 2; ++i) {
            int rl = (wave << 5) + (i << 4) + (lane >> 2);
            int cs = ((lane & 3) ^ ((rl >> 1) & 3)) << 3;
            long goA = (mbase + rl) * (long)lda + k0 + cs;
            long goB = (nbase + rl) * (long)ldb + k0 + cs;
            glds16(Ah + goA, &aHi[(wave << 10) + (i << 9)]);
            if constexpr (AM == 1) {
                const ush* Al_ = A1 + bz * sAz;
                glds16(Al_ + goA, &aLo[(wave << 10) + (i << 9)]);
            }
            glds16(Bh + goB, &bHi[(wave << 10) + (i << 9)]);
            glds16(Bl + goB, &bLo[(wave << 10) + (i << 9)]);
        }
        __syncthreads();

        bf16x8 ah[4], al[4], bh[4], bl[4];
        #pragma unroll
        for (int i = 0; i < 4; ++i) {
            int ra = wr + (i << 4) + fr, rb = wc + (i << 4) + fr;
            ah[i] = *(const bf16x8*)(aHi + (swzb(ra, kg << 4) >> 1));
            if constexpr (AM == 1)
                al[i] = *(const bf16x8*)(aLo + (swzb(ra, kg << 4) >> 1));
            bh[i] = *(const bf16x8*)(bHi + (swzb(rb, kg << 4) >> 1));
            bl[i] = *(const bf16x8*)(bLo + (swzb(rb, kg << 4) >> 1));
        }
        #pragma unroll
        for (int i = 0; i < 4; ++i) {
            #pragma unroll
            for (int j = 0; j < 4; ++j) {
                acc[i][j] = __builtin_amdgcn_mfma_f32_16x16x32_bf16(ah[i], bh[j], acc[i][j], 0, 0, 0);
                acc[i][j] = __builtin_amdgcn_mfma_f32_16x16x32_bf16(ah[i], bl[j], acc[i][j], 0, 0, 0);
                if constexpr (AM == 1)
                    acc[i][j] = __builtin_amdgcn_mfma_f32_16x16x32_bf16(al[i], bh[j], acc[i][j], 0, 0, 0);
            }
        }
        __syncthreads();
    }

    if constexpr (EPI == 1) {
        ush*   Pb  = Pout + bz * sPz;
        float* mlb = ml + bz * 2048L * 1024;
        #pragma unroll
        for (int i = 0; i < 4; ++i) {
            #pragma unroll
            for (int q = 0; q < 4; ++q) {
                long grow = mbase + wr + (i << 4) + (kg << 2) + q;
                float m = mlb[grow * 1024];
                float rs = 0.f;
                #pragma unroll
                for (int j = 0; j < 4; ++j) {
                    float p = __expf(acc[i][j][q] - m);
                    rs += p;
                    Pb[grow * 512 + nbase + wc + (j << 4) + fr] = f2bf_rne(p);
                }
                rs += __shfl_xor(rs, 1); rs += __shfl_xor(rs, 2);
                rs += __shfl_xor(rs, 4); rs += __shfl_xor(rs, 8);
                if (fr == 0) atomicAdd(&mlb[grow * 1024 + 1], rs);
            }
        }
    } else {
        float* Cb = C + bz * sCz;
        #pragma unroll
        for (int i = 0; i < 4; ++i) {
            #pragma unroll
            for (int q = 0; q < 4; ++q) {
                long grow = mbase + wr + (i << 4) + (kg << 2) + q;
                float scale = 1.0f;
                if constexpr (EPI == 3)
                    scale = 1.0f / (ml + bz * 2048L * 1024)[grow * 1024 + 1];
                float* crow = Cb + grow * (long)ldc + nbase + wc + fr;
                #pragma unroll
                for (int j = 0; j < 4; ++j) {
                    if constexpr (EPI == 2)      crow[j << 4] = crow[j << 4] + acc[i][j][q];
                    else if constexpr (EPI == 3) crow[j << 4] = (crow[j << 4] + acc[i][j][q]) * scale;
                    else                         crow[j << 4] = acc[i][j][q];
                }
            }
        }
    }
}

// ---------- bias + LayerNorm + ReLU; optional hi/lo bf16 output ----------
template<int NC, bool HILO>
__global__ void ln_relu_kernel(const float* __restrict__ Y, int ldy,
                               const float* __restrict__ bias,
                               const float* __restrict__ g, const float* __restrict__ beta,
                               float* __restrict__ outf, ush* __restrict__ oh,
                               ush* __restrict__ ol, int ldo)
{
    constexpr int PER = NC / 256;
    long row = blockIdx.x;
    const float* yr = Y + row * (long)ldy;
    int t = threadIdx.x;
    float v[PER]; float s = 0.f, s2 = 0.f;
    #pragma unroll
    for (int i = 0; i < PER; ++i) {
        int c = t + (i << 8);
        float x = yr[c] + bias[c];
        v[i] = x; s += x; s2 += x * x;
    }
    s = wave_sum(s); s2 = wave_sum(s2);
    __shared__ float ra[4], rb[4];
    int w = t >> 6, l = t & 63;
    if (!l) { ra[w] = s; rb[w] = s2; }
    __syncthreads();
    s  = ra[0] + ra[1] + ra[2] + ra[3];
    s2 = rb[0] + rb[1] + rb[2] + rb[3];
    float mu  = s * (1.0f / NC);
    float var = s2 * (1.0f / NC) - mu * mu;
    float inv = rsqrtf(var + 1e-5f);
    #pragma unroll
    for (int i = 0; i < PER; ++i) {
        int c = t + (i << 8);
        float x = (v[i] - mu) * inv * g[c] + beta[c];
        x = fmaxf(x, 0.0f);
        if constexpr (HILO) {
            ush h = f2bf_rne(x);
            ush lo = f2bf_rne(x - __uint_as_float((unsigned)h << 16));
            oh[row * (long)ldo + c] = h;
            ol[row * (long)ldo + c] = lo;
        } else {
            outf[row * (long)ldo + c] = x;
        }
    }
}

// ---------- fp32 -> hi/lo bf16 split (flat) ----------
__global__ void split_kernel(const float* __restrict__ in, ush* __restrict__ h,
                             ush* __restrict__ l, long n)
{
    long i = ((long)blockIdx.x * 256 + threadIdx.x) * 4;
    if (i >= n) return;
    float4 v = *(const float4*)(in + i);
    ushort4 hh, ll;
    hh.x = f2bf_rne(v.x); ll.x = f2bf_rne(v.x - __uint_as_float((unsigned)hh.x << 16));
    hh.y = f2bf_rne(v.y); ll.y = f2bf_rne(v.y - __uint_as_float((unsigned)hh.y << 16));
    hh.z = f2bf_rne(v.z); ll.z = f2bf_rne(v.z - __uint_as_float((unsigned)hh.z << 16));
    hh.w = f2bf_rne(v.w); ll.w = f2bf_rne(v.w - __uint_as_float((unsigned)hh.w << 16));
    *(ushort4*)(h + i) = hh;
    *(ushort4*)(l + i) = ll;
}

// ---------- per-batch transpose [2048,512] -> [512,2048], hi/lo split ----------
__global__ void transpose_split_kernel(const float* __restrict__ in,
                                       ush* __restrict__ oh, ush* __restrict__ ol)
{
    __shared__ float tile[32][33];
    long bz = blockIdx.z;
    const float* I = in + bz * (long)NN * HH;
    ush* OH = oh + bz * (long)HH * NN;
    ush* OL = ol + bz * (long)HH * NN;
    int c0 = blockIdx.x << 5, r0 = blockIdx.y << 5;
    int tx = threadIdx.x & 31, ty = threadIdx.x >> 5;   // 32 x 8
    #pragma unroll
    for (int i = 0; i < 32; i += 8)
        tile[ty + i][tx] = I[(long)(r0 + ty + i) * HH + c0 + tx];
    __syncthreads();
    #pragma unroll
    for (int i = 0; i < 32; i += 8) {
        float x = tile[tx][ty + i];
        ush h = f2bf_rne(x);
        ush lo = f2bf_rne(x - __uint_as_float((unsigned)h << 16));
        long o = (long)(c0 + ty + i) * NN + r0 + tx;
        OH[o] = h; OL[o] = lo;
    }
}

// ---------- exp pass over slab-0 scores ----------
__global__ void exp_pass_kernel(float* __restrict__ ml, ush* __restrict__ P)
{
    long row = blockIdx.x;               // 0..16383
    float* sr = ml + row * 1024;
    int t = threadIdx.x;
    float s0 = sr[t], s1 = sr[t + 256];
    float m = fmaxf(s0, s1);
    m = wave_max(m);
    __shared__ float ra[4], rb[4];
    int w = t >> 6, l = t & 63;
    if (!l) ra[w] = m;
    __syncthreads();
    m = fmaxf(fmaxf(ra[0], ra[1]), fmaxf(ra[2], ra[3]));
    float p0 = __expf(s0 - m), p1 = __expf(s1 - m);
    ush h0 = f2bf_rne(p0), h1 = f2bf_rne(p1);
    P[row * 512 + t] = h0;
    P[row * 512 + t + 256] = h1;
    float ls = bf2f(h0) + bf2f(h1);
    ls = wave_sum(ls);
    if (!l) rb[w] = ls;
    __syncthreads();
    if (t == 0) {
        sr[0] = m;
        sr[1] = rb[0] + rb[1] + rb[2] + rb[3];
    }
}

// ---------- launch ----------
extern "C" void kernel_launch(void* const* d_in, const int* in_sizes, int n_in,
                              void* d_out, int out_size, void* d_ws, size_t ws_size,
                              hipStream_t stream)
{
    const float* sgm   = (const float*)d_in[0];
    const float* velo  = (const float*)d_in[1];
    const float* Wq    = (const float*)d_in[2];
    const float* bq    = (const float*)d_in[3];
    const float* gq    = (const float*)d_in[4];
    const float* betaq = (const float*)d_in[5];
    const float* Wk    = (const float*)d_in[6];
    const float* bk    = (const float*)d_in[7];
    const float* gk    = (const float*)d_in[8];
    const float* betak = (const float*)d_in[9];
    const float* Wv1   = (const float*)d_in[10];
    const float* bv1   = (const float*)d_in[11];
    const float* gv1   = (const float*)d_in[12];
    const float* betav1= (const float*)d_in[13];
    const float* Wv2   = (const float*)d_in[14];
    const float* bv2   = (const float*)d_in[15];
    const float* gv2   = (const float*)d_in[16];
    const float* betav2= (const float*)d_in[17];
    float* out = (float*)d_out;
    char*  wsb = (char*)d_ws;

    if (ws_size < 176 * MiB) return;   // proven >= 176 MiB in round 3

    ush* xh   = (ush*)wsb;
    ush* xl   = (ush*)(wsb + 32 * MiB);
    ush* kh   = (ush*)(wsb + 64 * MiB);
    ush* kl   = (ush*)(wsb + 96 * MiB);
    ush* v1th = (ush*)(wsb + 128 * MiB);
    ush* v1tl = (ush*)(wsb + 144 * MiB);
    ush* Wqh  = (ush*)(wsb + 160 * MiB);
    ush* Wql  = (ush*)(wsb + 162 * MiB);
    ush* Wkh  = (ush*)(wsb + 164 * MiB);
    ush* Wkl  = (ush*)(wsb + 166 * MiB);
    ush* Wv1h = (ush*)(wsb + 168 * MiB);
    ush* Wv1l = (ush*)(wsb + 169 * MiB);
    ush* P    = (ush*)(wsb + 160 * MiB);
    float* v1f = out + 8388608L;       // out bytes [32..64) MiB

    dim3 blk(256);

    split_kernel<<<1024, blk, 0, stream>>>(Wq,  Wqh,  Wql,  (long)CC_*DD);
    split_kernel<<<1024, blk, 0, stream>>>(Wk,  Wkh,  Wkl,  (long)CC_*DD);
    split_kernel<<<512,  blk, 0, stream>>>(Wv1, Wv1h, Wv1l, (long)HH*DD);

    // --- velo-derived: k, v1 ---
    split_kernel<<<16384, blk, 0, stream>>>(velo, xh, xl, (long)RR*DD);
    gemm8p_kernel<<<dim3(4, 64), dim3(512), 0, stream>>>(xh, xl, Wkh, Wkl, out, CC_);
    ln_relu_kernel<1024,true><<<RR, blk, 0, stream>>>(out, CC_, bk, gk, betak, nullptr, kh, kl, CC_);
    gemm3_kernel<1,0><<<dim3(4,128,1), blk, 0, stream>>>(
        xh, xl, Wv1h, Wv1l, out, nullptr, nullptr, DD, DD, DD, HH, 0, 0, 0, 0);
    ln_relu_kernel<512,false><<<RR, blk, 0, stream>>>(out, HH, bv1, gv1, betav1, v1f, nullptr, nullptr, HH);
    transpose_split_kernel<<<dim3(16,64,BB), blk, 0, stream>>>(v1f, v1th, v1tl);

    // --- sgm-derived: q ---
    split_kernel<<<16384, blk, 0, stream>>>(sgm, xh, xl, (long)RR*DD);
    gemm8p_kernel<<<dim3(4, 64), dim3(512), 0, stream>>>(xh, xl, Wqh, Wql, out, CC_);
    ln_relu_kernel<1024,true><<<RR, blk, 0, stream>>>(out, CC_, bq, gq, betaq, nullptr, xh, xl, CC_);

    // --- attention (4 key-slabs of 512) ---
    gemm3_kernel<1,0><<<dim3(4,16,8), blk, 0, stream>>>(
        xh, xl, kh, kl, out, nullptr, nullptr,
        CC_, CC_, CC_, 1024, 2048L*1024, 2048L*1024, 2048L*1024, 0);
    exp_pass_kernel<<<RR, blk, 0, stream>>>(out, P);
    gemm3_kernel<2,0><<<dim3(4,16,8), blk, 0, stream>>>(
        P, nullptr, v1th, v1tl, out + HH, nullptr, nullptr,
        512, 512, NN, CC_, 2048L*512, 512L*2048, 2048L*1024, 0);
    for (int s = 1; s < 4; ++s) {
        gemm3_kernel<1,1><<<dim3(4,16,8), blk, 0, stream>>>(
            xh, xl, kh + (long)s*512*1024, kl + (long)s*512*1024,
            nullptr, P, out, CC_, CC_, CC_, 0,
            2048L*1024, 2048L*1024, 0, 2048L*512);
        if (s < 3)
            gemm3_kernel<2,2><<<dim3(4,16,8), blk, 0, stream>>>(
                P, nullptr, v1th + s*512, v1tl + s*512,
                out + HH, nullptr, nullptr, 512, 512, NN, CC_,
                2048L*512, 512L*2048, 2048L*1024, 0);
        else
            gemm3_kernel<2,3><<<dim3(4,16,8), blk, 0, stream>>>(
                P, nullptr, v1th + s*512, v1tl + s*512,
                out + HH, nullptr, out, 512, 512, NN, CC_,
                2048L*512, 512L*2048, 2048L*1024, 0);
    }

    // --- v2 last ---
    split_kernel<<<16384, blk, 0, stream>>>(sgm, xh, xl, (long)RR*DD);
    ush* Wv2h = (ush*)(wsb + 160 * MiB);
    ush* Wv2l = (ush*)(wsb + 161 * MiB);
    split_kernel<<<512, blk, 0, stream>>>(Wv2, Wv2h, Wv2l, (long)HH*DD);
    gemm3_kernel<1,0><<<dim3(4,128,1), blk, 0, stream>>>(
        xh, xl, Wv2h, Wv2l, out, nullptr, nullptr, DD, DD, DD, CC_, 0, 0, 0, 0);
    ln_relu_kernel<512,false><<<RR, blk, 0, stream>>>(out, CC_, bv2, gv2, betav2, out, nullptr, nullptr, CC_);
}

// Round 18
// 840.647 us; speedup vs baseline: 2.5106x; 1.0639x over previous
//
#include <hip/hip_runtime.h>
#include <hip/hip_bf16.h>

// B=8, N=2048, D=1024, C=1024, H=512 (fp32 in/out)
//  q = LNReLU(sgm@Wq^T+bq); k = LNReLU(velo@Wk^T+bk)
//  S = q k^T; P = softmax(S); v1 = LNReLU(velo@Wv1^T); v2 = LNReLU(sgm@Wv2^T)
//  out = concat(v2, P@v1)
//
// Round 18: round-17 gemm8q bug found by inspection — staging scol was
// missing the (wid&1)<<5 column-block term (present in the proven gemm8p),
// so odd waves re-loaded k-cols 0..31 into the cols-32..63 subtiles ->
// half of every dot product wrong (absmax 5.47). One-line fix; everything
// else identical to round 17 (round 16 baseline: 894us, absmax 0.03125).

#define BB 8
#define NN 2048
#define DD 1024
#define CC_ 1024
#define HH 512
#define RR (BB*NN)   // 16384 rows

typedef unsigned short ush;
typedef short bf16x8 __attribute__((ext_vector_type(8)));
typedef float f32x4  __attribute__((ext_vector_type(4)));

#define MiB (1024L*1024L)

// ---------- helpers ----------
__device__ __forceinline__ ush f2bf_rne(float x) {
    unsigned u = __float_as_uint(x);
    return (ush)((u + 0x7fffu + ((u >> 16) & 1u)) >> 16);
}
__device__ __forceinline__ float bf2f(ush h) {
    return __uint_as_float((unsigned)h << 16);
}
__device__ __forceinline__ float wave_sum(float v) {
    #pragma unroll
    for (int o = 32; o; o >>= 1) v += __shfl_down(v, o);
    return v;
}
__device__ __forceinline__ float wave_max(float v) {
    #pragma unroll
    for (int o = 32; o; o >>= 1) v = fmaxf(v, __shfl_down(v, o));
    return v;
}

// gemm3 LDS tile [128 rows][32 bf16]; swizzle XORs byte bits 4..5 w/ (row>>1)&3.
__device__ __forceinline__ int swzb(int row, int kbyte) {
    return ((row << 6) | kbyte) ^ (((row >> 1) & 3) << 4);
}

// async global->LDS, 16B/lane. LDS dest wave-uniform base + lane*16;
// global src per-lane (pre-swizzled so linear LDS holds swizzled layout).
__device__ __forceinline__ void glds16(const void* g, void* l) {
    __builtin_amdgcn_global_load_lds(
        (const __attribute__((address_space(1))) unsigned*)g,
        (__attribute__((address_space(3))) unsigned*)l, 16, 0, 0);
}

// ---------- 8-phase 256x256 bf16 GEMM for the two N=1024 linears ----------
__global__ __launch_bounds__(512, 2)
void gemm8p_kernel(const ush* __restrict__ Ah, const ush* __restrict__ Al,
                   const ush* __restrict__ Bh, const ush* __restrict__ Bl,
                   float* __restrict__ C, int ldc)
{
    __shared__ ush L[65536];   // 128 KiB
    constexpr int NT = 48;     // K' / 64

    int nwg = gridDim.x * gridDim.y;
    int wg  = blockIdx.x + gridDim.x * blockIdx.y;
    int sz  = (wg & 7) * (nwg >> 3) + (wg >> 3);
    int bx  = sz % gridDim.x, by = sz / gridDim.x;
    const long brow = (long)by << 8, bcol = (long)bx << 8;

    const int t = threadIdx.x, wid = t >> 6, lane = t & 63;
    const int wr = (wid >> 2) << 7;
    const int wc = (wid & 3) << 6;
    const int fr = lane & 15, kg = lane >> 4;

    const int srow = ((wid >> 1) << 4) + (lane >> 2);
    const int scol = ((wid & 1) << 5) + ((((lane & 3) << 3)) ^ ((lane >> 5) << 4));
    const int sdst = wid << 9;

    const int cterm = (fr << 5) + ((kg << 3) ^ ((fr >> 3) << 4));
    const int ha13  = (wr >> 7) << 13;
    const int bbase = 16384 + ((wc >> 7) << 13);
    const int sb0   = (wc & 64) >> 4;

    f32x4 acc[8][4] = {};
    bf16x8 bfrag[4][2];

    auto stage = [&](int X, int half) {   // half: 0=A0 1=A1 2=B0 3=B1
        if (X >= NT) return;
        int pI = X >> 4, kc = (X & 15) << 6;
        const ush* s; long rb;
        if (half < 2) { s = (pI == 1) ? Al : Ah; rb = brow + ((long)(half & 1) << 7); }
        else          { s = (pI == 2) ? Bl : Bh; rb = bcol + ((long)(half & 1) << 7); }
        int lb = ((X & 1) << 15) + ((half >> 1) << 14) + ((half & 1) << 13) + sdst;
        glds16(s + (rb + srow) * 1024 + kc + scol,      &L[lb]);
        glds16(s + (rb + srow + 64) * 1024 + kc + scol, &L[lb + 4096]);
    };

    stage(0, 0); stage(0, 1); stage(0, 2); stage(0, 3);
    stage(1, 2); stage(1, 3);
    asm volatile("s_waitcnt vmcnt(4)");
    __builtin_amdgcn_sched_barrier(0);
    __builtin_amdgcn_s_barrier();

    for (int kt = 0; kt < NT; ++kt) {
        const int ab = (kt & 1) << 15;
        #pragma unroll
        for (int p = 0; p < 4; ++p) {
            bf16x8 afrag[2][2];
            #pragma unroll
            for (int ii = 0; ii < 2; ++ii)
                #pragma unroll
                for (int ks = 0; ks < 2; ++ks)
                    afrag[ii][ks] = *(const bf16x8*)&L[ab + ha13 +
                        ((((2 * p + ii) << 1) | ks) << 9) + cterm];
            if (p == 0) {
                #pragma unroll
                for (int fj = 0; fj < 4; ++fj)
                    #pragma unroll
                    for (int ks = 0; ks < 2; ++ks)
                        bfrag[fj][ks] = *(const bf16x8*)&L[ab + bbase +
                            ((((sb0 + fj) << 1) | ks) << 9) + cterm];
            }
            if      (p == 0) stage(kt + 1, 0);
            else if (p == 1) stage(kt + 1, 1);
            else if (p == 2) stage(kt + 2, 2);
            else             stage(kt + 2, 3);

            __builtin_amdgcn_s_barrier();
            asm volatile("s_waitcnt lgkmcnt(0)");
            __builtin_amdgcn_sched_barrier(0);
            __builtin_amdgcn_s_setprio(1);
            #pragma unroll
            for (int ii = 0; ii < 2; ++ii)
                #pragma unroll
                for (int fj = 0; fj < 4; ++fj)
                    #pragma unroll
                    for (int ks = 0; ks < 2; ++ks)
                        acc[2 * p + ii][fj] = __builtin_amdgcn_mfma_f32_16x16x32_bf16(
                            afrag[ii][ks], bfrag[fj][ks], acc[2 * p + ii][fj], 0, 0, 0);
            __builtin_amdgcn_s_setprio(0);
            if (p == 3) {
                if (kt < NT - 2) asm volatile("s_waitcnt vmcnt(4)");
                else             asm volatile("s_waitcnt vmcnt(0)");
                __builtin_amdgcn_sched_barrier(0);
            }
            __builtin_amdgcn_s_barrier();
        }
    }

    #pragma unroll
    for (int fi = 0; fi < 8; ++fi)
        #pragma unroll
        for (int q = 0; q < 4; ++q) {
            long grow = brow + wr + fi * 16 + (kg << 2) + q;
            float* cr = C + grow * (long)ldc + bcol + wc + fr;
            #pragma unroll
            for (int fj = 0; fj < 4; ++fj) cr[fj << 4] = acc[fi][fj][q];
        }
}

// ---------- 8p-structure 256x128 batched GEMM for QK slabs ----------
// C[row, key] = q[row,:] . k[key,:], 3-pass via K'=3K table. Per batch z.
// EPI=0: raw S fp32 (ldc 1024). EPI=1: P=exp(s-m) bf16 + atomicAdd l.
// LDS 96KB: [parity][A 32KB][B 16KB], st_16x32 subtiles.
template<int EPI>
__global__ __launch_bounds__(512, 2)
void gemm8q_kernel(const ush* __restrict__ Ah, const ush* __restrict__ Al,
                   const ush* __restrict__ Bh, const ush* __restrict__ Bl,
                   float* __restrict__ C, ush* __restrict__ Pout,
                   float* __restrict__ ml)
{
    __shared__ ush L[49152];   // 96 KiB
    constexpr int NT = 48;

    long nwg = (long)gridDim.x * gridDim.y * gridDim.z;
    long wg  = (long)blockIdx.x + gridDim.x * ((long)blockIdx.y + (long)gridDim.y * blockIdx.z);
    long sz  = (wg & 7) * (nwg >> 3) + (wg >> 3);
    const int bx = (int)(sz % gridDim.x);
    long rem = sz / gridDim.x;
    const int by = (int)(rem % gridDim.y);
    const long bz = rem / gridDim.y;

    const long brow = (long)by << 8;     // 0..1792 (batch-local rows)
    const long bcol = (long)bx << 7;     // 0..384  (keys within slab)

    const int t = threadIdx.x, wid = t >> 6, lane = t & 63;
    const int wr4 = wid >> 1;            // 0..3  -> rows wr4*64
    const int wc2 = wid & 1;             // 0..1  -> keys wc2*64
    const int fr = lane & 15, kg = lane >> 4;

    const int srow = ((wid >> 1) << 4) + (lane >> 2);   // 0..63 within call
    const int scol = ((wid & 1) << 5) + (((lane & 3) << 3) ^ ((lane >> 5) << 4)); // FIX
    const int sdst = wid << 9;

    const int cterm = (fr << 5) + ((kg << 3) ^ ((fr >> 3) << 4));

    const ush* qh = Ah + bz * 2048L * 1024;
    const ush* ql = Al + bz * 2048L * 1024;
    const ush* kh = Bh + bz * 2048L * 1024;
    const ush* kl = Bl + bz * 2048L * 1024;

    f32x4 acc[4][4] = {};
    bf16x8 bfrag[4][2];

    auto stageA = [&](int X, int c) {
        if (X >= NT) return;
        int pI = X >> 4, kc = (X & 15) << 6;
        const ush* s = (pI == 1) ? ql : qh;
        glds16(s + (brow + c * 64 + srow) * 1024 + kc + scol,
               &L[((X & 1) ? 24576 : 0) + ((c * 8) << 9) + sdst]);
    };
    auto stageB = [&](int X, int c) {
        if (X >= NT) return;
        int pI = X >> 4, kc = (X & 15) << 6;
        const ush* s = (pI == 2) ? kl : kh;
        glds16(s + (bcol + c * 64 + srow) * 1024 + kc + scol,
               &L[((X & 1) ? 24576 : 0) + 16384 + ((c * 8) << 9) + sdst]);
    };

    // prologue: A(0) x4, B(0) x2, B(1) x2 ; vmcnt(2) -> A0,B0 landed
    stageA(0, 0); stageA(0, 1); stageA(0, 2); stageA(0, 3);
    stageB(0, 0); stageB(0, 1);
    stageB(1, 0); stageB(1, 1);
    asm volatile("s_waitcnt vmcnt(2)");
    __builtin_amdgcn_sched_barrier(0);
    __builtin_amdgcn_s_barrier();

    for (int kt = 0; kt < NT; ++kt) {
        const int ab = (kt & 1) ? 24576 : 0;
        #pragma unroll
        for (int p = 0; p < 2; ++p) {
            bf16x8 afrag[2][2];
            #pragma unroll
            for (int ii = 0; ii < 2; ++ii)
                #pragma unroll
                for (int ks = 0; ks < 2; ++ks) {
                    int fi = 2 * p + ii;
                    int sA = (wr4 * 4 + fi) * 2 + ks;
                    afrag[ii][ks] = *(const bf16x8*)&L[ab + (sA << 9) + cterm];
                }
            if (p == 0) {
                #pragma unroll
                for (int fj = 0; fj < 4; ++fj)
                    #pragma unroll
                    for (int ks = 0; ks < 2; ++ks) {
                        int sB = (wc2 * 4 + fj) * 2 + ks;
                        bfrag[fj][ks] = *(const bf16x8*)&L[ab + 16384 + (sB << 9) + cterm];
                    }
                stageA(kt + 1, 0); stageA(kt + 1, 1); stageA(kt + 1, 2);
            } else {
                stageA(kt + 1, 3); stageB(kt + 2, 0); stageB(kt + 2, 1);
            }

            __builtin_amdgcn_s_barrier();
            asm volatile("s_waitcnt lgkmcnt(0)");
            __builtin_amdgcn_sched_barrier(0);
            __builtin_amdgcn_s_setprio(1);
            #pragma unroll
            for (int ii = 0; ii < 2; ++ii)
                #pragma unroll
                for (int fj = 0; fj < 4; ++fj)
                    #pragma unroll
                    for (int ks = 0; ks < 2; ++ks)
                        acc[2 * p + ii][fj] = __builtin_amdgcn_mfma_f32_16x16x32_bf16(
                            afrag[ii][ks], bfrag[fj][ks], acc[2 * p + ii][fj], 0, 0, 0);
            __builtin_amdgcn_s_setprio(0);
            if (p == 1) {
                if (kt < NT - 2) asm volatile("s_waitcnt vmcnt(2)");
                else             asm volatile("s_waitcnt vmcnt(0)");
                __builtin_amdgcn_sched_barrier(0);
            }
            __builtin_amdgcn_s_barrier();
        }
    }

    // C/D layout (m89): col = lane&15, row = (lane>>4)*4 + reg
    if constexpr (EPI == 1) {
        ush*   Pb  = Pout + bz * 2048L * 512;
        float* mlb = ml + bz * 2048L * 1024;
        #pragma unroll
        for (int fi = 0; fi < 4; ++fi) {
            #pragma unroll
            for (int q = 0; q < 4; ++q) {
                long grow = brow + wr4 * 64 + fi * 16 + (kg << 2) + q;
                float m = mlb[grow * 1024];
                float rs = 0.f;
                #pragma unroll
                for (int fj = 0; fj < 4; ++fj) {
                    float pv = __expf(acc[fi][fj][q] - m);
                    rs += pv;
                    Pb[grow * 512 + bcol + wc2 * 64 + fj * 16 + fr] = f2bf_rne(pv);
                }
                rs += __shfl_xor(rs, 1); rs += __shfl_xor(rs, 2);
                rs += __shfl_xor(rs, 4); rs += __shfl_xor(rs, 8);
                if (fr == 0) atomicAdd(&mlb[grow * 1024 + 1], rs);
            }
        }
    } else {
        float* Cb = C + bz * 2048L * 1024;
        #pragma unroll
        for (int fi = 0; fi < 4; ++fi)
            #pragma unroll
            for (int q = 0; q < 4; ++q) {
                long grow = brow + wr4 * 64 + fi * 16 + (kg << 2) + q;
                float* cr = Cb + grow * 1024 + bcol + wc2 * 64 + fr;
                #pragma unroll
                for (int fj = 0; fj < 4; ++fj) cr[fj << 4] = acc[fi][fj][q];
            }
    }
}

// ---------- split-bf16 MFMA GEMM (proven 2-barrier path) ----------
template<int AM, int EPI>
__global__ __launch_bounds__(256, 4)
void gemm3_kernel(const ush* __restrict__ A0, const ush* __restrict__ A1,
                  const ush* __restrict__ B0, const ush* __restrict__ B1,
                  float* __restrict__ C, ush* __restrict__ Pout,
                  float* __restrict__ ml,
                  int K, int lda, int ldb, int ldc,
                  long sAz, long sBz, long sCz, long sPz)
{
    __shared__ alignas(16) ush aHi[128*32];
    __shared__ alignas(16) ush aLo[128*32];
    __shared__ alignas(16) ush bHi[128*32];
    __shared__ alignas(16) ush bLo[128*32];

    long wg  = (long)blockIdx.x +
               (long)gridDim.x * ((long)blockIdx.y + (long)gridDim.y * blockIdx.z);
    long nwg = (long)gridDim.x * gridDim.y * gridDim.z;
    long swz = (wg & 7) * (nwg >> 3) + (wg >> 3);
    const int bx = (int)(swz % gridDim.x);
    long rem = swz / gridDim.x;
    const int by = (int)(rem % gridDim.y);
    const long bz = rem / gridDim.y;

    const long mbase = (long)by << 7;
    const long nbase = (long)bx << 7;
    const int  t    = threadIdx.x;
    const int  wave = t >> 6, lane = t & 63;
    const int  wr = (wave >> 1) << 6;
    const int  wc = (wave & 1)  << 6;
    const int  fr = lane & 15;
    const int  kg = lane >> 4;

    const ush* Ah = A0 + bz * sAz;
    const ush* Bh = B0 + bz * sBz;
    const ush* Bl = B1 + bz * sBz;

    f32x4 acc[4][4] = {};

    for (int k0 = 0; k0 < K; k0 += 32) {
        #pragma unroll
        for (int i = 0; i < 2; ++i) {
            int rl = (wave << 5) + (i << 4) + (lane >> 2);
            int cs = ((lane & 3) ^ ((rl >> 1) & 3)) << 3;
            long goA = (mbase + rl) * (long)lda + k0 + cs;
            long goB = (nbase + rl) * (long)ldb + k0 + cs;
            glds16(Ah + goA, &aHi[(wave << 10) + (i << 9)]);
            if constexpr (AM == 1) {
                const ush* Al_ = A1 + bz * sAz;
                glds16(Al_ + goA, &aLo[(wave << 10) + (i << 9)]);
            }
            glds16(Bh + goB, &bHi[(wave << 10) + (i << 9)]);
            glds16(Bl + goB, &bLo[(wave << 10) + (i << 9)]);
        }
        __syncthreads();

        bf16x8 ah[4], al[4], bh[4], bl[4];
        #pragma unroll
        for (int i = 0; i < 4; ++i) {
            int ra = wr + (i << 4) + fr, rb = wc + (i << 4) + fr;
            ah[i] = *(const bf16x8*)(aHi + (swzb(ra, kg << 4) >> 1));
            if constexpr (AM == 1)
                al[i] = *(const bf16x8*)(aLo + (swzb(ra, kg << 4) >> 1));
            bh[i] = *(const bf16x8*)(bHi + (swzb(rb, kg << 4) >> 1));
            bl[i] = *(const bf16x8*)(bLo + (swzb(rb, kg << 4) >> 1));
        }
        #pragma unroll
        for (int i = 0; i < 4; ++i) {
            #pragma unroll
            for (int j = 0; j < 4; ++j) {
                acc[i][j] = __builtin_amdgcn_mfma_f32_16x16x32_bf16(ah[i], bh[j], acc[i][j], 0, 0, 0);
                acc[i][j] = __builtin_amdgcn_mfma_f32_16x16x32_bf16(ah[i], bl[j], acc[i][j], 0, 0, 0);
                if constexpr (AM == 1)
                    acc[i][j] = __builtin_amdgcn_mfma_f32_16x16x32_bf16(al[i], bh[j], acc[i][j], 0, 0, 0);
            }
        }
        __syncthreads();
    }

    if constexpr (EPI == 1) {
        ush*   Pb  = Pout + bz * sPz;
        float* mlb = ml + bz * 2048L * 1024;
        #pragma unroll
        for (int i = 0; i < 4; ++i) {
            #pragma unroll
            for (int q = 0; q < 4; ++q) {
                long grow = mbase + wr + (i << 4) + (kg << 2) + q;
                float m = mlb[grow * 1024];
                float rs = 0.f;
                #pragma unroll
                for (int j = 0; j < 4; ++j) {
                    float p = __expf(acc[i][j][q] - m);
                    rs += p;
                    Pb[grow * 512 + nbase + wc + (j << 4) + fr] = f2bf_rne(p);
                }
                rs += __shfl_xor(rs, 1); rs += __shfl_xor(rs, 2);
                rs += __shfl_xor(rs, 4); rs += __shfl_xor(rs, 8);
                if (fr == 0) atomicAdd(&mlb[grow * 1024 + 1], rs);
            }
        }
    } else {
        float* Cb = C + bz * sCz;
        #pragma unroll
        for (int i = 0; i < 4; ++i) {
            #pragma unroll
            for (int q = 0; q < 4; ++q) {
                long grow = mbase + wr + (i << 4) + (kg << 2) + q;
                float scale = 1.0f;
                if constexpr (EPI == 3)
                    scale = 1.0f / (ml + bz * 2048L * 1024)[grow * 1024 + 1];
                float* crow = Cb + grow * (long)ldc + nbase + wc + fr;
                #pragma unroll
                for (int j = 0; j < 4; ++j) {
                    if constexpr (EPI == 2)      crow[j << 4] = crow[j << 4] + acc[i][j][q];
                    else if constexpr (EPI == 3) crow[j << 4] = (crow[j << 4] + acc[i][j][q]) * scale;
                    else                         crow[j << 4] = acc[i][j][q];
                }
            }
        }
    }
}

// ---------- bias + LayerNorm + ReLU; optional hi/lo bf16 output ----------
template<int NC, bool HILO>
__global__ void ln_relu_kernel(const float* __restrict__ Y, int ldy,
                               const float* __restrict__ bias,
                               const float* __restrict__ g, const float* __restrict__ beta,
                               float* __restrict__ outf, ush* __restrict__ oh,
                               ush* __restrict__ ol, int ldo)
{
    constexpr int PER = NC / 256;
    long row = blockIdx.x;
    const float* yr = Y + row * (long)ldy;
    int t = threadIdx.x;
    float v[PER]; float s = 0.f, s2 = 0.f;
    #pragma unroll
    for (int i = 0; i < PER; ++i) {
        int c = t + (i << 8);
        float x = yr[c] + bias[c];
        v[i] = x; s += x; s2 += x * x;
    }
    s = wave_sum(s); s2 = wave_sum(s2);
    __shared__ float ra[4], rb[4];
    int w = t >> 6, l = t & 63;
    if (!l) { ra[w] = s; rb[w] = s2; }
    __syncthreads();
    s  = ra[0] + ra[1] + ra[2] + ra[3];
    s2 = rb[0] + rb[1] + rb[2] + rb[3];
    float mu  = s * (1.0f / NC);
    float var = s2 * (1.0f / NC) - mu * mu;
    float inv = rsqrtf(var + 1e-5f);
    #pragma unroll
    for (int i = 0; i < PER; ++i) {
        int c = t + (i << 8);
        float x = (v[i] - mu) * inv * g[c] + beta[c];
        x = fmaxf(x, 0.0f);
        if constexpr (HILO) {
            ush h = f2bf_rne(x);
            ush lo = f2bf_rne(x - __uint_as_float((unsigned)h << 16));
            oh[row * (long)ldo + c] = h;
            ol[row * (long)ldo + c] = lo;
        } else {
            outf[row * (long)ldo + c] = x;
        }
    }
}

// ---------- fp32 -> hi/lo bf16 split (flat) ----------
__global__ void split_kernel(const float* __restrict__ in, ush* __restrict__ h,
                             ush* __restrict__ l, long n)
{
    long i = ((long)blockIdx.x * 256 + threadIdx.x) * 4;
    if (i >= n) return;
    float4 v = *(const float4*)(in + i);
    ushort4 hh, ll;
    hh.x = f2bf_rne(v.x); ll.x = f2bf_rne(v.x - __uint_as_float((unsigned)hh.x << 16));
    hh.y = f2bf_rne(v.y); ll.y = f2bf_rne(v.y - __uint_as_float((unsigned)hh.y << 16));
    hh.z = f2bf_rne(v.z); ll.z = f2bf_rne(v.z - __uint_as_float((unsigned)hh.z << 16));
    hh.w = f2bf_rne(v.w); ll.w = f2bf_rne(v.w - __uint_as_float((unsigned)hh.w << 16));
    *(ushort4*)(h + i) = hh;
    *(ushort4*)(l + i) = ll;
}

// ---------- per-batch transpose [2048,512] -> [512,2048], hi/lo split ----------
__global__ void transpose_split_kernel(const float* __restrict__ in,
                                       ush* __restrict__ oh, ush* __restrict__ ol)
{
    __shared__ float tile[32][33];
    long bz = blockIdx.z;
    const float* I = in + bz * (long)NN * HH;
    ush* OH = oh + bz * (long)HH * NN;
    ush* OL = ol + bz * (long)HH * NN;
    int c0 = blockIdx.x << 5, r0 = blockIdx.y << 5;
    int tx = threadIdx.x & 31, ty = threadIdx.x >> 5;   // 32 x 8
    #pragma unroll
    for (int i = 0; i < 32; i += 8)
        tile[ty + i][tx] = I[(long)(r0 + ty + i) * HH + c0 + tx];
    __syncthreads();
    #pragma unroll
    for (int i = 0; i < 32; i += 8) {
        float x = tile[tx][ty + i];
        ush h = f2bf_rne(x);
        ush lo = f2bf_rne(x - __uint_as_float((unsigned)h << 16));
        long o = (long)(c0 + ty + i) * NN + r0 + tx;
        OH[o] = h; OL[o] = lo;
    }
}

// ---------- exp pass over slab-0 scores ----------
__global__ void exp_pass_kernel(float* __restrict__ ml, ush* __restrict__ P)
{
    long row = blockIdx.x;               // 0..16383
    float* sr = ml + row * 1024;
    int t = threadIdx.x;
    float s0 = sr[t], s1 = sr[t + 256];
    float m = fmaxf(s0, s1);
    m = wave_max(m);
    __shared__ float ra[4], rb[4];
    int w = t >> 6, l = t & 63;
    if (!l) ra[w] = m;
    __syncthreads();
    m = fmaxf(fmaxf(ra[0], ra[1]), fmaxf(ra[2], ra[3]));
    float p0 = __expf(s0 - m), p1 = __expf(s1 - m);
    ush h0 = f2bf_rne(p0), h1 = f2bf_rne(p1);
    P[row * 512 + t] = h0;
    P[row * 512 + t + 256] = h1;
    float ls = bf2f(h0) + bf2f(h1);
    ls = wave_sum(ls);
    if (!l) rb[w] = ls;
    __syncthreads();
    if (t == 0) {
        sr[0] = m;
        sr[1] = rb[0] + rb[1] + rb[2] + rb[3];
    }
}

// ---------- launch ----------
extern "C" void kernel_launch(void* const* d_in, const int* in_sizes, int n_in,
                              void* d_out, int out_size, void* d_ws, size_t ws_size,
                              hipStream_t stream)
{
    const float* sgm   = (const float*)d_in[0];
    const float* velo  = (const float*)d_in[1];
    const float* Wq    = (const float*)d_in[2];
    const float* bq    = (const float*)d_in[3];
    const float* gq    = (const float*)d_in[4];
    const float* betaq = (const float*)d_in[5];
    const float* Wk    = (const float*)d_in[6];
    const float* bk    = (const float*)d_in[7];
    const float* gk    = (const float*)d_in[8];
    const float* betak = (const float*)d_in[9];
    const float* Wv1   = (const float*)d_in[10];
    const float* bv1   = (const float*)d_in[11];
    const float* gv1   = (const float*)d_in[12];
    const float* betav1= (const float*)d_in[13];
    const float* Wv2   = (const float*)d_in[14];
    const float* bv2   = (const float*)d_in[15];
    const float* gv2   = (const float*)d_in[16];
    const float* betav2= (const float*)d_in[17];
    float* out = (float*)d_out;
    char*  wsb = (char*)d_ws;

    if (ws_size < 176 * MiB) return;   // proven >= 176 MiB in round 3

    ush* xh   = (ush*)wsb;
    ush* xl   = (ush*)(wsb + 32 * MiB);
    ush* kh   = (ush*)(wsb + 64 * MiB);
    ush* kl   = (ush*)(wsb + 96 * MiB);
    ush* v1th = (ush*)(wsb + 128 * MiB);
    ush* v1tl = (ush*)(wsb + 144 * MiB);
    ush* Wqh  = (ush*)(wsb + 160 * MiB);
    ush* Wql  = (ush*)(wsb + 162 * MiB);
    ush* Wkh  = (ush*)(wsb + 164 * MiB);
    ush* Wkl  = (ush*)(wsb + 166 * MiB);
    ush* Wv1h = (ush*)(wsb + 168 * MiB);
    ush* Wv1l = (ush*)(wsb + 169 * MiB);
    ush* P    = (ush*)(wsb + 160 * MiB);
    float* v1f = out + 8388608L;       // out bytes [32..64) MiB

    dim3 blk(256);

    split_kernel<<<1024, blk, 0, stream>>>(Wq,  Wqh,  Wql,  (long)CC_*DD);
    split_kernel<<<1024, blk, 0, stream>>>(Wk,  Wkh,  Wkl,  (long)CC_*DD);
    split_kernel<<<512,  blk, 0, stream>>>(Wv1, Wv1h, Wv1l, (long)HH*DD);

    // --- velo-derived: k, v1 ---
    split_kernel<<<16384, blk, 0, stream>>>(velo, xh, xl, (long)RR*DD);
    gemm8p_kernel<<<dim3(4, 64), dim3(512), 0, stream>>>(xh, xl, Wkh, Wkl, out, CC_);
    ln_relu_kernel<1024,true><<<RR, blk, 0, stream>>>(out, CC_, bk, gk, betak, nullptr, kh, kl, CC_);
    gemm3_kernel<1,0><<<dim3(4,128,1), blk, 0, stream>>>(
        xh, xl, Wv1h, Wv1l, out, nullptr, nullptr, DD, DD, DD, HH, 0, 0, 0, 0);
    ln_relu_kernel<512,false><<<RR, blk, 0, stream>>>(out, HH, bv1, gv1, betav1, v1f, nullptr, nullptr, HH);
    transpose_split_kernel<<<dim3(16,64,BB), blk, 0, stream>>>(v1f, v1th, v1tl);

    // --- sgm-derived: q ---
    split_kernel<<<16384, blk, 0, stream>>>(sgm, xh, xl, (long)RR*DD);
    gemm8p_kernel<<<dim3(4, 64), dim3(512), 0, stream>>>(xh, xl, Wqh, Wql, out, CC_);
    ln_relu_kernel<1024,true><<<RR, blk, 0, stream>>>(out, CC_, bq, gq, betaq, nullptr, xh, xl, CC_);

    // --- attention (4 key-slabs of 512) ---
    gemm8q_kernel<0><<<dim3(4, 8, 8), dim3(512), 0, stream>>>(
        xh, xl, kh, kl, out, nullptr, nullptr);
    exp_pass_kernel<<<RR, blk, 0, stream>>>(out, P);
    gemm3_kernel<2,0><<<dim3(4,16,8), blk, 0, stream>>>(
        P, nullptr, v1th, v1tl, out + HH, nullptr, nullptr,
        512, 512, NN, CC_, 2048L*512, 512L*2048, 2048L*1024, 0);
    for (int s = 1; s < 4; ++s) {
        gemm8q_kernel<1><<<dim3(4, 8, 8), dim3(512), 0, stream>>>(
            xh, xl, kh + (long)s*512*1024, kl + (long)s*512*1024,
            nullptr, P, out);
        if (s < 3)
            gemm3_kernel<2,2><<<dim3(4,16,8), blk, 0, stream>>>(
                P, nullptr, v1th + s*512, v1tl + s*512,
                out + HH, nullptr, nullptr, 512, 512, NN, CC_,
                2048L*512, 512L*2048, 2048L*1024, 0);
        else
            gemm3_kernel<2,3><<<dim3(4,16,8), blk, 0, stream>>>(
                P, nullptr, v1th + s*512, v1tl + s*512,
                out + HH, nullptr, out, 512, 512, NN, CC_,
                2048L*512, 512L*2048, 2048L*1024, 0);
    }

    // --- v2 last ---
    split_kernel<<<16384, blk, 0, stream>>>(sgm, xh, xl, (long)RR*DD);
    ush* Wv2h = (ush*)(wsb + 160 * MiB);
    ush* Wv2l = (ush*)(wsb + 161 * MiB);
    split_kernel<<<512, blk, 0, stream>>>(Wv2, Wv2h, Wv2l, (long)HH*DD);
    gemm3_kernel<1,0><<<dim3(4,128,1), blk, 0, stream>>>(
        xh, xl, Wv2h, Wv2l, out, nullptr, nullptr, DD, DD, DD, CC_, 0, 0, 0, 0);
    ln_relu_kernel<512,false><<<RR, blk, 0, stream>>>(out, CC_, bv2, gv2, betav2, out, nullptr, nullptr, CC_);
}

// Round 19
// 796.903 us; speedup vs baseline: 2.6484x; 1.0549x over previous
//
#include <hip/hip_runtime.h>
#include <hip/hip_bf16.h>

// B=8, N=2048, D=1024, C=1024, H=512 (fp32 in/out)
//  q = LNReLU(sgm@Wq^T+bq); k = LNReLU(velo@Wk^T+bk)
//  S = q k^T; P = softmax(S); v1 = LNReLU(velo@Wv1^T); v2 = LNReLU(sgm@Wv2^T)
//  out = concat(v2, P@v1)
//
// Round 19 (round 18 = 840us, absmax 0.03125):
//  (1) Wv1/Wv2 linears moved to the proven gemm8q 256x128 8-phase structure
//      (ldc now a parameter; grid (4,64,1), bz=0, B=weight rows).
//  (2) v1t stored single bf16 -> PV is 1-pass (gemm3 AM=3), transpose writes
//      half the bytes. Added error ~0.002 abs (<< 0.109 threshold).

#define BB 8
#define NN 2048
#define DD 1024
#define CC_ 1024
#define HH 512
#define RR (BB*NN)   // 16384 rows

typedef unsigned short ush;
typedef short bf16x8 __attribute__((ext_vector_type(8)));
typedef float f32x4  __attribute__((ext_vector_type(4)));

#define MiB (1024L*1024L)

// ---------- helpers ----------
__device__ __forceinline__ ush f2bf_rne(float x) {
    unsigned u = __float_as_uint(x);
    return (ush)((u + 0x7fffu + ((u >> 16) & 1u)) >> 16);
}
__device__ __forceinline__ float bf2f(ush h) {
    return __uint_as_float((unsigned)h << 16);
}
__device__ __forceinline__ float wave_sum(float v) {
    #pragma unroll
    for (int o = 32; o; o >>= 1) v += __shfl_down(v, o);
    return v;
}
__device__ __forceinline__ float wave_max(float v) {
    #pragma unroll
    for (int o = 32; o; o >>= 1) v = fmaxf(v, __shfl_down(v, o));
    return v;
}

// gemm3 LDS tile [128 rows][32 bf16]; swizzle XORs byte bits 4..5 w/ (row>>1)&3.
__device__ __forceinline__ int swzb(int row, int kbyte) {
    return ((row << 6) | kbyte) ^ (((row >> 1) & 3) << 4);
}

// async global->LDS, 16B/lane. LDS dest wave-uniform base + lane*16;
// global src per-lane (pre-swizzled so linear LDS holds swizzled layout).
__device__ __forceinline__ void glds16(const void* g, void* l) {
    __builtin_amdgcn_global_load_lds(
        (const __attribute__((address_space(1))) unsigned*)g,
        (__attribute__((address_space(3))) unsigned*)l, 16, 0, 0);
}

// ---------- 8-phase 256x256 bf16 GEMM for the two N=1024 linears ----------
__global__ __launch_bounds__(512, 2)
void gemm8p_kernel(const ush* __restrict__ Ah, const ush* __restrict__ Al,
                   const ush* __restrict__ Bh, const ush* __restrict__ Bl,
                   float* __restrict__ C, int ldc)
{
    __shared__ ush L[65536];   // 128 KiB
    constexpr int NT = 48;     // K' / 64

    int nwg = gridDim.x * gridDim.y;
    int wg  = blockIdx.x + gridDim.x * blockIdx.y;
    int sz  = (wg & 7) * (nwg >> 3) + (wg >> 3);
    int bx  = sz % gridDim.x, by = sz / gridDim.x;
    const long brow = (long)by << 8, bcol = (long)bx << 8;

    const int t = threadIdx.x, wid = t >> 6, lane = t & 63;
    const int wr = (wid >> 2) << 7;
    const int wc = (wid & 3) << 6;
    const int fr = lane & 15, kg = lane >> 4;

    const int srow = ((wid >> 1) << 4) + (lane >> 2);
    const int scol = ((wid & 1) << 5) + ((((lane & 3) << 3)) ^ ((lane >> 5) << 4));
    const int sdst = wid << 9;

    const int cterm = (fr << 5) + ((kg << 3) ^ ((fr >> 3) << 4));
    const int ha13  = (wr >> 7) << 13;
    const int bbase = 16384 + ((wc >> 7) << 13);
    const int sb0   = (wc & 64) >> 4;

    f32x4 acc[8][4] = {};
    bf16x8 bfrag[4][2];

    auto stage = [&](int X, int half) {   // half: 0=A0 1=A1 2=B0 3=B1
        if (X >= NT) return;
        int pI = X >> 4, kc = (X & 15) << 6;
        const ush* s; long rb;
        if (half < 2) { s = (pI == 1) ? Al : Ah; rb = brow + ((long)(half & 1) << 7); }
        else          { s = (pI == 2) ? Bl : Bh; rb = bcol + ((long)(half & 1) << 7); }
        int lb = ((X & 1) << 15) + ((half >> 1) << 14) + ((half & 1) << 13) + sdst;
        glds16(s + (rb + srow) * 1024 + kc + scol,      &L[lb]);
        glds16(s + (rb + srow + 64) * 1024 + kc + scol, &L[lb + 4096]);
    };

    stage(0, 0); stage(0, 1); stage(0, 2); stage(0, 3);
    stage(1, 2); stage(1, 3);
    asm volatile("s_waitcnt vmcnt(4)");
    __builtin_amdgcn_sched_barrier(0);
    __builtin_amdgcn_s_barrier();

    for (int kt = 0; kt < NT; ++kt) {
        const int ab = (kt & 1) << 15;
        #pragma unroll
        for (int p = 0; p < 4; ++p) {
            bf16x8 afrag[2][2];
            #pragma unroll
            for (int ii = 0; ii < 2; ++ii)
                #pragma unroll
                for (int ks = 0; ks < 2; ++ks)
                    afrag[ii][ks] = *(const bf16x8*)&L[ab + ha13 +
                        ((((2 * p + ii) << 1) | ks) << 9) + cterm];
            if (p == 0) {
                #pragma unroll
                for (int fj = 0; fj < 4; ++fj)
                    #pragma unroll
                    for (int ks = 0; ks < 2; ++ks)
                        bfrag[fj][ks] = *(const bf16x8*)&L[ab + bbase +
                            ((((sb0 + fj) << 1) | ks) << 9) + cterm];
            }
            if      (p == 0) stage(kt + 1, 0);
            else if (p == 1) stage(kt + 1, 1);
            else if (p == 2) stage(kt + 2, 2);
            else             stage(kt + 2, 3);

            __builtin_amdgcn_s_barrier();
            asm volatile("s_waitcnt lgkmcnt(0)");
            __builtin_amdgcn_sched_barrier(0);
            __builtin_amdgcn_s_setprio(1);
            #pragma unroll
            for (int ii = 0; ii < 2; ++ii)
                #pragma unroll
                for (int fj = 0; fj < 4; ++fj)
                    #pragma unroll
                    for (int ks = 0; ks < 2; ++ks)
                        acc[2 * p + ii][fj] = __builtin_amdgcn_mfma_f32_16x16x32_bf16(
                            afrag[ii][ks], bfrag[fj][ks], acc[2 * p + ii][fj], 0, 0, 0);
            __builtin_amdgcn_s_setprio(0);
            if (p == 3) {
                if (kt < NT - 2) asm volatile("s_waitcnt vmcnt(4)");
                else             asm volatile("s_waitcnt vmcnt(0)");
                __builtin_amdgcn_sched_barrier(0);
            }
            __builtin_amdgcn_s_barrier();
        }
    }

    #pragma unroll
    for (int fi = 0; fi < 8; ++fi)
        #pragma unroll
        for (int q = 0; q < 4; ++q) {
            long grow = brow + wr + fi * 16 + (kg << 2) + q;
            float* cr = C + grow * (long)ldc + bcol + wc + fr;
            #pragma unroll
            for (int fj = 0; fj < 4; ++fj) cr[fj << 4] = acc[fi][fj][q];
        }
}

// ---------- 8p-structure 256x128 batched GEMM (QK slabs + H=512 linears) ----------
// C[row, col] = A[row,:] . B[col,:], 3-pass via K'=3K table.
// EPI=0: raw C fp32 at ldc (batch stride 2048*1024 when gridDim.z>1).
// EPI=1: P=exp(s-m) bf16 + atomicAdd l.
// LDS 96KB: [parity][A 32KB][B 16KB], st_16x32 subtiles.
template<int EPI>
__global__ __launch_bounds__(512, 2)
void gemm8q_kernel(const ush* __restrict__ Ah, const ush* __restrict__ Al,
                   const ush* __restrict__ Bh, const ush* __restrict__ Bl,
                   float* __restrict__ C, ush* __restrict__ Pout,
                   float* __restrict__ ml, int ldc)
{
    __shared__ ush L[49152];   // 96 KiB
    constexpr int NT = 48;

    long nwg = (long)gridDim.x * gridDim.y * gridDim.z;
    long wg  = (long)blockIdx.x + gridDim.x * ((long)blockIdx.y + (long)gridDim.y * blockIdx.z);
    long sz  = (wg & 7) * (nwg >> 3) + (wg >> 3);
    const int bx = (int)(sz % gridDim.x);
    long rem = sz / gridDim.x;
    const int by = (int)(rem % gridDim.y);
    const long bz = rem / gridDim.y;

    const long brow = (long)by << 8;
    const long bcol = (long)bx << 7;

    const int t = threadIdx.x, wid = t >> 6, lane = t & 63;
    const int wr4 = wid >> 1;
    const int wc2 = wid & 1;
    const int fr = lane & 15, kg = lane >> 4;

    const int srow = ((wid >> 1) << 4) + (lane >> 2);
    const int scol = ((wid & 1) << 5) + (((lane & 3) << 3) ^ ((lane >> 5) << 4));
    const int sdst = wid << 9;

    const int cterm = (fr << 5) + ((kg << 3) ^ ((fr >> 3) << 4));

    const ush* qh = Ah + bz * 2048L * 1024;
    const ush* ql = Al + bz * 2048L * 1024;
    const ush* kh = Bh + bz * 2048L * 1024;
    const ush* kl = Bl + bz * 2048L * 1024;

    f32x4 acc[4][4] = {};
    bf16x8 bfrag[4][2];

    auto stageA = [&](int X, int c) {
        if (X >= NT) return;
        int pI = X >> 4, kc = (X & 15) << 6;
        const ush* s = (pI == 1) ? ql : qh;
        glds16(s + (brow + c * 64 + srow) * 1024 + kc + scol,
               &L[((X & 1) ? 24576 : 0) + ((c * 8) << 9) + sdst]);
    };
    auto stageB = [&](int X, int c) {
        if (X >= NT) return;
        int pI = X >> 4, kc = (X & 15) << 6;
        const ush* s = (pI == 2) ? kl : kh;
        glds16(s + (bcol + c * 64 + srow) * 1024 + kc + scol,
               &L[((X & 1) ? 24576 : 0) + 16384 + ((c * 8) << 9) + sdst]);
    };

    stageA(0, 0); stageA(0, 1); stageA(0, 2); stageA(0, 3);
    stageB(0, 0); stageB(0, 1);
    stageB(1, 0); stageB(1, 1);
    asm volatile("s_waitcnt vmcnt(2)");
    __builtin_amdgcn_sched_barrier(0);
    __builtin_amdgcn_s_barrier();

    for (int kt = 0; kt < NT; ++kt) {
        const int ab = (kt & 1) ? 24576 : 0;
        #pragma unroll
        for (int p = 0; p < 2; ++p) {
            bf16x8 afrag[2][2];
            #pragma unroll
            for (int ii = 0; ii < 2; ++ii)
                #pragma unroll
                for (int ks = 0; ks < 2; ++ks) {
                    int fi = 2 * p + ii;
                    int sA = (wr4 * 4 + fi) * 2 + ks;
                    afrag[ii][ks] = *(const bf16x8*)&L[ab + (sA << 9) + cterm];
                }
            if (p == 0) {
                #pragma unroll
                for (int fj = 0; fj < 4; ++fj)
                    #pragma unroll
                    for (int ks = 0; ks < 2; ++ks) {
                        int sB = (wc2 * 4 + fj) * 2 + ks;
                        bfrag[fj][ks] = *(const bf16x8*)&L[ab + 16384 + (sB << 9) + cterm];
                    }
                stageA(kt + 1, 0); stageA(kt + 1, 1); stageA(kt + 1, 2);
            } else {
                stageA(kt + 1, 3); stageB(kt + 2, 0); stageB(kt + 2, 1);
            }

            __builtin_amdgcn_s_barrier();
            asm volatile("s_waitcnt lgkmcnt(0)");
            __builtin_amdgcn_sched_barrier(0);
            __builtin_amdgcn_s_setprio(1);
            #pragma unroll
            for (int ii = 0; ii < 2; ++ii)
                #pragma unroll
                for (int fj = 0; fj < 4; ++fj)
                    #pragma unroll
                    for (int ks = 0; ks < 2; ++ks)
                        acc[2 * p + ii][fj] = __builtin_amdgcn_mfma_f32_16x16x32_bf16(
                            afrag[ii][ks], bfrag[fj][ks], acc[2 * p + ii][fj], 0, 0, 0);
            __builtin_amdgcn_s_setprio(0);
            if (p == 1) {
                if (kt < NT - 2) asm volatile("s_waitcnt vmcnt(2)");
                else             asm volatile("s_waitcnt vmcnt(0)");
                __builtin_amdgcn_sched_barrier(0);
            }
            __builtin_amdgcn_s_barrier();
        }
    }

    // C/D layout (m89): col = lane&15, row = (lane>>4)*4 + reg
    if constexpr (EPI == 1) {
        ush*   Pb  = Pout + bz * 2048L * 512;
        float* mlb = ml + bz * 2048L * 1024;
        #pragma unroll
        for (int fi = 0; fi < 4; ++fi) {
            #pragma unroll
            for (int q = 0; q < 4; ++q) {
                long grow = brow + wr4 * 64 + fi * 16 + (kg << 2) + q;
                float m = mlb[grow * 1024];
                float rs = 0.f;
                #pragma unroll
                for (int fj = 0; fj < 4; ++fj) {
                    float pv = __expf(acc[fi][fj][q] - m);
                    rs += pv;
                    Pb[grow * 512 + bcol + wc2 * 64 + fj * 16 + fr] = f2bf_rne(pv);
                }
                rs += __shfl_xor(rs, 1); rs += __shfl_xor(rs, 2);
                rs += __shfl_xor(rs, 4); rs += __shfl_xor(rs, 8);
                if (fr == 0) atomicAdd(&mlb[grow * 1024 + 1], rs);
            }
        }
    } else {
        float* Cb = C + bz * 2048L * 1024;
        #pragma unroll
        for (int fi = 0; fi < 4; ++fi)
            #pragma unroll
            for (int q = 0; q < 4; ++q) {
                long grow = brow + wr4 * 64 + fi * 16 + (kg << 2) + q;
                float* cr = Cb + grow * (long)ldc + bcol + wc2 * 64 + fr;
                #pragma unroll
                for (int fj = 0; fj < 4; ++fj) cr[fj << 4] = acc[fi][fj][q];
            }
    }
}

// ---------- split-bf16 MFMA GEMM (proven 2-barrier path) ----------
// AM=1: A hi/lo 3-pass. AM=2: A single, B hi/lo 2-pass. AM=3: A,B single 1-pass.
// EPI=0 store, EPI=2 +=, EPI=3 (c+acc)/l.
template<int AM, int EPI>
__global__ __launch_bounds__(256, 4)
void gemm3_kernel(const ush* __restrict__ A0, const ush* __restrict__ A1,
                  const ush* __restrict__ B0, const ush* __restrict__ B1,
                  float* __restrict__ C, ush* __restrict__ Pout,
                  float* __restrict__ ml,
                  int K, int lda, int ldb, int ldc,
                  long sAz, long sBz, long sCz, long sPz)
{
    __shared__ alignas(16) ush aHi[128*32];
    __shared__ alignas(16) ush aLo[128*32];
    __shared__ alignas(16) ush bHi[128*32];
    __shared__ alignas(16) ush bLo[128*32];

    long wg  = (long)blockIdx.x +
               (long)gridDim.x * ((long)blockIdx.y + (long)gridDim.y * blockIdx.z);
    long nwg = (long)gridDim.x * gridDim.y * gridDim.z;
    long swz = (wg & 7) * (nwg >> 3) + (wg >> 3);
    const int bx = (int)(swz % gridDim.x);
    long rem = swz / gridDim.x;
    const int by = (int)(rem % gridDim.y);
    const long bz = rem / gridDim.y;

    const long mbase = (long)by << 7;
    const long nbase = (long)bx << 7;
    const int  t    = threadIdx.x;
    const int  wave = t >> 6, lane = t & 63;
    const int  wr = (wave >> 1) << 6;
    const int  wc = (wave & 1)  << 6;
    const int  fr = lane & 15;
    const int  kg = lane >> 4;

    const ush* Ah = A0 + bz * sAz;
    const ush* Bh = B0 + bz * sBz;

    f32x4 acc[4][4] = {};

    for (int k0 = 0; k0 < K; k0 += 32) {
        #pragma unroll
        for (int i = 0; i < 2; ++i) {
            int rl = (wave << 5) + (i << 4) + (lane >> 2);
            int cs = ((lane & 3) ^ ((rl >> 1) & 3)) << 3;
            long goA = (mbase + rl) * (long)lda + k0 + cs;
            long goB = (nbase + rl) * (long)ldb + k0 + cs;
            glds16(Ah + goA, &aHi[(wave << 10) + (i << 9)]);
            if constexpr (AM == 1) {
                const ush* Al_ = A1 + bz * sAz;
                glds16(Al_ + goA, &aLo[(wave << 10) + (i << 9)]);
            }
            glds16(Bh + goB, &bHi[(wave << 10) + (i << 9)]);
            if constexpr (AM != 3) {
                const ush* Bl_ = B1 + bz * sBz;
                glds16(Bl_ + goB, &bLo[(wave << 10) + (i << 9)]);
            }
        }
        __syncthreads();

        bf16x8 ah[4], al[4], bh[4], bl[4];
        #pragma unroll
        for (int i = 0; i < 4; ++i) {
            int ra = wr + (i << 4) + fr, rb = wc + (i << 4) + fr;
            ah[i] = *(const bf16x8*)(aHi + (swzb(ra, kg << 4) >> 1));
            if constexpr (AM == 1)
                al[i] = *(const bf16x8*)(aLo + (swzb(ra, kg << 4) >> 1));
            bh[i] = *(const bf16x8*)(bHi + (swzb(rb, kg << 4) >> 1));
            if constexpr (AM != 3)
                bl[i] = *(const bf16x8*)(bLo + (swzb(rb, kg << 4) >> 1));
        }
        #pragma unroll
        for (int i = 0; i < 4; ++i) {
            #pragma unroll
            for (int j = 0; j < 4; ++j) {
                acc[i][j] = __builtin_amdgcn_mfma_f32_16x16x32_bf16(ah[i], bh[j], acc[i][j], 0, 0, 0);
                if constexpr (AM != 3)
                    acc[i][j] = __builtin_amdgcn_mfma_f32_16x16x32_bf16(ah[i], bl[j], acc[i][j], 0, 0, 0);
                if constexpr (AM == 1)
                    acc[i][j] = __builtin_amdgcn_mfma_f32_16x16x32_bf16(al[i], bh[j], acc[i][j], 0, 0, 0);
            }
        }
        __syncthreads();
    }

    {
        float* Cb = C + bz * sCz;
        #pragma unroll
        for (int i = 0; i < 4; ++i) {
            #pragma unroll
            for (int q = 0; q < 4; ++q) {
                long grow = mbase + wr + (i << 4) + (kg << 2) + q;
                float scale = 1.0f;
                if constexpr (EPI == 3)
                    scale = 1.0f / (ml + bz * 2048L * 1024)[grow * 1024 + 1];
                float* crow = Cb + grow * (long)ldc + nbase + wc + fr;
                #pragma unroll
                for (int j = 0; j < 4; ++j) {
                    if constexpr (EPI == 2)      crow[j << 4] = crow[j << 4] + acc[i][j][q];
                    else if constexpr (EPI == 3) crow[j << 4] = (crow[j << 4] + acc[i][j][q]) * scale;
                    else                         crow[j << 4] = acc[i][j][q];
                }
            }
        }
    }
}

// ---------- bias + LayerNorm + ReLU; optional hi/lo bf16 output ----------
template<int NC, bool HILO>
__global__ void ln_relu_kernel(const float* __restrict__ Y, int ldy,
                               const float* __restrict__ bias,
                               const float* __restrict__ g, const float* __restrict__ beta,
                               float* __restrict__ outf, ush* __restrict__ oh,
                               ush* __restrict__ ol, int ldo)
{
    constexpr int PER = NC / 256;
    long row = blockIdx.x;
    const float* yr = Y + row * (long)ldy;
    int t = threadIdx.x;
    float v[PER]; float s = 0.f, s2 = 0.f;
    #pragma unroll
    for (int i = 0; i < PER; ++i) {
        int c = t + (i << 8);
        float x = yr[c] + bias[c];
        v[i] = x; s += x; s2 += x * x;
    }
    s = wave_sum(s); s2 = wave_sum(s2);
    __shared__ float ra[4], rb[4];
    int w = t >> 6, l = t & 63;
    if (!l) { ra[w] = s; rb[w] = s2; }
    __syncthreads();
    s  = ra[0] + ra[1] + ra[2] + ra[3];
    s2 = rb[0] + rb[1] + rb[2] + rb[3];
    float mu  = s * (1.0f / NC);
    float var = s2 * (1.0f / NC) - mu * mu;
    float inv = rsqrtf(var + 1e-5f);
    #pragma unroll
    for (int i = 0; i < PER; ++i) {
        int c = t + (i << 8);
        float x = (v[i] - mu) * inv * g[c] + beta[c];
        x = fmaxf(x, 0.0f);
        if constexpr (HILO) {
            ush h = f2bf_rne(x);
            ush lo = f2bf_rne(x - __uint_as_float((unsigned)h << 16));
            oh[row * (long)ldo + c] = h;
            ol[row * (long)ldo + c] = lo;
        } else {
            outf[row * (long)ldo + c] = x;
        }
    }
}

// ---------- fp32 -> hi/lo bf16 split (flat) ----------
__global__ void split_kernel(const float* __restrict__ in, ush* __restrict__ h,
                             ush* __restrict__ l, long n)
{
    long i = ((long)blockIdx.x * 256 + threadIdx.x) * 4;
    if (i >= n) return;
    float4 v = *(const float4*)(in + i);
    ushort4 hh, ll;
    hh.x = f2bf_rne(v.x); ll.x = f2bf_rne(v.x - __uint_as_float((unsigned)hh.x << 16));
    hh.y = f2bf_rne(v.y); ll.y = f2bf_rne(v.y - __uint_as_float((unsigned)hh.y << 16));
    hh.z = f2bf_rne(v.z); ll.z = f2bf_rne(v.z - __uint_as_float((unsigned)hh.z << 16));
    hh.w = f2bf_rne(v.w); ll.w = f2bf_rne(v.w - __uint_as_float((unsigned)hh.w << 16));
    *(ushort4*)(h + i) = hh;
    *(ushort4*)(l + i) = ll;
}

// ---------- per-batch transpose [2048,512] -> [512,2048], single bf16 ----------
__global__ void transpose_split_kernel(const float* __restrict__ in,
                                       ush* __restrict__ oh)
{
    __shared__ float tile[32][33];
    long bz = blockIdx.z;
    const float* I = in + bz * (long)NN * HH;
    ush* OH = oh + bz * (long)HH * NN;
    int c0 = blockIdx.x << 5, r0 = blockIdx.y << 5;
    int tx = threadIdx.x & 31, ty = threadIdx.x >> 5;   // 32 x 8
    #pragma unroll
    for (int i = 0; i < 32; i += 8)
        tile[ty + i][tx] = I[(long)(r0 + ty + i) * HH + c0 + tx];
    __syncthreads();
    #pragma unroll
    for (int i = 0; i < 32; i += 8) {
        float x = tile[tx][ty + i];
        long o = (long)(c0 + ty + i) * NN + r0 + tx;
        OH[o] = f2bf_rne(x);
    }
}

// ---------- exp pass over slab-0 scores ----------
__global__ void exp_pass_kernel(float* __restrict__ ml, ush* __restrict__ P)
{
    long row = blockIdx.x;               // 0..16383
    float* sr = ml + row * 1024;
    int t = threadIdx.x;
    float s0 = sr[t], s1 = sr[t + 256];
    float m = fmaxf(s0, s1);
    m = wave_max(m);
    __shared__ float ra[4], rb[4];
    int w = t >> 6, l = t & 63;
    if (!l) ra[w] = m;
    __syncthreads();
    m = fmaxf(fmaxf(ra[0], ra[1]), fmaxf(ra[2], ra[3]));
    float p0 = __expf(s0 - m), p1 = __expf(s1 - m);
    ush h0 = f2bf_rne(p0), h1 = f2bf_rne(p1);
    P[row * 512 + t] = h0;
    P[row * 512 + t + 256] = h1;
    float ls = bf2f(h0) + bf2f(h1);
    ls = wave_sum(ls);
    if (!l) rb[w] = ls;
    __syncthreads();
    if (t == 0) {
        sr[0] = m;
        sr[1] = rb[0] + rb[1] + rb[2] + rb[3];
    }
}

// ---------- launch ----------
extern "C" void kernel_launch(void* const* d_in, const int* in_sizes, int n_in,
                              void* d_out, int out_size, void* d_ws, size_t ws_size,
                              hipStream_t stream)
{
    const float* sgm   = (const float*)d_in[0];
    const float* velo  = (const float*)d_in[1];
    const float* Wq    = (const float*)d_in[2];
    const float* bq    = (const float*)d_in[3];
    const float* gq    = (const float*)d_in[4];
    const float* betaq = (const float*)d_in[5];
    const float* Wk    = (const float*)d_in[6];
    const float* bk    = (const float*)d_in[7];
    const float* gk    = (const float*)d_in[8];
    const float* betak = (const float*)d_in[9];
    const float* Wv1   = (const float*)d_in[10];
    const float* bv1   = (const float*)d_in[11];
    const float* gv1   = (const float*)d_in[12];
    const float* betav1= (const float*)d_in[13];
    const float* Wv2   = (const float*)d_in[14];
    const float* bv2   = (const float*)d_in[15];
    const float* gv2   = (const float*)d_in[16];
    const float* betav2= (const float*)d_in[17];
    float* out = (float*)d_out;
    char*  wsb = (char*)d_ws;

    if (ws_size < 176 * MiB) return;   // proven >= 176 MiB in round 3

    ush* xh   = (ush*)wsb;
    ush* xl   = (ush*)(wsb + 32 * MiB);
    ush* kh   = (ush*)(wsb + 64 * MiB);
    ush* kl   = (ush*)(wsb + 96 * MiB);
    ush* v1th = (ush*)(wsb + 128 * MiB);       // single bf16 now (16 MiB)
    ush* Wqh  = (ush*)(wsb + 160 * MiB);
    ush* Wql  = (ush*)(wsb + 162 * MiB);
    ush* Wkh  = (ush*)(wsb + 164 * MiB);
    ush* Wkl  = (ush*)(wsb + 166 * MiB);
    ush* Wv1h = (ush*)(wsb + 168 * MiB);
    ush* Wv1l = (ush*)(wsb + 169 * MiB);
    ush* P    = (ush*)(wsb + 160 * MiB);
    float* v1f = out + 8388608L;       // out bytes [32..64) MiB

    dim3 blk(256);

    split_kernel<<<1024, blk, 0, stream>>>(Wq,  Wqh,  Wql,  (long)CC_*DD);
    split_kernel<<<1024, blk, 0, stream>>>(Wk,  Wkh,  Wkl,  (long)CC_*DD);
    split_kernel<<<512,  blk, 0, stream>>>(Wv1, Wv1h, Wv1l, (long)HH*DD);

    // --- velo-derived: k, v1 ---
    split_kernel<<<16384, blk, 0, stream>>>(velo, xh, xl, (long)RR*DD);
    gemm8p_kernel<<<dim3(4, 64), dim3(512), 0, stream>>>(xh, xl, Wkh, Wkl, out, CC_);
    ln_relu_kernel<1024,true><<<RR, blk, 0, stream>>>(out, CC_, bk, gk, betak, nullptr, kh, kl, CC_);
    gemm8q_kernel<0><<<dim3(4, 64, 1), dim3(512), 0, stream>>>(
        xh, xl, Wv1h, Wv1l, out, nullptr, nullptr, HH);
    ln_relu_kernel<512,false><<<RR, blk, 0, stream>>>(out, HH, bv1, gv1, betav1, v1f, nullptr, nullptr, HH);
    transpose_split_kernel<<<dim3(16,64,BB), blk, 0, stream>>>(v1f, v1th);

    // --- sgm-derived: q ---
    split_kernel<<<16384, blk, 0, stream>>>(sgm, xh, xl, (long)RR*DD);
    gemm8p_kernel<<<dim3(4, 64), dim3(512), 0, stream>>>(xh, xl, Wqh, Wql, out, CC_);
    ln_relu_kernel<1024,true><<<RR, blk, 0, stream>>>(out, CC_, bq, gq, betaq, nullptr, xh, xl, CC_);

    // --- attention (4 key-slabs of 512) ---
    gemm8q_kernel<0><<<dim3(4, 8, 8), dim3(512), 0, stream>>>(
        xh, xl, kh, kl, out, nullptr, nullptr, 1024);
    exp_pass_kernel<<<RR, blk, 0, stream>>>(out, P);
    gemm3_kernel<3,0><<<dim3(4,16,8), blk, 0, stream>>>(
        P, nullptr, v1th, nullptr, out + HH, nullptr, nullptr,
        512, 512, NN, CC_, 2048L*512, 512L*2048, 2048L*1024, 0);
    for (int s = 1; s < 4; ++s) {
        gemm8q_kernel<1><<<dim3(4, 8, 8), dim3(512), 0, stream>>>(
            xh, xl, kh + (long)s*512*1024, kl + (long)s*512*1024,
            nullptr, P, out, 0);
        if (s < 3)
            gemm3_kernel<3,2><<<dim3(4,16,8), blk, 0, stream>>>(
                P, nullptr, v1th + s*512, nullptr,
                out + HH, nullptr, nullptr, 512, 512, NN, CC_,
                2048L*512, 512L*2048, 2048L*1024, 0);
        else
            gemm3_kernel<3,3><<<dim3(4,16,8), blk, 0, stream>>>(
                P, nullptr, v1th + s*512, nullptr,
                out + HH, nullptr, out, 512, 512, NN, CC_,
                2048L*512, 512L*2048, 2048L*1024, 0);
    }

    // --- v2 last ---
    split_kernel<<<16384, blk, 0, stream>>>(sgm, xh, xl, (long)RR*DD);
    ush* Wv2h = (ush*)(wsb + 160 * MiB);
    ush* Wv2l = (ush*)(wsb + 161 * MiB);
    split_kernel<<<512, blk, 0, stream>>>(Wv2, Wv2h, Wv2l, (long)HH*DD);
    gemm8q_kernel<0><<<dim3(4, 64, 1), dim3(512), 0, stream>>>(
        xh, xl, Wv2h, Wv2l, out, nullptr, nullptr, CC_);
    ln_relu_kernel<512,false><<<RR, blk, 0, stream>>>(out, CC_, bv2, gv2, betav2, out, nullptr, nullptr, CC_);
}

// Round 20
// 784.631 us; speedup vs baseline: 2.6898x; 1.0156x over previous
//
#include <hip/hip_runtime.h>
#include <hip/hip_bf16.h>

// B=8, N=2048, D=1024, C=1024, H=512 (fp32 in/out)
//  q = LNReLU(sgm@Wq^T+bq); k = LNReLU(velo@Wk^T+bk)
//  S = q k^T; P = softmax(S); v1 = LNReLU(velo@Wv1^T); v2 = LNReLU(sgm@Wv2^T)
//  out = concat(v2, P@v1)
//
// Round 20 (round 19 = 797us, absmax 0.03125): v2 computed EARLY (right
// after the single sgm split, before q destroys x) and parked as bf16 in the
// 16 MiB ws hole freed by v1t's halving; expanded to out[:, :512] fp32 after
// PV. Kills the tail re-split of sgm. Attention + all GEMM kernels unchanged.

#define BB 8
#define NN 2048
#define DD 1024
#define CC_ 1024
#define HH 512
#define RR (BB*NN)   // 16384 rows

typedef unsigned short ush;
typedef short bf16x8 __attribute__((ext_vector_type(8)));
typedef float f32x4  __attribute__((ext_vector_type(4)));

#define MiB (1024L*1024L)

// ---------- helpers ----------
__device__ __forceinline__ ush f2bf_rne(float x) {
    unsigned u = __float_as_uint(x);
    return (ush)((u + 0x7fffu + ((u >> 16) & 1u)) >> 16);
}
__device__ __forceinline__ float bf2f(ush h) {
    return __uint_as_float((unsigned)h << 16);
}
__device__ __forceinline__ float wave_sum(float v) {
    #pragma unroll
    for (int o = 32; o; o >>= 1) v += __shfl_down(v, o);
    return v;
}
__device__ __forceinline__ float wave_max(float v) {
    #pragma unroll
    for (int o = 32; o; o >>= 1) v = fmaxf(v, __shfl_down(v, o));
    return v;
}

// gemm3 LDS tile [128 rows][32 bf16]; swizzle XORs byte bits 4..5 w/ (row>>1)&3.
__device__ __forceinline__ int swzb(int row, int kbyte) {
    return ((row << 6) | kbyte) ^ (((row >> 1) & 3) << 4);
}

// async global->LDS, 16B/lane. LDS dest wave-uniform base + lane*16;
// global src per-lane (pre-swizzled so linear LDS holds swizzled layout).
__device__ __forceinline__ void glds16(const void* g, void* l) {
    __builtin_amdgcn_global_load_lds(
        (const __attribute__((address_space(1))) unsigned*)g,
        (__attribute__((address_space(3))) unsigned*)l, 16, 0, 0);
}

// ---------- 8-phase 256x256 bf16 GEMM for the two N=1024 linears ----------
__global__ __launch_bounds__(512, 2)
void gemm8p_kernel(const ush* __restrict__ Ah, const ush* __restrict__ Al,
                   const ush* __restrict__ Bh, const ush* __restrict__ Bl,
                   float* __restrict__ C, int ldc)
{
    __shared__ ush L[65536];   // 128 KiB
    constexpr int NT = 48;     // K' / 64

    int nwg = gridDim.x * gridDim.y;
    int wg  = blockIdx.x + gridDim.x * blockIdx.y;
    int sz  = (wg & 7) * (nwg >> 3) + (wg >> 3);
    int bx  = sz % gridDim.x, by = sz / gridDim.x;
    const long brow = (long)by << 8, bcol = (long)bx << 8;

    const int t = threadIdx.x, wid = t >> 6, lane = t & 63;
    const int wr = (wid >> 2) << 7;
    const int wc = (wid & 3) << 6;
    const int fr = lane & 15, kg = lane >> 4;

    const int srow = ((wid >> 1) << 4) + (lane >> 2);
    const int scol = ((wid & 1) << 5) + ((((lane & 3) << 3)) ^ ((lane >> 5) << 4));
    const int sdst = wid << 9;

    const int cterm = (fr << 5) + ((kg << 3) ^ ((fr >> 3) << 4));
    const int ha13  = (wr >> 7) << 13;
    const int bbase = 16384 + ((wc >> 7) << 13);
    const int sb0   = (wc & 64) >> 4;

    f32x4 acc[8][4] = {};
    bf16x8 bfrag[4][2];

    auto stage = [&](int X, int half) {   // half: 0=A0 1=A1 2=B0 3=B1
        if (X >= NT) return;
        int pI = X >> 4, kc = (X & 15) << 6;
        const ush* s; long rb;
        if (half < 2) { s = (pI == 1) ? Al : Ah; rb = brow + ((long)(half & 1) << 7); }
        else          { s = (pI == 2) ? Bl : Bh; rb = bcol + ((long)(half & 1) << 7); }
        int lb = ((X & 1) << 15) + ((half >> 1) << 14) + ((half & 1) << 13) + sdst;
        glds16(s + (rb + srow) * 1024 + kc + scol,      &L[lb]);
        glds16(s + (rb + srow + 64) * 1024 + kc + scol, &L[lb + 4096]);
    };

    stage(0, 0); stage(0, 1); stage(0, 2); stage(0, 3);
    stage(1, 2); stage(1, 3);
    asm volatile("s_waitcnt vmcnt(4)");
    __builtin_amdgcn_sched_barrier(0);
    __builtin_amdgcn_s_barrier();

    for (int kt = 0; kt < NT; ++kt) {
        const int ab = (kt & 1) << 15;
        #pragma unroll
        for (int p = 0; p < 4; ++p) {
            bf16x8 afrag[2][2];
            #pragma unroll
            for (int ii = 0; ii < 2; ++ii)
                #pragma unroll
                for (int ks = 0; ks < 2; ++ks)
                    afrag[ii][ks] = *(const bf16x8*)&L[ab + ha13 +
                        ((((2 * p + ii) << 1) | ks) << 9) + cterm];
            if (p == 0) {
                #pragma unroll
                for (int fj = 0; fj < 4; ++fj)
                    #pragma unroll
                    for (int ks = 0; ks < 2; ++ks)
                        bfrag[fj][ks] = *(const bf16x8*)&L[ab + bbase +
                            ((((sb0 + fj) << 1) | ks) << 9) + cterm];
            }
            if      (p == 0) stage(kt + 1, 0);
            else if (p == 1) stage(kt + 1, 1);
            else if (p == 2) stage(kt + 2, 2);
            else             stage(kt + 2, 3);

            __builtin_amdgcn_s_barrier();
            asm volatile("s_waitcnt lgkmcnt(0)");
            __builtin_amdgcn_sched_barrier(0);
            __builtin_amdgcn_s_setprio(1);
            #pragma unroll
            for (int ii = 0; ii < 2; ++ii)
                #pragma unroll
                for (int fj = 0; fj < 4; ++fj)
                    #pragma unroll
                    for (int ks = 0; ks < 2; ++ks)
                        acc[2 * p + ii][fj] = __builtin_amdgcn_mfma_f32_16x16x32_bf16(
                            afrag[ii][ks], bfrag[fj][ks], acc[2 * p + ii][fj], 0, 0, 0);
            __builtin_amdgcn_s_setprio(0);
            if (p == 3) {
                if (kt < NT - 2) asm volatile("s_waitcnt vmcnt(4)");
                else             asm volatile("s_waitcnt vmcnt(0)");
                __builtin_amdgcn_sched_barrier(0);
            }
            __builtin_amdgcn_s_barrier();
        }
    }

    #pragma unroll
    for (int fi = 0; fi < 8; ++fi)
        #pragma unroll
        for (int q = 0; q < 4; ++q) {
            long grow = brow + wr + fi * 16 + (kg << 2) + q;
            float* cr = C + grow * (long)ldc + bcol + wc + fr;
            #pragma unroll
            for (int fj = 0; fj < 4; ++fj) cr[fj << 4] = acc[fi][fj][q];
        }
}

// ---------- 8p-structure 256x128 batched GEMM (QK slabs + H=512 linears) ----------
// EPI=0: raw C fp32 at ldc. EPI=1: P=exp(s-m) bf16 + atomicAdd l (ml[row*2+{0,1}]
// lives at out cols 0,1 -> mlb stride 1024 as before).
template<int EPI>
__global__ __launch_bounds__(512, 2)
void gemm8q_kernel(const ush* __restrict__ Ah, const ush* __restrict__ Al,
                   const ush* __restrict__ Bh, const ush* __restrict__ Bl,
                   float* __restrict__ C, ush* __restrict__ Pout,
                   float* __restrict__ ml, int ldc)
{
    __shared__ ush L[49152];   // 96 KiB
    constexpr int NT = 48;

    long nwg = (long)gridDim.x * gridDim.y * gridDim.z;
    long wg  = (long)blockIdx.x + gridDim.x * ((long)blockIdx.y + (long)gridDim.y * blockIdx.z);
    long sz  = (wg & 7) * (nwg >> 3) + (wg >> 3);
    const int bx = (int)(sz % gridDim.x);
    long rem = sz / gridDim.x;
    const int by = (int)(rem % gridDim.y);
    const long bz = rem / gridDim.y;

    const long brow = (long)by << 8;
    const long bcol = (long)bx << 7;

    const int t = threadIdx.x, wid = t >> 6, lane = t & 63;
    const int wr4 = wid >> 1;
    const int wc2 = wid & 1;
    const int fr = lane & 15, kg = lane >> 4;

    const int srow = ((wid >> 1) << 4) + (lane >> 2);
    const int scol = ((wid & 1) << 5) + (((lane & 3) << 3) ^ ((lane >> 5) << 4));
    const int sdst = wid << 9;

    const int cterm = (fr << 5) + ((kg << 3) ^ ((fr >> 3) << 4));

    const ush* qh = Ah + bz * 2048L * 1024;
    const ush* ql = Al + bz * 2048L * 1024;
    const ush* kh = Bh + bz * 2048L * 1024;
    const ush* kl = Bl + bz * 2048L * 1024;

    f32x4 acc[4][4] = {};
    bf16x8 bfrag[4][2];

    auto stageA = [&](int X, int c) {
        if (X >= NT) return;
        int pI = X >> 4, kc = (X & 15) << 6;
        const ush* s = (pI == 1) ? ql : qh;
        glds16(s + (brow + c * 64 + srow) * 1024 + kc + scol,
               &L[((X & 1) ? 24576 : 0) + ((c * 8) << 9) + sdst]);
    };
    auto stageB = [&](int X, int c) {
        if (X >= NT) return;
        int pI = X >> 4, kc = (X & 15) << 6;
        const ush* s = (pI == 2) ? kl : kh;
        glds16(s + (bcol + c * 64 + srow) * 1024 + kc + scol,
               &L[((X & 1) ? 24576 : 0) + 16384 + ((c * 8) << 9) + sdst]);
    };

    stageA(0, 0); stageA(0, 1); stageA(0, 2); stageA(0, 3);
    stageB(0, 0); stageB(0, 1);
    stageB(1, 0); stageB(1, 1);
    asm volatile("s_waitcnt vmcnt(2)");
    __builtin_amdgcn_sched_barrier(0);
    __builtin_amdgcn_s_barrier();

    for (int kt = 0; kt < NT; ++kt) {
        const int ab = (kt & 1) ? 24576 : 0;
        #pragma unroll
        for (int p = 0; p < 2; ++p) {
            bf16x8 afrag[2][2];
            #pragma unroll
            for (int ii = 0; ii < 2; ++ii)
                #pragma unroll
                for (int ks = 0; ks < 2; ++ks) {
                    int fi = 2 * p + ii;
                    int sA = (wr4 * 4 + fi) * 2 + ks;
                    afrag[ii][ks] = *(const bf16x8*)&L[ab + (sA << 9) + cterm];
                }
            if (p == 0) {
                #pragma unroll
                for (int fj = 0; fj < 4; ++fj)
                    #pragma unroll
                    for (int ks = 0; ks < 2; ++ks) {
                        int sB = (wc2 * 4 + fj) * 2 + ks;
                        bfrag[fj][ks] = *(const bf16x8*)&L[ab + 16384 + (sB << 9) + cterm];
                    }
                stageA(kt + 1, 0); stageA(kt + 1, 1); stageA(kt + 1, 2);
            } else {
                stageA(kt + 1, 3); stageB(kt + 2, 0); stageB(kt + 2, 1);
            }

            __builtin_amdgcn_s_barrier();
            asm volatile("s_waitcnt lgkmcnt(0)");
            __builtin_amdgcn_sched_barrier(0);
            __builtin_amdgcn_s_setprio(1);
            #pragma unroll
            for (int ii = 0; ii < 2; ++ii)
                #pragma unroll
                for (int fj = 0; fj < 4; ++fj)
                    #pragma unroll
                    for (int ks = 0; ks < 2; ++ks)
                        acc[2 * p + ii][fj] = __builtin_amdgcn_mfma_f32_16x16x32_bf16(
                            afrag[ii][ks], bfrag[fj][ks], acc[2 * p + ii][fj], 0, 0, 0);
            __builtin_amdgcn_s_setprio(0);
            if (p == 1) {
                if (kt < NT - 2) asm volatile("s_waitcnt vmcnt(2)");
                else             asm volatile("s_waitcnt vmcnt(0)");
                __builtin_amdgcn_sched_barrier(0);
            }
            __builtin_amdgcn_s_barrier();
        }
    }

    // C/D layout (m89): col = lane&15, row = (lane>>4)*4 + reg
    if constexpr (EPI == 1) {
        ush*   Pb  = Pout + bz * 2048L * 512;
        float* mlb = ml + bz * 2048L * 1024;
        #pragma unroll
        for (int fi = 0; fi < 4; ++fi) {
            #pragma unroll
            for (int q = 0; q < 4; ++q) {
                long grow = brow + wr4 * 64 + fi * 16 + (kg << 2) + q;
                float m = mlb[grow * 1024];
                float rs = 0.f;
                #pragma unroll
                for (int fj = 0; fj < 4; ++fj) {
                    float pv = __expf(acc[fi][fj][q] - m);
                    rs += pv;
                    Pb[grow * 512 + bcol + wc2 * 64 + fj * 16 + fr] = f2bf_rne(pv);
                }
                rs += __shfl_xor(rs, 1); rs += __shfl_xor(rs, 2);
                rs += __shfl_xor(rs, 4); rs += __shfl_xor(rs, 8);
                if (fr == 0) atomicAdd(&mlb[grow * 1024 + 1], rs);
            }
        }
    } else {
        float* Cb = C + bz * 2048L * 1024;
        #pragma unroll
        for (int fi = 0; fi < 4; ++fi)
            #pragma unroll
            for (int q = 0; q < 4; ++q) {
                long grow = brow + wr4 * 64 + fi * 16 + (kg << 2) + q;
                float* cr = Cb + grow * (long)ldc + bcol + wc2 * 64 + fr;
                #pragma unroll
                for (int fj = 0; fj < 4; ++fj) cr[fj << 4] = acc[fi][fj][q];
            }
    }
}

// ---------- split-bf16 MFMA GEMM (proven 2-barrier path) ----------
// AM=3: A,B single bf16, 1 pass. EPI=0 store, EPI=2 +=, EPI=3 (c+acc)/l.
template<int AM, int EPI>
__global__ __launch_bounds__(256, 4)
void gemm3_kernel(const ush* __restrict__ A0, const ush* __restrict__ A1,
                  const ush* __restrict__ B0, const ush* __restrict__ B1,
                  float* __restrict__ C, ush* __restrict__ Pout,
                  float* __restrict__ ml,
                  int K, int lda, int ldb, int ldc,
                  long sAz, long sBz, long sCz, long sPz)
{
    __shared__ alignas(16) ush aHi[128*32];
    __shared__ alignas(16) ush aLo[128*32];
    __shared__ alignas(16) ush bHi[128*32];
    __shared__ alignas(16) ush bLo[128*32];

    long wg  = (long)blockIdx.x +
               (long)gridDim.x * ((long)blockIdx.y + (long)gridDim.y * blockIdx.z);
    long nwg = (long)gridDim.x * gridDim.y * gridDim.z;
    long swz = (wg & 7) * (nwg >> 3) + (wg >> 3);
    const int bx = (int)(swz % gridDim.x);
    long rem = swz / gridDim.x;
    const int by = (int)(rem % gridDim.y);
    const long bz = rem / gridDim.y;

    const long mbase = (long)by << 7;
    const long nbase = (long)bx << 7;
    const int  t    = threadIdx.x;
    const int  wave = t >> 6, lane = t & 63;
    const int  wr = (wave >> 1) << 6;
    const int  wc = (wave & 1)  << 6;
    const int  fr = lane & 15;
    const int  kg = lane >> 4;

    const ush* Ah = A0 + bz * sAz;
    const ush* Bh = B0 + bz * sBz;

    f32x4 acc[4][4] = {};

    for (int k0 = 0; k0 < K; k0 += 32) {
        #pragma unroll
        for (int i = 0; i < 2; ++i) {
            int rl = (wave << 5) + (i << 4) + (lane >> 2);
            int cs = ((lane & 3) ^ ((rl >> 1) & 3)) << 3;
            long goA = (mbase + rl) * (long)lda + k0 + cs;
            long goB = (nbase + rl) * (long)ldb + k0 + cs;
            glds16(Ah + goA, &aHi[(wave << 10) + (i << 9)]);
            if constexpr (AM == 1) {
                const ush* Al_ = A1 + bz * sAz;
                glds16(Al_ + goA, &aLo[(wave << 10) + (i << 9)]);
            }
            glds16(Bh + goB, &bHi[(wave << 10) + (i << 9)]);
            if constexpr (AM != 3) {
                const ush* Bl_ = B1 + bz * sBz;
                glds16(Bl_ + goB, &bLo[(wave << 10) + (i << 9)]);
            }
        }
        __syncthreads();

        bf16x8 ah[4], al[4], bh[4], bl[4];
        #pragma unroll
        for (int i = 0; i < 4; ++i) {
            int ra = wr + (i << 4) + fr, rb = wc + (i << 4) + fr;
            ah[i] = *(const bf16x8*)(aHi + (swzb(ra, kg << 4) >> 1));
            if constexpr (AM == 1)
                al[i] = *(const bf16x8*)(aLo + (swzb(ra, kg << 4) >> 1));
            bh[i] = *(const bf16x8*)(bHi + (swzb(rb, kg << 4) >> 1));
            if constexpr (AM != 3)
                bl[i] = *(const bf16x8*)(bLo + (swzb(rb, kg << 4) >> 1));
        }
        #pragma unroll
        for (int i = 0; i < 4; ++i) {
            #pragma unroll
            for (int j = 0; j < 4; ++j) {
                acc[i][j] = __builtin_amdgcn_mfma_f32_16x16x32_bf16(ah[i], bh[j], acc[i][j], 0, 0, 0);
                if constexpr (AM != 3)
                    acc[i][j] = __builtin_amdgcn_mfma_f32_16x16x32_bf16(ah[i], bl[j], acc[i][j], 0, 0, 0);
                if constexpr (AM == 1)
                    acc[i][j] = __builtin_amdgcn_mfma_f32_16x16x32_bf16(al[i], bh[j], acc[i][j], 0, 0, 0);
            }
        }
        __syncthreads();
    }

    {
        float* Cb = C + bz * sCz;
        #pragma unroll
        for (int i = 0; i < 4; ++i) {
            #pragma unroll
            for (int q = 0; q < 4; ++q) {
                long grow = mbase + wr + (i << 4) + (kg << 2) + q;
                float scale = 1.0f;
                if constexpr (EPI == 3)
                    scale = 1.0f / (ml + bz * 2048L * 1024)[grow * 1024 + 1];
                float* crow = Cb + grow * (long)ldc + nbase + wc + fr;
                #pragma unroll
                for (int j = 0; j < 4; ++j) {
                    if constexpr (EPI == 2)      crow[j << 4] = crow[j << 4] + acc[i][j][q];
                    else if constexpr (EPI == 3) crow[j << 4] = (crow[j << 4] + acc[i][j][q]) * scale;
                    else                         crow[j << 4] = acc[i][j][q];
                }
            }
        }
    }
}

// ---------- bias + LayerNorm + ReLU; OUT: 0=fp32, 1=hi/lo bf16, 2=bf16 ----------
template<int NC, int OUT>
__global__ void ln_relu_kernel(const float* __restrict__ Y, int ldy,
                               const float* __restrict__ bias,
                               const float* __restrict__ g, const float* __restrict__ beta,
                               float* __restrict__ outf, ush* __restrict__ oh,
                               ush* __restrict__ ol, int ldo)
{
    constexpr int PER = NC / 256;
    long row = blockIdx.x;
    const float* yr = Y + row * (long)ldy;
    int t = threadIdx.x;
    float v[PER]; float s = 0.f, s2 = 0.f;
    #pragma unroll
    for (int i = 0; i < PER; ++i) {
        int c = t + (i << 8);
        float x = yr[c] + bias[c];
        v[i] = x; s += x; s2 += x * x;
    }
    s = wave_sum(s); s2 = wave_sum(s2);
    __shared__ float ra[4], rb[4];
    int w = t >> 6, l = t & 63;
    if (!l) { ra[w] = s; rb[w] = s2; }
    __syncthreads();
    s  = ra[0] + ra[1] + ra[2] + ra[3];
    s2 = rb[0] + rb[1] + rb[2] + rb[3];
    float mu  = s * (1.0f / NC);
    float var = s2 * (1.0f / NC) - mu * mu;
    float inv = rsqrtf(var + 1e-5f);
    #pragma unroll
    for (int i = 0; i < PER; ++i) {
        int c = t + (i << 8);
        float x = (v[i] - mu) * inv * g[c] + beta[c];
        x = fmaxf(x, 0.0f);
        if constexpr (OUT == 1) {
            ush h = f2bf_rne(x);
            ush lo = f2bf_rne(x - __uint_as_float((unsigned)h << 16));
            oh[row * (long)ldo + c] = h;
            ol[row * (long)ldo + c] = lo;
        } else if constexpr (OUT == 2) {
            oh[row * (long)ldo + c] = f2bf_rne(x);
        } else {
            outf[row * (long)ldo + c] = x;
        }
    }
}

// ---------- fp32 -> hi/lo bf16 split (flat) ----------
__global__ void split_kernel(const float* __restrict__ in, ush* __restrict__ h,
                             ush* __restrict__ l, long n)
{
    long i = ((long)blockIdx.x * 256 + threadIdx.x) * 4;
    if (i >= n) return;
    float4 v = *(const float4*)(in + i);
    ushort4 hh, ll;
    hh.x = f2bf_rne(v.x); ll.x = f2bf_rne(v.x - __uint_as_float((unsigned)hh.x << 16));
    hh.y = f2bf_rne(v.y); ll.y = f2bf_rne(v.y - __uint_as_float((unsigned)hh.y << 16));
    hh.z = f2bf_rne(v.z); ll.z = f2bf_rne(v.z - __uint_as_float((unsigned)hh.z << 16));
    hh.w = f2bf_rne(v.w); ll.w = f2bf_rne(v.w - __uint_as_float((unsigned)hh.w << 16));
    *(ushort4*)(h + i) = hh;
    *(ushort4*)(l + i) = ll;
}

// ---------- per-batch transpose [2048,512] -> [512,2048], single bf16 ----------
__global__ void transpose_split_kernel(const float* __restrict__ in,
                                       ush* __restrict__ oh)
{
    __shared__ float tile[32][33];
    long bz = blockIdx.z;
    const float* I = in + bz * (long)NN * HH;
    ush* OH = oh + bz * (long)HH * NN;
    int c0 = blockIdx.x << 5, r0 = blockIdx.y << 5;
    int tx = threadIdx.x & 31, ty = threadIdx.x >> 5;   // 32 x 8
    #pragma unroll
    for (int i = 0; i < 32; i += 8)
        tile[ty + i][tx] = I[(long)(r0 + ty + i) * HH + c0 + tx];
    __syncthreads();
    #pragma unroll
    for (int i = 0; i < 32; i += 8) {
        float x = tile[tx][ty + i];
        long o = (long)(c0 + ty + i) * NN + r0 + tx;
        OH[o] = f2bf_rne(x);
    }
}

// ---------- exp pass over slab-0 scores (S at out[:,0:512], ml at cols 0,1) ----------
__global__ void exp_pass_kernel(float* __restrict__ ml, ush* __restrict__ P)
{
    long row = blockIdx.x;               // 0..16383
    float* sr = ml + row * 1024;
    int t = threadIdx.x;
    float s0 = sr[t], s1 = sr[t + 256];
    float m = fmaxf(s0, s1);
    m = wave_max(m);
    __shared__ float ra[4], rb[4];
    int w = t >> 6, l = t & 63;
    if (!l) ra[w] = m;
    __syncthreads();
    m = fmaxf(fmaxf(ra[0], ra[1]), fmaxf(ra[2], ra[3]));
    float p0 = __expf(s0 - m), p1 = __expf(s1 - m);
    ush h0 = f2bf_rne(p0), h1 = f2bf_rne(p1);
    P[row * 512 + t] = h0;
    P[row * 512 + t + 256] = h1;
    float ls = bf2f(h0) + bf2f(h1);
    ls = wave_sum(ls);
    if (!l) rb[w] = ls;
    __syncthreads();
    if (t == 0) {
        sr[0] = m;
        sr[1] = rb[0] + rb[1] + rb[2] + rb[3];
    }
}

// ---------- expand parked v2 bf16 -> out[:, 0:512] fp32 ----------
__global__ void expand_v2_kernel(const ush* __restrict__ v2b, float* __restrict__ o)
{
    long row = blockIdx.x;
    const ush* s = v2b + row * 512;
    float* d = o + row * 1024;
    int t = threadIdx.x;
    d[t] = bf2f(s[t]);
    d[t + 256] = bf2f(s[t + 256]);
}

// ---------- launch ----------
extern "C" void kernel_launch(void* const* d_in, const int* in_sizes, int n_in,
                              void* d_out, int out_size, void* d_ws, size_t ws_size,
                              hipStream_t stream)
{
    const float* sgm   = (const float*)d_in[0];
    const float* velo  = (const float*)d_in[1];
    const float* Wq    = (const float*)d_in[2];
    const float* bq    = (const float*)d_in[3];
    const float* gq    = (const float*)d_in[4];
    const float* betaq = (const float*)d_in[5];
    const float* Wk    = (const float*)d_in[6];
    const float* bk    = (const float*)d_in[7];
    const float* gk    = (const float*)d_in[8];
    const float* betak = (const float*)d_in[9];
    const float* Wv1   = (const float*)d_in[10];
    const float* bv1   = (const float*)d_in[11];
    const float* gv1   = (const float*)d_in[12];
    const float* betav1= (const float*)d_in[13];
    const float* Wv2   = (const float*)d_in[14];
    const float* bv2   = (const float*)d_in[15];
    const float* gv2   = (const float*)d_in[16];
    const float* betav2= (const float*)d_in[17];
    float* out = (float*)d_out;
    char*  wsb = (char*)d_ws;

    if (ws_size < 176 * MiB) return;   // proven >= 176 MiB in round 3

    // ws layout: x/q 64 | k 64 | v1t 16 | v2b 16 | {W splits 12 -> P 16}
    ush* xh   = (ush*)wsb;
    ush* xl   = (ush*)(wsb + 32 * MiB);
    ush* kh   = (ush*)(wsb + 64 * MiB);
    ush* kl   = (ush*)(wsb + 96 * MiB);
    ush* v1th = (ush*)(wsb + 128 * MiB);
    ush* v2b  = (ush*)(wsb + 144 * MiB);
    ush* Wqh  = (ush*)(wsb + 160 * MiB);
    ush* Wql  = (ush*)(wsb + 162 * MiB);
    ush* Wkh  = (ush*)(wsb + 164 * MiB);
    ush* Wkl  = (ush*)(wsb + 166 * MiB);
    ush* Wv1h = (ush*)(wsb + 168 * MiB);
    ush* Wv1l = (ush*)(wsb + 169 * MiB);
    ush* Wv2h = (ush*)(wsb + 170 * MiB);
    ush* Wv2l = (ush*)(wsb + 171 * MiB);
    ush* P    = (ush*)(wsb + 160 * MiB);
    float* v1f = out + 8388608L;       // out bytes [32..64) MiB

    dim3 blk(256);

    split_kernel<<<1024, blk, 0, stream>>>(Wq,  Wqh,  Wql,  (long)CC_*DD);
    split_kernel<<<1024, blk, 0, stream>>>(Wk,  Wkh,  Wkl,  (long)CC_*DD);
    split_kernel<<<512,  blk, 0, stream>>>(Wv1, Wv1h, Wv1l, (long)HH*DD);
    split_kernel<<<512,  blk, 0, stream>>>(Wv2, Wv2h, Wv2l, (long)HH*DD);

    // --- velo-derived: k, v1 ---
    split_kernel<<<16384, blk, 0, stream>>>(velo, xh, xl, (long)RR*DD);
    gemm8p_kernel<<<dim3(4, 64), dim3(512), 0, stream>>>(xh, xl, Wkh, Wkl, out, CC_);
    ln_relu_kernel<1024,1><<<RR, blk, 0, stream>>>(out, CC_, bk, gk, betak, nullptr, kh, kl, CC_);
    gemm8q_kernel<0><<<dim3(4, 64, 1), dim3(512), 0, stream>>>(
        xh, xl, Wv1h, Wv1l, out, nullptr, nullptr, HH);
    ln_relu_kernel<512,0><<<RR, blk, 0, stream>>>(out, HH, bv1, gv1, betav1, v1f, nullptr, nullptr, HH);
    transpose_split_kernel<<<dim3(16,64,BB), blk, 0, stream>>>(v1f, v1th);

    // --- sgm-derived: v2 (parked bf16), then q ---
    split_kernel<<<16384, blk, 0, stream>>>(sgm, xh, xl, (long)RR*DD);
    gemm8q_kernel<0><<<dim3(4, 64, 1), dim3(512), 0, stream>>>(
        xh, xl, Wv2h, Wv2l, out, nullptr, nullptr, HH);
    ln_relu_kernel<512,2><<<RR, blk, 0, stream>>>(out, HH, bv2, gv2, betav2, nullptr, v2b, nullptr, HH);
    gemm8p_kernel<<<dim3(4, 64), dim3(512), 0, stream>>>(xh, xl, Wqh, Wql, out, CC_);
    ln_relu_kernel<1024,1><<<RR, blk, 0, stream>>>(out, CC_, bq, gq, betaq, nullptr, xh, xl, CC_);

    // --- attention (4 key-slabs of 512); S-slab0 + ml in out[:, 0:512] ---
    gemm8q_kernel<0><<<dim3(4, 8, 8), dim3(512), 0, stream>>>(
        xh, xl, kh, kl, out, nullptr, nullptr, 1024);
    exp_pass_kernel<<<RR, blk, 0, stream>>>(out, P);
    gemm3_kernel<3,0><<<dim3(4,16,8), blk, 0, stream>>>(
        P, nullptr, v1th, nullptr, out + HH, nullptr, nullptr,
        512, 512, NN, CC_, 2048L*512, 512L*2048, 2048L*1024, 0);
    for (int s = 1; s < 4; ++s) {
        gemm8q_kernel<1><<<dim3(4, 8, 8), dim3(512), 0, stream>>>(
            xh, xl, kh + (long)s*512*1024, kl + (long)s*512*1024,
            nullptr, P, out, 0);
        if (s < 3)
            gemm3_kernel<3,2><<<dim3(4,16,8), blk, 0, stream>>>(
                P, nullptr, v1th + s*512, nullptr,
                out + HH, nullptr, nullptr, 512, 512, NN, CC_,
                2048L*512, 512L*2048, 2048L*1024, 0);
        else
            gemm3_kernel<3,3><<<dim3(4,16,8), blk, 0, stream>>>(
                P, nullptr, v1th + s*512, nullptr,
                out + HH, nullptr, out, 512, 512, NN, CC_,
                2048L*512, 512L*2048, 2048L*1024, 0);
    }

    // --- v2 expand into out[:, 0:512] (after PV-3 consumed ml) ---
    expand_v2_kernel<<<RR, blk, 0, stream>>>(v2b, out);
}

// Round 21
// 772.109 us; speedup vs baseline: 2.7335x; 1.0162x over previous
//
#include <hip/hip_runtime.h>
#include <hip/hip_bf16.h>

// B=8, N=2048, D=1024, C=1024, H=512 (fp32 in/out)
//  q = LNReLU(sgm@Wq^T+bq); k = LNReLU(velo@Wk^T+bk)
//  S = q k^T; P = softmax(S); v1 = LNReLU(velo@Wv1^T); v2 = LNReLU(sgm@Wv2^T)
//  out = concat(v2, P@v1)
//
// Round 21 (round 20 = 785us, absmax 0.03125): PV moved onto the 8-phase
// template — gemm8q gains MODE=1 (single-bf16 A/B, NT=8, lda/ldb params) and
// EPI=2 (+=) / EPI=3 ((C+acc)/l) epilogues. gemm3 retired. Everything else
// identical to round 20.

#define BB 8
#define NN 2048
#define DD 1024
#define CC_ 1024
#define HH 512
#define RR (BB*NN)   // 16384 rows

typedef unsigned short ush;
typedef short bf16x8 __attribute__((ext_vector_type(8)));
typedef float f32x4  __attribute__((ext_vector_type(4)));

#define MiB (1024L*1024L)

// ---------- helpers ----------
__device__ __forceinline__ ush f2bf_rne(float x) {
    unsigned u = __float_as_uint(x);
    return (ush)((u + 0x7fffu + ((u >> 16) & 1u)) >> 16);
}
__device__ __forceinline__ float bf2f(ush h) {
    return __uint_as_float((unsigned)h << 16);
}
__device__ __forceinline__ float wave_sum(float v) {
    #pragma unroll
    for (int o = 32; o; o >>= 1) v += __shfl_down(v, o);
    return v;
}
__device__ __forceinline__ float wave_max(float v) {
    #pragma unroll
    for (int o = 32; o; o >>= 1) v = fmaxf(v, __shfl_down(v, o));
    return v;
}

// async global->LDS, 16B/lane. LDS dest wave-uniform base + lane*16;
// global src per-lane (pre-swizzled so linear LDS holds swizzled layout).
__device__ __forceinline__ void glds16(const void* g, void* l) {
    __builtin_amdgcn_global_load_lds(
        (const __attribute__((address_space(1))) unsigned*)g,
        (__attribute__((address_space(3))) unsigned*)l, 16, 0, 0);
}

// ---------- 8-phase 256x256 bf16 GEMM for the two N=1024 linears ----------
__global__ __launch_bounds__(512, 2)
void gemm8p_kernel(const ush* __restrict__ Ah, const ush* __restrict__ Al,
                   const ush* __restrict__ Bh, const ush* __restrict__ Bl,
                   float* __restrict__ C, int ldc)
{
    __shared__ ush L[65536];   // 128 KiB
    constexpr int NT = 48;     // K' / 64

    int nwg = gridDim.x * gridDim.y;
    int wg  = blockIdx.x + gridDim.x * blockIdx.y;
    int sz  = (wg & 7) * (nwg >> 3) + (wg >> 3);
    int bx  = sz % gridDim.x, by = sz / gridDim.x;
    const long brow = (long)by << 8, bcol = (long)bx << 8;

    const int t = threadIdx.x, wid = t >> 6, lane = t & 63;
    const int wr = (wid >> 2) << 7;
    const int wc = (wid & 3) << 6;
    const int fr = lane & 15, kg = lane >> 4;

    const int srow = ((wid >> 1) << 4) + (lane >> 2);
    const int scol = ((wid & 1) << 5) + ((((lane & 3) << 3)) ^ ((lane >> 5) << 4));
    const int sdst = wid << 9;

    const int cterm = (fr << 5) + ((kg << 3) ^ ((fr >> 3) << 4));
    const int ha13  = (wr >> 7) << 13;
    const int bbase = 16384 + ((wc >> 7) << 13);
    const int sb0   = (wc & 64) >> 4;

    f32x4 acc[8][4] = {};
    bf16x8 bfrag[4][2];

    auto stage = [&](int X, int half) {   // half: 0=A0 1=A1 2=B0 3=B1
        if (X >= NT) return;
        int pI = X >> 4, kc = (X & 15) << 6;
        const ush* s; long rb;
        if (half < 2) { s = (pI == 1) ? Al : Ah; rb = brow + ((long)(half & 1) << 7); }
        else          { s = (pI == 2) ? Bl : Bh; rb = bcol + ((long)(half & 1) << 7); }
        int lb = ((X & 1) << 15) + ((half >> 1) << 14) + ((half & 1) << 13) + sdst;
        glds16(s + (rb + srow) * 1024 + kc + scol,      &L[lb]);
        glds16(s + (rb + srow + 64) * 1024 + kc + scol, &L[lb + 4096]);
    };

    stage(0, 0); stage(0, 1); stage(0, 2); stage(0, 3);
    stage(1, 2); stage(1, 3);
    asm volatile("s_waitcnt vmcnt(4)");
    __builtin_amdgcn_sched_barrier(0);
    __builtin_amdgcn_s_barrier();

    for (int kt = 0; kt < NT; ++kt) {
        const int ab = (kt & 1) << 15;
        #pragma unroll
        for (int p = 0; p < 4; ++p) {
            bf16x8 afrag[2][2];
            #pragma unroll
            for (int ii = 0; ii < 2; ++ii)
                #pragma unroll
                for (int ks = 0; ks < 2; ++ks)
                    afrag[ii][ks] = *(const bf16x8*)&L[ab + ha13 +
                        ((((2 * p + ii) << 1) | ks) << 9) + cterm];
            if (p == 0) {
                #pragma unroll
                for (int fj = 0; fj < 4; ++fj)
                    #pragma unroll
                    for (int ks = 0; ks < 2; ++ks)
                        bfrag[fj][ks] = *(const bf16x8*)&L[ab + bbase +
                            ((((sb0 + fj) << 1) | ks) << 9) + cterm];
            }
            if      (p == 0) stage(kt + 1, 0);
            else if (p == 1) stage(kt + 1, 1);
            else if (p == 2) stage(kt + 2, 2);
            else             stage(kt + 2, 3);

            __builtin_amdgcn_s_barrier();
            asm volatile("s_waitcnt lgkmcnt(0)");
            __builtin_amdgcn_sched_barrier(0);
            __builtin_amdgcn_s_setprio(1);
            #pragma unroll
            for (int ii = 0; ii < 2; ++ii)
                #pragma unroll
                for (int fj = 0; fj < 4; ++fj)
                    #pragma unroll
                    for (int ks = 0; ks < 2; ++ks)
                        acc[2 * p + ii][fj] = __builtin_amdgcn_mfma_f32_16x16x32_bf16(
                            afrag[ii][ks], bfrag[fj][ks], acc[2 * p + ii][fj], 0, 0, 0);
            __builtin_amdgcn_s_setprio(0);
            if (p == 3) {
                if (kt < NT - 2) asm volatile("s_waitcnt vmcnt(4)");
                else             asm volatile("s_waitcnt vmcnt(0)");
                __builtin_amdgcn_sched_barrier(0);
            }
            __builtin_amdgcn_s_barrier();
        }
    }

    #pragma unroll
    for (int fi = 0; fi < 8; ++fi)
        #pragma unroll
        for (int q = 0; q < 4; ++q) {
            long grow = brow + wr + fi * 16 + (kg << 2) + q;
            float* cr = C + grow * (long)ldc + bcol + wc + fr;
            #pragma unroll
            for (int fj = 0; fj < 4; ++fj) cr[fj << 4] = acc[fi][fj][q];
        }
}

// ---------- 8p-structure 256x128 batched GEMM ----------
// MODE=0: 3-pass K'=3K hi/lo (lda=ldb=1024). MODE=1: single bf16, NT=8 (PV).
// EPI=0: store C fp32 at ldc. EPI=1: P=exp(s-m) bf16 + atomicAdd l.
// EPI=2: C += acc. EPI=3: C = (C+acc)/l.
template<int EPI, int MODE>
__global__ __launch_bounds__(512, 2)
void gemm8q_kernel(const ush* __restrict__ Ah, const ush* __restrict__ Al,
                   const ush* __restrict__ Bh, const ush* __restrict__ Bl,
                   float* __restrict__ C, ush* __restrict__ Pout,
                   float* __restrict__ ml, int ldc, int lda, int ldb,
                   long sAz, long sBz)
{
    __shared__ ush L[49152];   // 96 KiB
    constexpr int NT = MODE ? 8 : 48;

    long nwg = (long)gridDim.x * gridDim.y * gridDim.z;
    long wg  = (long)blockIdx.x + gridDim.x * ((long)blockIdx.y + (long)gridDim.y * blockIdx.z);
    long sz  = (wg & 7) * (nwg >> 3) + (wg >> 3);
    const int bx = (int)(sz % gridDim.x);
    long rem = sz / gridDim.x;
    const int by = (int)(rem % gridDim.y);
    const long bz = rem / gridDim.y;

    const long brow = (long)by << 8;
    const long bcol = (long)bx << 7;

    const int t = threadIdx.x, wid = t >> 6, lane = t & 63;
    const int wr4 = wid >> 1;
    const int wc2 = wid & 1;
    const int fr = lane & 15, kg = lane >> 4;

    const int srow = ((wid >> 1) << 4) + (lane >> 2);
    const int scol = ((wid & 1) << 5) + (((lane & 3) << 3) ^ ((lane >> 5) << 4));
    const int sdst = wid << 9;

    const int cterm = (fr << 5) + ((kg << 3) ^ ((fr >> 3) << 4));

    const ush* qh = Ah + bz * sAz;
    const ush* ql = (MODE == 0) ? Al + bz * sAz : nullptr;
    const ush* kh = Bh + bz * sBz;
    const ush* kl = (MODE == 0) ? Bl + bz * sBz : nullptr;

    f32x4 acc[4][4] = {};
    bf16x8 bfrag[4][2];

    auto stageA = [&](int X, int c) {
        if (X >= NT) return;
        int kc = (X & 15) << 6;
        const ush* s = (MODE == 0 && (X >> 4) == 1) ? ql : qh;
        glds16(s + (brow + c * 64 + srow) * (long)lda + kc + scol,
               &L[((X & 1) ? 24576 : 0) + ((c * 8) << 9) + sdst]);
    };
    auto stageB = [&](int X, int c) {
        if (X >= NT) return;
        int kc = (X & 15) << 6;
        const ush* s = (MODE == 0 && (X >> 4) == 2) ? kl : kh;
        glds16(s + (bcol + c * 64 + srow) * (long)ldb + kc + scol,
               &L[((X & 1) ? 24576 : 0) + 16384 + ((c * 8) << 9) + sdst]);
    };

    stageA(0, 0); stageA(0, 1); stageA(0, 2); stageA(0, 3);
    stageB(0, 0); stageB(0, 1);
    stageB(1, 0); stageB(1, 1);
    asm volatile("s_waitcnt vmcnt(2)");
    __builtin_amdgcn_sched_barrier(0);
    __builtin_amdgcn_s_barrier();

    for (int kt = 0; kt < NT; ++kt) {
        const int ab = (kt & 1) ? 24576 : 0;
        #pragma unroll
        for (int p = 0; p < 2; ++p) {
            bf16x8 afrag[2][2];
            #pragma unroll
            for (int ii = 0; ii < 2; ++ii)
                #pragma unroll
                for (int ks = 0; ks < 2; ++ks) {
                    int fi = 2 * p + ii;
                    int sA = (wr4 * 4 + fi) * 2 + ks;
                    afrag[ii][ks] = *(const bf16x8*)&L[ab + (sA << 9) + cterm];
                }
            if (p == 0) {
                #pragma unroll
                for (int fj = 0; fj < 4; ++fj)
                    #pragma unroll
                    for (int ks = 0; ks < 2; ++ks) {
                        int sB = (wc2 * 4 + fj) * 2 + ks;
                        bfrag[fj][ks] = *(const bf16x8*)&L[ab + 16384 + (sB << 9) + cterm];
                    }
                stageA(kt + 1, 0); stageA(kt + 1, 1); stageA(kt + 1, 2);
            } else {
                stageA(kt + 1, 3); stageB(kt + 2, 0); stageB(kt + 2, 1);
            }

            __builtin_amdgcn_s_barrier();
            asm volatile("s_waitcnt lgkmcnt(0)");
            __builtin_amdgcn_sched_barrier(0);
            __builtin_amdgcn_s_setprio(1);
            #pragma unroll
            for (int ii = 0; ii < 2; ++ii)
                #pragma unroll
                for (int fj = 0; fj < 4; ++fj)
                    #pragma unroll
                    for (int ks = 0; ks < 2; ++ks)
                        acc[2 * p + ii][fj] = __builtin_amdgcn_mfma_f32_16x16x32_bf16(
                            afrag[ii][ks], bfrag[fj][ks], acc[2 * p + ii][fj], 0, 0, 0);
            __builtin_amdgcn_s_setprio(0);
            if (p == 1) {
                if (kt < NT - 2) asm volatile("s_waitcnt vmcnt(2)");
                else             asm volatile("s_waitcnt vmcnt(0)");
                __builtin_amdgcn_sched_barrier(0);
            }
            __builtin_amdgcn_s_barrier();
        }
    }

    // C/D layout (m89): col = lane&15, row = (lane>>4)*4 + reg
    if constexpr (EPI == 1) {
        ush*   Pb  = Pout + bz * 2048L * 512;
        float* mlb = ml + bz * 2048L * 1024;
        #pragma unroll
        for (int fi = 0; fi < 4; ++fi) {
            #pragma unroll
            for (int q = 0; q < 4; ++q) {
                long grow = brow + wr4 * 64 + fi * 16 + (kg << 2) + q;
                float m = mlb[grow * 1024];
                float rs = 0.f;
                #pragma unroll
                for (int fj = 0; fj < 4; ++fj) {
                    float pv = __expf(acc[fi][fj][q] - m);
                    rs += pv;
                    Pb[grow * 512 + bcol + wc2 * 64 + fj * 16 + fr] = f2bf_rne(pv);
                }
                rs += __shfl_xor(rs, 1); rs += __shfl_xor(rs, 2);
                rs += __shfl_xor(rs, 4); rs += __shfl_xor(rs, 8);
                if (fr == 0) atomicAdd(&mlb[grow * 1024 + 1], rs);
            }
        }
    } else {
        float* Cb = C + bz * 2048L * 1024;
        #pragma unroll
        for (int fi = 0; fi < 4; ++fi)
            #pragma unroll
            for (int q = 0; q < 4; ++q) {
                long grow = brow + wr4 * 64 + fi * 16 + (kg << 2) + q;
                float scale = 1.0f;
                if constexpr (EPI == 3)
                    scale = 1.0f / (ml + bz * 2048L * 1024)[grow * 1024 + 1];
                float* cr = Cb + grow * (long)ldc + bcol + wc2 * 64 + fr;
                #pragma unroll
                for (int fj = 0; fj < 4; ++fj) {
                    if constexpr (EPI == 2)      cr[fj << 4] = cr[fj << 4] + acc[fi][fj][q];
                    else if constexpr (EPI == 3) cr[fj << 4] = (cr[fj << 4] + acc[fi][fj][q]) * scale;
                    else                         cr[fj << 4] = acc[fi][fj][q];
                }
            }
    }
}

// ---------- bias + LayerNorm + ReLU; OUT: 0=fp32, 1=hi/lo bf16, 2=bf16 ----------
template<int NC, int OUT>
__global__ void ln_relu_kernel(const float* __restrict__ Y, int ldy,
                               const float* __restrict__ bias,
                               const float* __restrict__ g, const float* __restrict__ beta,
                               float* __restrict__ outf, ush* __restrict__ oh,
                               ush* __restrict__ ol, int ldo)
{
    constexpr int PER = NC / 256;
    long row = blockIdx.x;
    const float* yr = Y + row * (long)ldy;
    int t = threadIdx.x;
    float v[PER]; float s = 0.f, s2 = 0.f;
    #pragma unroll
    for (int i = 0; i < PER; ++i) {
        int c = t + (i << 8);
        float x = yr[c] + bias[c];
        v[i] = x; s += x; s2 += x * x;
    }
    s = wave_sum(s); s2 = wave_sum(s2);
    __shared__ float ra[4], rb[4];
    int w = t >> 6, l = t & 63;
    if (!l) { ra[w] = s; rb[w] = s2; }
    __syncthreads();
    s  = ra[0] + ra[1] + ra[2] + ra[3];
    s2 = rb[0] + rb[1] + rb[2] + rb[3];
    float mu  = s * (1.0f / NC);
    float var = s2 * (1.0f / NC) - mu * mu;
    float inv = rsqrtf(var + 1e-5f);
    #pragma unroll
    for (int i = 0; i < PER; ++i) {
        int c = t + (i << 8);
        float x = (v[i] - mu) * inv * g[c] + beta[c];
        x = fmaxf(x, 0.0f);
        if constexpr (OUT == 1) {
            ush h = f2bf_rne(x);
            ush lo = f2bf_rne(x - __uint_as_float((unsigned)h << 16));
            oh[row * (long)ldo + c] = h;
            ol[row * (long)ldo + c] = lo;
        } else if constexpr (OUT == 2) {
            oh[row * (long)ldo + c] = f2bf_rne(x);
        } else {
            outf[row * (long)ldo + c] = x;
        }
    }
}

// ---------- fp32 -> hi/lo bf16 split (flat) ----------
__global__ void split_kernel(const float* __restrict__ in, ush* __restrict__ h,
                             ush* __restrict__ l, long n)
{
    long i = ((long)blockIdx.x * 256 + threadIdx.x) * 4;
    if (i >= n) return;
    float4 v = *(const float4*)(in + i);
    ushort4 hh, ll;
    hh.x = f2bf_rne(v.x); ll.x = f2bf_rne(v.x - __uint_as_float((unsigned)hh.x << 16));
    hh.y = f2bf_rne(v.y); ll.y = f2bf_rne(v.y - __uint_as_float((unsigned)hh.y << 16));
    hh.z = f2bf_rne(v.z); ll.z = f2bf_rne(v.z - __uint_as_float((unsigned)hh.z << 16));
    hh.w = f2bf_rne(v.w); ll.w = f2bf_rne(v.w - __uint_as_float((unsigned)hh.w << 16));
    *(ushort4*)(h + i) = hh;
    *(ushort4*)(l + i) = ll;
}

// ---------- per-batch transpose [2048,512] -> [512,2048], single bf16 ----------
__global__ void transpose_split_kernel(const float* __restrict__ in,
                                       ush* __restrict__ oh)
{
    __shared__ float tile[32][33];
    long bz = blockIdx.z;
    const float* I = in + bz * (long)NN * HH;
    ush* OH = oh + bz * (long)HH * NN;
    int c0 = blockIdx.x << 5, r0 = blockIdx.y << 5;
    int tx = threadIdx.x & 31, ty = threadIdx.x >> 5;   // 32 x 8
    #pragma unroll
    for (int i = 0; i < 32; i += 8)
        tile[ty + i][tx] = I[(long)(r0 + ty + i) * HH + c0 + tx];
    __syncthreads();
    #pragma unroll
    for (int i = 0; i < 32; i += 8) {
        float x = tile[tx][ty + i];
        long o = (long)(c0 + ty + i) * NN + r0 + tx;
        OH[o] = f2bf_rne(x);
    }
}

// ---------- exp pass over slab-0 scores (S at out[:,0:512], ml at cols 0,1) ----------
__global__ void exp_pass_kernel(float* __restrict__ ml, ush* __restrict__ P)
{
    long row = blockIdx.x;               // 0..16383
    float* sr = ml + row * 1024;
    int t = threadIdx.x;
    float s0 = sr[t], s1 = sr[t + 256];
    float m = fmaxf(s0, s1);
    m = wave_max(m);
    __shared__ float ra[4], rb[4];
    int w = t >> 6, l = t & 63;
    if (!l) ra[w] = m;
    __syncthreads();
    m = fmaxf(fmaxf(ra[0], ra[1]), fmaxf(ra[2], ra[3]));
    float p0 = __expf(s0 - m), p1 = __expf(s1 - m);
    ush h0 = f2bf_rne(p0), h1 = f2bf_rne(p1);
    P[row * 512 + t] = h0;
    P[row * 512 + t + 256] = h1;
    float ls = bf2f(h0) + bf2f(h1);
    ls = wave_sum(ls);
    if (!l) rb[w] = ls;
    __syncthreads();
    if (t == 0) {
        sr[0] = m;
        sr[1] = rb[0] + rb[1] + rb[2] + rb[3];
    }
}

// ---------- expand parked v2 bf16 -> out[:, 0:512] fp32 ----------
__global__ void expand_v2_kernel(const ush* __restrict__ v2b, float* __restrict__ o)
{
    long row = blockIdx.x;
    const ush* s = v2b + row * 512;
    float* d = o + row * 1024;
    int t = threadIdx.x;
    d[t] = bf2f(s[t]);
    d[t + 256] = bf2f(s[t + 256]);
}

// ---------- launch ----------
extern "C" void kernel_launch(void* const* d_in, const int* in_sizes, int n_in,
                              void* d_out, int out_size, void* d_ws, size_t ws_size,
                              hipStream_t stream)
{
    const float* sgm   = (const float*)d_in[0];
    const float* velo  = (const float*)d_in[1];
    const float* Wq    = (const float*)d_in[2];
    const float* bq    = (const float*)d_in[3];
    const float* gq    = (const float*)d_in[4];
    const float* betaq = (const float*)d_in[5];
    const float* Wk    = (const float*)d_in[6];
    const float* bk    = (const float*)d_in[7];
    const float* gk    = (const float*)d_in[8];
    const float* betak = (const float*)d_in[9];
    const float* Wv1   = (const float*)d_in[10];
    const float* bv1   = (const float*)d_in[11];
    const float* gv1   = (const float*)d_in[12];
    const float* betav1= (const float*)d_in[13];
    const float* Wv2   = (const float*)d_in[14];
    const float* bv2   = (const float*)d_in[15];
    const float* gv2   = (const float*)d_in[16];
    const float* betav2= (const float*)d_in[17];
    float* out = (float*)d_out;
    char*  wsb = (char*)d_ws;

    if (ws_size < 176 * MiB) return;   // proven >= 176 MiB in round 3

    // ws layout: x/q 64 | k 64 | v1t 16 | v2b 16 | {W splits 12 -> P 16}
    ush* xh   = (ush*)wsb;
    ush* xl   = (ush*)(wsb + 32 * MiB);
    ush* kh   = (ush*)(wsb + 64 * MiB);
    ush* kl   = (ush*)(wsb + 96 * MiB);
    ush* v1th = (ush*)(wsb + 128 * MiB);
    ush* v2b  = (ush*)(wsb + 144 * MiB);
    ush* Wqh  = (ush*)(wsb + 160 * MiB);
    ush* Wql  = (ush*)(wsb + 162 * MiB);
    ush* Wkh  = (ush*)(wsb + 164 * MiB);
    ush* Wkl  = (ush*)(wsb + 166 * MiB);
    ush* Wv1h = (ush*)(wsb + 168 * MiB);
    ush* Wv1l = (ush*)(wsb + 169 * MiB);
    ush* Wv2h = (ush*)(wsb + 170 * MiB);
    ush* Wv2l = (ush*)(wsb + 171 * MiB);
    ush* P    = (ush*)(wsb + 160 * MiB);
    float* v1f = out + 8388608L;       // out bytes [32..64) MiB

    dim3 blk(256);
    const long SQ = 2048L * 1024;      // q/k batch stride
    const long SP = 2048L * 512;       // P / v1t batch stride

    split_kernel<<<1024, blk, 0, stream>>>(Wq,  Wqh,  Wql,  (long)CC_*DD);
    split_kernel<<<1024, blk, 0, stream>>>(Wk,  Wkh,  Wkl,  (long)CC_*DD);
    split_kernel<<<512,  blk, 0, stream>>>(Wv1, Wv1h, Wv1l, (long)HH*DD);
    split_kernel<<<512,  blk, 0, stream>>>(Wv2, Wv2h, Wv2l, (long)HH*DD);

    // --- velo-derived: k, v1 ---
    split_kernel<<<16384, blk, 0, stream>>>(velo, xh, xl, (long)RR*DD);
    gemm8p_kernel<<<dim3(4, 64), dim3(512), 0, stream>>>(xh, xl, Wkh, Wkl, out, CC_);
    ln_relu_kernel<1024,1><<<RR, blk, 0, stream>>>(out, CC_, bk, gk, betak, nullptr, kh, kl, CC_);
    gemm8q_kernel<0,0><<<dim3(4, 64, 1), dim3(512), 0, stream>>>(
        xh, xl, Wv1h, Wv1l, out, nullptr, nullptr, HH, 1024, 1024, SQ, SQ);
    ln_relu_kernel<512,0><<<RR, blk, 0, stream>>>(out, HH, bv1, gv1, betav1, v1f, nullptr, nullptr, HH);
    transpose_split_kernel<<<dim3(16,64,BB), blk, 0, stream>>>(v1f, v1th);

    // --- sgm-derived: v2 (parked bf16), then q ---
    split_kernel<<<16384, blk, 0, stream>>>(sgm, xh, xl, (long)RR*DD);
    gemm8q_kernel<0,0><<<dim3(4, 64, 1), dim3(512), 0, stream>>>(
        xh, xl, Wv2h, Wv2l, out, nullptr, nullptr, HH, 1024, 1024, SQ, SQ);
    ln_relu_kernel<512,2><<<RR, blk, 0, stream>>>(out, HH, bv2, gv2, betav2, nullptr, v2b, nullptr, HH);
    gemm8p_kernel<<<dim3(4, 64), dim3(512), 0, stream>>>(xh, xl, Wqh, Wql, out, CC_);
    ln_relu_kernel<1024,1><<<RR, blk, 0, stream>>>(out, CC_, bq, gq, betaq, nullptr, xh, xl, CC_);

    // --- attention (4 key-slabs of 512); S-slab0 + ml in out[:, 0:512] ---
    gemm8q_kernel<0,0><<<dim3(4, 8, 8), dim3(512), 0, stream>>>(
        xh, xl, kh, kl, out, nullptr, nullptr, 1024, 1024, 1024, SQ, SQ);
    exp_pass_kernel<<<RR, blk, 0, stream>>>(out, P);
    gemm8q_kernel<0,1><<<dim3(4, 8, 8), dim3(512), 0, stream>>>(
        P, nullptr, v1th, nullptr, out + HH, nullptr, nullptr,
        1024, 512, 2048, SP, SP);
    for (int s = 1; s < 4; ++s) {
        gemm8q_kernel<1,0><<<dim3(4, 8, 8), dim3(512), 0, stream>>>(
            xh, xl, kh + (long)s*512*1024, kl + (long)s*512*1024,
            nullptr, P, out, 0, 1024, 1024, SQ, SQ);
        if (s < 3)
            gemm8q_kernel<2,1><<<dim3(4, 8, 8), dim3(512), 0, stream>>>(
                P, nullptr, v1th + s*512, nullptr, out + HH, nullptr, nullptr,
                1024, 512, 2048, SP, SP);
        else
            gemm8q_kernel<3,1><<<dim3(4, 8, 8), dim3(512), 0, stream>>>(
                P, nullptr, v1th + s*512, nullptr, out + HH, nullptr, out,
                1024, 512, 2048, SP, SP);
    }

    // --- v2 expand into out[:, 0:512] (after PV-3 consumed ml) ---
    expand_v2_kernel<<<RR, blk, 0, stream>>>(v2b, out);
}

// Round 22
// 741.708 us; speedup vs baseline: 2.8455x; 1.0410x over previous
//
#include <hip/hip_runtime.h>
#include <hip/hip_bf16.h>

// B=8, N=2048, D=1024, C=1024, H=512 (fp32 in/out)
//  q = LNReLU(sgm@Wq^T+bq); k = LNReLU(velo@Wk^T+bk)
//  S = q k^T; P = softmax(S); v1 = LNReLU(velo@Wv1^T); v2 = LNReLU(sgm@Wv2^T)
//  out = concat(v2, P@v1)
//
// Round 22 (round 21 = 772us, absmax 0.03125): Wv1/Wv2 linears cut to 2-pass
// (MODE=2: A = x_hi only, B = Wh|Wl, NT=32). Their outputs are bf16-quantized
// values anyway -> dropped xl*Wh term (~0.002 abs) is noise. q/k linears and
// QK stay 3-pass (score errors amplify by sqrt(K)*sigma). Rest identical.

#define BB 8
#define NN 2048
#define DD 1024
#define CC_ 1024
#define HH 512
#define RR (BB*NN)   // 16384 rows

typedef unsigned short ush;
typedef short bf16x8 __attribute__((ext_vector_type(8)));
typedef float f32x4  __attribute__((ext_vector_type(4)));

#define MiB (1024L*1024L)

// ---------- helpers ----------
__device__ __forceinline__ ush f2bf_rne(float x) {
    unsigned u = __float_as_uint(x);
    return (ush)((u + 0x7fffu + ((u >> 16) & 1u)) >> 16);
}
__device__ __forceinline__ float bf2f(ush h) {
    return __uint_as_float((unsigned)h << 16);
}
__device__ __forceinline__ float wave_sum(float v) {
    #pragma unroll
    for (int o = 32; o; o >>= 1) v += __shfl_down(v, o);
    return v;
}
__device__ __forceinline__ float wave_max(float v) {
    #pragma unroll
    for (int o = 32; o; o >>= 1) v = fmaxf(v, __shfl_down(v, o));
    return v;
}

// async global->LDS, 16B/lane. LDS dest wave-uniform base + lane*16;
// global src per-lane (pre-swizzled so linear LDS holds swizzled layout).
__device__ __forceinline__ void glds16(const void* g, void* l) {
    __builtin_amdgcn_global_load_lds(
        (const __attribute__((address_space(1))) unsigned*)g,
        (__attribute__((address_space(3))) unsigned*)l, 16, 0, 0);
}

// ---------- 8-phase 256x256 bf16 GEMM for the two N=1024 linears ----------
__global__ __launch_bounds__(512, 2)
void gemm8p_kernel(const ush* __restrict__ Ah, const ush* __restrict__ Al,
                   const ush* __restrict__ Bh, const ush* __restrict__ Bl,
                   float* __restrict__ C, int ldc)
{
    __shared__ ush L[65536];   // 128 KiB
    constexpr int NT = 48;     // K' / 64

    int nwg = gridDim.x * gridDim.y;
    int wg  = blockIdx.x + gridDim.x * blockIdx.y;
    int sz  = (wg & 7) * (nwg >> 3) + (wg >> 3);
    int bx  = sz % gridDim.x, by = sz / gridDim.x;
    const long brow = (long)by << 8, bcol = (long)bx << 8;

    const int t = threadIdx.x, wid = t >> 6, lane = t & 63;
    const int wr = (wid >> 2) << 7;
    const int wc = (wid & 3) << 6;
    const int fr = lane & 15, kg = lane >> 4;

    const int srow = ((wid >> 1) << 4) + (lane >> 2);
    const int scol = ((wid & 1) << 5) + ((((lane & 3) << 3)) ^ ((lane >> 5) << 4));
    const int sdst = wid << 9;

    const int cterm = (fr << 5) + ((kg << 3) ^ ((fr >> 3) << 4));
    const int ha13  = (wr >> 7) << 13;
    const int bbase = 16384 + ((wc >> 7) << 13);
    const int sb0   = (wc & 64) >> 4;

    f32x4 acc[8][4] = {};
    bf16x8 bfrag[4][2];

    auto stage = [&](int X, int half) {   // half: 0=A0 1=A1 2=B0 3=B1
        if (X >= NT) return;
        int pI = X >> 4, kc = (X & 15) << 6;
        const ush* s; long rb;
        if (half < 2) { s = (pI == 1) ? Al : Ah; rb = brow + ((long)(half & 1) << 7); }
        else          { s = (pI == 2) ? Bl : Bh; rb = bcol + ((long)(half & 1) << 7); }
        int lb = ((X & 1) << 15) + ((half >> 1) << 14) + ((half & 1) << 13) + sdst;
        glds16(s + (rb + srow) * 1024 + kc + scol,      &L[lb]);
        glds16(s + (rb + srow + 64) * 1024 + kc + scol, &L[lb + 4096]);
    };

    stage(0, 0); stage(0, 1); stage(0, 2); stage(0, 3);
    stage(1, 2); stage(1, 3);
    asm volatile("s_waitcnt vmcnt(4)");
    __builtin_amdgcn_sched_barrier(0);
    __builtin_amdgcn_s_barrier();

    for (int kt = 0; kt < NT; ++kt) {
        const int ab = (kt & 1) << 15;
        #pragma unroll
        for (int p = 0; p < 4; ++p) {
            bf16x8 afrag[2][2];
            #pragma unroll
            for (int ii = 0; ii < 2; ++ii)
                #pragma unroll
                for (int ks = 0; ks < 2; ++ks)
                    afrag[ii][ks] = *(const bf16x8*)&L[ab + ha13 +
                        ((((2 * p + ii) << 1) | ks) << 9) + cterm];
            if (p == 0) {
                #pragma unroll
                for (int fj = 0; fj < 4; ++fj)
                    #pragma unroll
                    for (int ks = 0; ks < 2; ++ks)
                        bfrag[fj][ks] = *(const bf16x8*)&L[ab + bbase +
                            ((((sb0 + fj) << 1) | ks) << 9) + cterm];
            }
            if      (p == 0) stage(kt + 1, 0);
            else if (p == 1) stage(kt + 1, 1);
            else if (p == 2) stage(kt + 2, 2);
            else             stage(kt + 2, 3);

            __builtin_amdgcn_s_barrier();
            asm volatile("s_waitcnt lgkmcnt(0)");
            __builtin_amdgcn_sched_barrier(0);
            __builtin_amdgcn_s_setprio(1);
            #pragma unroll
            for (int ii = 0; ii < 2; ++ii)
                #pragma unroll
                for (int fj = 0; fj < 4; ++fj)
                    #pragma unroll
                    for (int ks = 0; ks < 2; ++ks)
                        acc[2 * p + ii][fj] = __builtin_amdgcn_mfma_f32_16x16x32_bf16(
                            afrag[ii][ks], bfrag[fj][ks], acc[2 * p + ii][fj], 0, 0, 0);
            __builtin_amdgcn_s_setprio(0);
            if (p == 3) {
                if (kt < NT - 2) asm volatile("s_waitcnt vmcnt(4)");
                else             asm volatile("s_waitcnt vmcnt(0)");
                __builtin_amdgcn_sched_barrier(0);
            }
            __builtin_amdgcn_s_barrier();
        }
    }

    #pragma unroll
    for (int fi = 0; fi < 8; ++fi)
        #pragma unroll
        for (int q = 0; q < 4; ++q) {
            long grow = brow + wr + fi * 16 + (kg << 2) + q;
            float* cr = C + grow * (long)ldc + bcol + wc + fr;
            #pragma unroll
            for (int fj = 0; fj < 4; ++fj) cr[fj << 4] = acc[fi][fj][q];
        }
}

// ---------- 8p-structure 256x128 batched GEMM ----------
// MODE=0: 3-pass K'=3K hi/lo (NT=48). MODE=1: single bf16, NT=8 (PV).
// MODE=2: 2-pass A=x_hi only, B = Bh|Bl (NT=32, v-branch linears).
// EPI=0: store C fp32 at ldc. EPI=1: P=exp(s-m) bf16 + atomicAdd l.
// EPI=2: C += acc. EPI=3: C = (C+acc)/l.
template<int EPI, int MODE>
__global__ __launch_bounds__(512, 2)
void gemm8q_kernel(const ush* __restrict__ Ah, const ush* __restrict__ Al,
                   const ush* __restrict__ Bh, const ush* __restrict__ Bl,
                   float* __restrict__ C, ush* __restrict__ Pout,
                   float* __restrict__ ml, int ldc, int lda, int ldb,
                   long sAz, long sBz)
{
    __shared__ ush L[49152];   // 96 KiB
    constexpr int NT = (MODE == 1) ? 8 : (MODE == 2) ? 32 : 48;

    long nwg = (long)gridDim.x * gridDim.y * gridDim.z;
    long wg  = (long)blockIdx.x + gridDim.x * ((long)blockIdx.y + (long)gridDim.y * blockIdx.z);
    long sz  = (wg & 7) * (nwg >> 3) + (wg >> 3);
    const int bx = (int)(sz % gridDim.x);
    long rem = sz / gridDim.x;
    const int by = (int)(rem % gridDim.y);
    const long bz = rem / gridDim.y;

    const long brow = (long)by << 8;
    const long bcol = (long)bx << 7;

    const int t = threadIdx.x, wid = t >> 6, lane = t & 63;
    const int wr4 = wid >> 1;
    const int wc2 = wid & 1;
    const int fr = lane & 15, kg = lane >> 4;

    const int srow = ((wid >> 1) << 4) + (lane >> 2);
    const int scol = ((wid & 1) << 5) + (((lane & 3) << 3) ^ ((lane >> 5) << 4));
    const int sdst = wid << 9;

    const int cterm = (fr << 5) + ((kg << 3) ^ ((fr >> 3) << 4));

    const ush* qh = Ah + bz * sAz;
    const ush* ql = (MODE == 0) ? Al + bz * sAz : nullptr;
    const ush* kh = Bh + bz * sBz;
    const ush* kl = (MODE != 1) ? Bl + bz * sBz : nullptr;

    f32x4 acc[4][4] = {};
    bf16x8 bfrag[4][2];

    auto stageA = [&](int X, int c) {
        if (X >= NT) return;
        int kc = (X & 15) << 6;
        const ush* s = (MODE == 0 && (X >> 4) == 1) ? ql : qh;
        glds16(s + (brow + c * 64 + srow) * (long)lda + kc + scol,
               &L[((X & 1) ? 24576 : 0) + ((c * 8) << 9) + sdst]);
    };
    auto stageB = [&](int X, int c) {
        if (X >= NT) return;
        int kc = (X & 15) << 6;
        const ush* s = ((MODE == 0 && (X >> 4) == 2) ||
                        (MODE == 2 && (X >> 4) == 1)) ? kl : kh;
        glds16(s + (bcol + c * 64 + srow) * (long)ldb + kc + scol,
               &L[((X & 1) ? 24576 : 0) + 16384 + ((c * 8) << 9) + sdst]);
    };

    stageA(0, 0); stageA(0, 1); stageA(0, 2); stageA(0, 3);
    stageB(0, 0); stageB(0, 1);
    stageB(1, 0); stageB(1, 1);
    asm volatile("s_waitcnt vmcnt(2)");
    __builtin_amdgcn_sched_barrier(0);
    __builtin_amdgcn_s_barrier();

    for (int kt = 0; kt < NT; ++kt) {
        const int ab = (kt & 1) ? 24576 : 0;
        #pragma unroll
        for (int p = 0; p < 2; ++p) {
            bf16x8 afrag[2][2];
            #pragma unroll
            for (int ii = 0; ii < 2; ++ii)
                #pragma unroll
                for (int ks = 0; ks < 2; ++ks) {
                    int fi = 2 * p + ii;
                    int sA = (wr4 * 4 + fi) * 2 + ks;
                    afrag[ii][ks] = *(const bf16x8*)&L[ab + (sA << 9) + cterm];
                }
            if (p == 0) {
                #pragma unroll
                for (int fj = 0; fj < 4; ++fj)
                    #pragma unroll
                    for (int ks = 0; ks < 2; ++ks) {
                        int sB = (wc2 * 4 + fj) * 2 + ks;
                        bfrag[fj][ks] = *(const bf16x8*)&L[ab + 16384 + (sB << 9) + cterm];
                    }
                stageA(kt + 1, 0); stageA(kt + 1, 1); stageA(kt + 1, 2);
            } else {
                stageA(kt + 1, 3); stageB(kt + 2, 0); stageB(kt + 2, 1);
            }

            __builtin_amdgcn_s_barrier();
            asm volatile("s_waitcnt lgkmcnt(0)");
            __builtin_amdgcn_sched_barrier(0);
            __builtin_amdgcn_s_setprio(1);
            #pragma unroll
            for (int ii = 0; ii < 2; ++ii)
                #pragma unroll
                for (int fj = 0; fj < 4; ++fj)
                    #pragma unroll
                    for (int ks = 0; ks < 2; ++ks)
                        acc[2 * p + ii][fj] = __builtin_amdgcn_mfma_f32_16x16x32_bf16(
                            afrag[ii][ks], bfrag[fj][ks], acc[2 * p + ii][fj], 0, 0, 0);
            __builtin_amdgcn_s_setprio(0);
            if (p == 1) {
                if (kt < NT - 2) asm volatile("s_waitcnt vmcnt(2)");
                else             asm volatile("s_waitcnt vmcnt(0)");
                __builtin_amdgcn_sched_barrier(0);
            }
            __builtin_amdgcn_s_barrier();
        }
    }

    // C/D layout (m89): col = lane&15, row = (lane>>4)*4 + reg
    if constexpr (EPI == 1) {
        ush*   Pb  = Pout + bz * 2048L * 512;
        float* mlb = ml + bz * 2048L * 1024;
        #pragma unroll
        for (int fi = 0; fi < 4; ++fi) {
            #pragma unroll
            for (int q = 0; q < 4; ++q) {
                long grow = brow + wr4 * 64 + fi * 16 + (kg << 2) + q;
                float m = mlb[grow * 1024];
                float rs = 0.f;
                #pragma unroll
                for (int fj = 0; fj < 4; ++fj) {
                    float pv = __expf(acc[fi][fj][q] - m);
                    rs += pv;
                    Pb[grow * 512 + bcol + wc2 * 64 + fj * 16 + fr] = f2bf_rne(pv);
                }
                rs += __shfl_xor(rs, 1); rs += __shfl_xor(rs, 2);
                rs += __shfl_xor(rs, 4); rs += __shfl_xor(rs, 8);
                if (fr == 0) atomicAdd(&mlb[grow * 1024 + 1], rs);
            }
        }
    } else {
        float* Cb = C + bz * 2048L * 1024;
        #pragma unroll
        for (int fi = 0; fi < 4; ++fi)
            #pragma unroll
            for (int q = 0; q < 4; ++q) {
                long grow = brow + wr4 * 64 + fi * 16 + (kg << 2) + q;
                float scale = 1.0f;
                if constexpr (EPI == 3)
                    scale = 1.0f / (ml + bz * 2048L * 1024)[grow * 1024 + 1];
                float* cr = Cb + grow * (long)ldc + bcol + wc2 * 64 + fr;
                #pragma unroll
                for (int fj = 0; fj < 4; ++fj) {
                    if constexpr (EPI == 2)      cr[fj << 4] = cr[fj << 4] + acc[fi][fj][q];
                    else if constexpr (EPI == 3) cr[fj << 4] = (cr[fj << 4] + acc[fi][fj][q]) * scale;
                    else                         cr[fj << 4] = acc[fi][fj][q];
                }
            }
    }
}

// ---------- bias + LayerNorm + ReLU; OUT: 0=fp32, 1=hi/lo bf16, 2=bf16 ----------
template<int NC, int OUT>
__global__ void ln_relu_kernel(const float* __restrict__ Y, int ldy,
                               const float* __restrict__ bias,
                               const float* __restrict__ g, const float* __restrict__ beta,
                               float* __restrict__ outf, ush* __restrict__ oh,
                               ush* __restrict__ ol, int ldo)
{
    constexpr int PER = NC / 256;
    long row = blockIdx.x;
    const float* yr = Y + row * (long)ldy;
    int t = threadIdx.x;
    float v[PER]; float s = 0.f, s2 = 0.f;
    #pragma unroll
    for (int i = 0; i < PER; ++i) {
        int c = t + (i << 8);
        float x = yr[c] + bias[c];
        v[i] = x; s += x; s2 += x * x;
    }
    s = wave_sum(s); s2 = wave_sum(s2);
    __shared__ float ra[4], rb[4];
    int w = t >> 6, l = t & 63;
    if (!l) { ra[w] = s; rb[w] = s2; }
    __syncthreads();
    s  = ra[0] + ra[1] + ra[2] + ra[3];
    s2 = rb[0] + rb[1] + rb[2] + rb[3];
    float mu  = s * (1.0f / NC);
    float var = s2 * (1.0f / NC) - mu * mu;
    float inv = rsqrtf(var + 1e-5f);
    #pragma unroll
    for (int i = 0; i < PER; ++i) {
        int c = t + (i << 8);
        float x = (v[i] - mu) * inv * g[c] + beta[c];
        x = fmaxf(x, 0.0f);
        if constexpr (OUT == 1) {
            ush h = f2bf_rne(x);
            ush lo = f2bf_rne(x - __uint_as_float((unsigned)h << 16));
            oh[row * (long)ldo + c] = h;
            ol[row * (long)ldo + c] = lo;
        } else if constexpr (OUT == 2) {
            oh[row * (long)ldo + c] = f2bf_rne(x);
        } else {
            outf[row * (long)ldo + c] = x;
        }
    }
}

// ---------- fp32 -> hi/lo bf16 split (flat) ----------
__global__ void split_kernel(const float* __restrict__ in, ush* __restrict__ h,
                             ush* __restrict__ l, long n)
{
    long i = ((long)blockIdx.x * 256 + threadIdx.x) * 4;
    if (i >= n) return;
    float4 v = *(const float4*)(in + i);
    ushort4 hh, ll;
    hh.x = f2bf_rne(v.x); ll.x = f2bf_rne(v.x - __uint_as_float((unsigned)hh.x << 16));
    hh.y = f2bf_rne(v.y); ll.y = f2bf_rne(v.y - __uint_as_float((unsigned)hh.y << 16));
    hh.z = f2bf_rne(v.z); ll.z = f2bf_rne(v.z - __uint_as_float((unsigned)hh.z << 16));
    hh.w = f2bf_rne(v.w); ll.w = f2bf_rne(v.w - __uint_as_float((unsigned)hh.w << 16));
    *(ushort4*)(h + i) = hh;
    *(ushort4*)(l + i) = ll;
}

// ---------- per-batch transpose [2048,512] -> [512,2048], single bf16 ----------
__global__ void transpose_split_kernel(const float* __restrict__ in,
                                       ush* __restrict__ oh)
{
    __shared__ float tile[32][33];
    long bz = blockIdx.z;
    const float* I = in + bz * (long)NN * HH;
    ush* OH = oh + bz * (long)HH * NN;
    int c0 = blockIdx.x << 5, r0 = blockIdx.y << 5;
    int tx = threadIdx.x & 31, ty = threadIdx.x >> 5;   // 32 x 8
    #pragma unroll
    for (int i = 0; i < 32; i += 8)
        tile[ty + i][tx] = I[(long)(r0 + ty + i) * HH + c0 + tx];
    __syncthreads();
    #pragma unroll
    for (int i = 0; i < 32; i += 8) {
        float x = tile[tx][ty + i];
        long o = (long)(c0 + ty + i) * NN + r0 + tx;
        OH[o] = f2bf_rne(x);
    }
}

// ---------- exp pass over slab-0 scores (S at out[:,0:512], ml at cols 0,1) ----------
__global__ void exp_pass_kernel(float* __restrict__ ml, ush* __restrict__ P)
{
    long row = blockIdx.x;               // 0..16383
    float* sr = ml + row * 1024;
    int t = threadIdx.x;
    float s0 = sr[t], s1 = sr[t + 256];
    float m = fmaxf(s0, s1);
    m = wave_max(m);
    __shared__ float ra[4], rb[4];
    int w = t >> 6, l = t & 63;
    if (!l) ra[w] = m;
    __syncthreads();
    m = fmaxf(fmaxf(ra[0], ra[1]), fmaxf(ra[2], ra[3]));
    float p0 = __expf(s0 - m), p1 = __expf(s1 - m);
    ush h0 = f2bf_rne(p0), h1 = f2bf_rne(p1);
    P[row * 512 + t] = h0;
    P[row * 512 + t + 256] = h1;
    float ls = bf2f(h0) + bf2f(h1);
    ls = wave_sum(ls);
    if (!l) rb[w] = ls;
    __syncthreads();
    if (t == 0) {
        sr[0] = m;
        sr[1] = rb[0] + rb[1] + rb[2] + rb[3];
    }
}

// ---------- expand parked v2 bf16 -> out[:, 0:512] fp32 ----------
__global__ void expand_v2_kernel(const ush* __restrict__ v2b, float* __restrict__ o)
{
    long row = blockIdx.x;
    const ush* s = v2b + row * 512;
    float* d = o + row * 1024;
    int t = threadIdx.x;
    d[t] = bf2f(s[t]);
    d[t + 256] = bf2f(s[t + 256]);
}

// ---------- launch ----------
extern "C" void kernel_launch(void* const* d_in, const int* in_sizes, int n_in,
                              void* d_out, int out_size, void* d_ws, size_t ws_size,
                              hipStream_t stream)
{
    const float* sgm   = (const float*)d_in[0];
    const float* velo  = (const float*)d_in[1];
    const float* Wq    = (const float*)d_in[2];
    const float* bq    = (const float*)d_in[3];
    const float* gq    = (const float*)d_in[4];
    const float* betaq = (const float*)d_in[5];
    const float* Wk    = (const float*)d_in[6];
    const float* bk    = (const float*)d_in[7];
    const float* gk    = (const float*)d_in[8];
    const float* betak = (const float*)d_in[9];
    const float* Wv1   = (const float*)d_in[10];
    const float* bv1   = (const float*)d_in[11];
    const float* gv1   = (const float*)d_in[12];
    const float* betav1= (const float*)d_in[13];
    const float* Wv2   = (const float*)d_in[14];
    const float* bv2   = (const float*)d_in[15];
    const float* gv2   = (const float*)d_in[16];
    const float* betav2= (const float*)d_in[17];
    float* out = (float*)d_out;
    char*  wsb = (char*)d_ws;

    if (ws_size < 176 * MiB) return;   // proven >= 176 MiB in round 3

    // ws layout: x/q 64 | k 64 | v1t 16 | v2b 16 | {W splits 12 -> P 16}
    ush* xh   = (ush*)wsb;
    ush* xl   = (ush*)(wsb + 32 * MiB);
    ush* kh   = (ush*)(wsb + 64 * MiB);
    ush* kl   = (ush*)(wsb + 96 * MiB);
    ush* v1th = (ush*)(wsb + 128 * MiB);
    ush* v2b  = (ush*)(wsb + 144 * MiB);
    ush* Wqh  = (ush*)(wsb + 160 * MiB);
    ush* Wql  = (ush*)(wsb + 162 * MiB);
    ush* Wkh  = (ush*)(wsb + 164 * MiB);
    ush* Wkl  = (ush*)(wsb + 166 * MiB);
    ush* Wv1h = (ush*)(wsb + 168 * MiB);
    ush* Wv1l = (ush*)(wsb + 169 * MiB);
    ush* Wv2h = (ush*)(wsb + 170 * MiB);
    ush* Wv2l = (ush*)(wsb + 171 * MiB);
    ush* P    = (ush*)(wsb + 160 * MiB);
    float* v1f = out + 8388608L;       // out bytes [32..64) MiB

    dim3 blk(256);
    const long SQ = 2048L * 1024;      // q/k batch stride
    const long SP = 2048L * 512;       // P / v1t batch stride

    split_kernel<<<1024, blk, 0, stream>>>(Wq,  Wqh,  Wql,  (long)CC_*DD);
    split_kernel<<<1024, blk, 0, stream>>>(Wk,  Wkh,  Wkl,  (long)CC_*DD);
    split_kernel<<<512,  blk, 0, stream>>>(Wv1, Wv1h, Wv1l, (long)HH*DD);
    split_kernel<<<512,  blk, 0, stream>>>(Wv2, Wv2h, Wv2l, (long)HH*DD);

    // --- velo-derived: k, v1 ---
    split_kernel<<<16384, blk, 0, stream>>>(velo, xh, xl, (long)RR*DD);
    gemm8p_kernel<<<dim3(4, 64), dim3(512), 0, stream>>>(xh, xl, Wkh, Wkl, out, CC_);
    ln_relu_kernel<1024,1><<<RR, blk, 0, stream>>>(out, CC_, bk, gk, betak, nullptr, kh, kl, CC_);
    gemm8q_kernel<0,2><<<dim3(4, 64, 1), dim3(512), 0, stream>>>(
        xh, nullptr, Wv1h, Wv1l, out, nullptr, nullptr, HH, 1024, 1024, SQ, SQ);
    ln_relu_kernel<512,0><<<RR, blk, 0, stream>>>(out, HH, bv1, gv1, betav1, v1f, nullptr, nullptr, HH);
    transpose_split_kernel<<<dim3(16,64,BB), blk, 0, stream>>>(v1f, v1th);

    // --- sgm-derived: v2 (parked bf16), then q ---
    split_kernel<<<16384, blk, 0, stream>>>(sgm, xh, xl, (long)RR*DD);
    gemm8q_kernel<0,2><<<dim3(4, 64, 1), dim3(512), 0, stream>>>(
        xh, nullptr, Wv2h, Wv2l, out, nullptr, nullptr, HH, 1024, 1024, SQ, SQ);
    ln_relu_kernel<512,2><<<RR, blk, 0, stream>>>(out, HH, bv2, gv2, betav2, nullptr, v2b, nullptr, HH);
    gemm8p_kernel<<<dim3(4, 64), dim3(512), 0, stream>>>(xh, xl, Wqh, Wql, out, CC_);
    ln_relu_kernel<1024,1><<<RR, blk, 0, stream>>>(out, CC_, bq, gq, betaq, nullptr, xh, xl, CC_);

    // --- attention (4 key-slabs of 512); S-slab0 + ml in out[:, 0:512] ---
    gemm8q_kernel<0,0><<<dim3(4, 8, 8), dim3(512), 0, stream>>>(
        xh, xl, kh, kl, out, nullptr, nullptr, 1024, 1024, 1024, SQ, SQ);
    exp_pass_kernel<<<RR, blk, 0, stream>>>(out, P);
    gemm8q_kernel<0,1><<<dim3(4, 8, 8), dim3(512), 0, stream>>>(
        P, nullptr, v1th, nullptr, out + HH, nullptr, nullptr,
        1024, 512, 2048, SP, SP);
    for (int s = 1; s < 4; ++s) {
        gemm8q_kernel<1,0><<<dim3(4, 8, 8), dim3(512), 0, stream>>>(
            xh, xl, kh + (long)s*512*1024, kl + (long)s*512*1024,
            nullptr, P, out, 0, 1024, 1024, SQ, SQ);
        if (s < 3)
            gemm8q_kernel<2,1><<<dim3(4, 8, 8), dim3(512), 0, stream>>>(
                P, nullptr, v1th + s*512, nullptr, out + HH, nullptr, nullptr,
                1024, 512, 2048, SP, SP);
        else
            gemm8q_kernel<3,1><<<dim3(4, 8, 8), dim3(512), 0, stream>>>(
                P, nullptr, v1th + s*512, nullptr, out + HH, nullptr, out,
                1024, 512, 2048, SP, SP);
    }

    // --- v2 expand into out[:, 0:512] (after PV-3 consumed ml) ---
    expand_v2_kernel<<<RR, blk, 0, stream>>>(v2b, out);
}

// Round 23
// 711.806 us; speedup vs baseline: 2.9650x; 1.0420x over previous
//
#include <hip/hip_runtime.h>
#include <hip/hip_bf16.h>

// B=8, N=2048, D=1024, C=1024, H=512 (fp32 in/out)
//  q = LNReLU(sgm@Wq^T+bq); k = LNReLU(velo@Wk^T+bk)
//  S = q k^T; P = softmax(S); v1 = LNReLU(velo@Wv1^T); v2 = LNReLU(sgm@Wv2^T)
//  out = concat(v2, P@v1)
//
// Round 23 (round 22 = 742us, absmax 0.03125 = v2-bf16 ulp floor): q/k
// linears also cut to 2-pass MODE=2 (A=x_hi, B=[Wh|Wl], NT=32); gemm8p
// retired. Score-error budget: eps_q~0.0011 -> score eps ~0.035 rms ->
// out eps ~0.01 rms / 0.04 tails; predicted absmax 0.05-0.08 < 0.109.
// QK itself stays 3-pass. Everything else identical to round 22.

#define BB 8
#define NN 2048
#define DD 1024
#define CC_ 1024
#define HH 512
#define RR (BB*NN)   // 16384 rows

typedef unsigned short ush;
typedef short bf16x8 __attribute__((ext_vector_type(8)));
typedef float f32x4  __attribute__((ext_vector_type(4)));

#define MiB (1024L*1024L)

// ---------- helpers ----------
__device__ __forceinline__ ush f2bf_rne(float x) {
    unsigned u = __float_as_uint(x);
    return (ush)((u + 0x7fffu + ((u >> 16) & 1u)) >> 16);
}
__device__ __forceinline__ float bf2f(ush h) {
    return __uint_as_float((unsigned)h << 16);
}
__device__ __forceinline__ float wave_sum(float v) {
    #pragma unroll
    for (int o = 32; o; o >>= 1) v += __shfl_down(v, o);
    return v;
}
__device__ __forceinline__ float wave_max(float v) {
    #pragma unroll
    for (int o = 32; o; o >>= 1) v = fmaxf(v, __shfl_down(v, o));
    return v;
}

// async global->LDS, 16B/lane. LDS dest wave-uniform base + lane*16;
// global src per-lane (pre-swizzled so linear LDS holds swizzled layout).
__device__ __forceinline__ void glds16(const void* g, void* l) {
    __builtin_amdgcn_global_load_lds(
        (const __attribute__((address_space(1))) unsigned*)g,
        (__attribute__((address_space(3))) unsigned*)l, 16, 0, 0);
}

// ---------- 8p-structure 256x128 batched GEMM ----------
// MODE=0: 3-pass K'=3K hi/lo (NT=48). MODE=1: single bf16, NT=8 (PV).
// MODE=2: 2-pass A=x_hi only, B = Bh|Bl (NT=32, all four linears).
// EPI=0: store C fp32 at ldc. EPI=1: P=exp(s-m) bf16 + atomicAdd l.
// EPI=2: C += acc. EPI=3: C = (C+acc)/l.
template<int EPI, int MODE>
__global__ __launch_bounds__(512, 2)
void gemm8q_kernel(const ush* __restrict__ Ah, const ush* __restrict__ Al,
                   const ush* __restrict__ Bh, const ush* __restrict__ Bl,
                   float* __restrict__ C, ush* __restrict__ Pout,
                   float* __restrict__ ml, int ldc, int lda, int ldb,
                   long sAz, long sBz)
{
    __shared__ ush L[49152];   // 96 KiB
    constexpr int NT = (MODE == 1) ? 8 : (MODE == 2) ? 32 : 48;

    long nwg = (long)gridDim.x * gridDim.y * gridDim.z;
    long wg  = (long)blockIdx.x + gridDim.x * ((long)blockIdx.y + (long)gridDim.y * blockIdx.z);
    long sz  = (wg & 7) * (nwg >> 3) + (wg >> 3);
    const int bx = (int)(sz % gridDim.x);
    long rem = sz / gridDim.x;
    const int by = (int)(rem % gridDim.y);
    const long bz = rem / gridDim.y;

    const long brow = (long)by << 8;
    const long bcol = (long)bx << 7;

    const int t = threadIdx.x, wid = t >> 6, lane = t & 63;
    const int wr4 = wid >> 1;
    const int wc2 = wid & 1;
    const int fr = lane & 15, kg = lane >> 4;

    const int srow = ((wid >> 1) << 4) + (lane >> 2);
    const int scol = ((wid & 1) << 5) + (((lane & 3) << 3) ^ ((lane >> 5) << 4));
    const int sdst = wid << 9;

    const int cterm = (fr << 5) + ((kg << 3) ^ ((fr >> 3) << 4));

    const ush* qh = Ah + bz * sAz;
    const ush* ql = (MODE == 0) ? Al + bz * sAz : nullptr;
    const ush* kh = Bh + bz * sBz;
    const ush* kl = (MODE != 1) ? Bl + bz * sBz : nullptr;

    f32x4 acc[4][4] = {};
    bf16x8 bfrag[4][2];

    auto stageA = [&](int X, int c) {
        if (X >= NT) return;
        int kc = (X & 15) << 6;
        const ush* s = (MODE == 0 && (X >> 4) == 1) ? ql : qh;
        glds16(s + (brow + c * 64 + srow) * (long)lda + kc + scol,
               &L[((X & 1) ? 24576 : 0) + ((c * 8) << 9) + sdst]);
    };
    auto stageB = [&](int X, int c) {
        if (X >= NT) return;
        int kc = (X & 15) << 6;
        const ush* s = ((MODE == 0 && (X >> 4) == 2) ||
                        (MODE == 2 && (X >> 4) == 1)) ? kl : kh;
        glds16(s + (bcol + c * 64 + srow) * (long)ldb + kc + scol,
               &L[((X & 1) ? 24576 : 0) + 16384 + ((c * 8) << 9) + sdst]);
    };

    stageA(0, 0); stageA(0, 1); stageA(0, 2); stageA(0, 3);
    stageB(0, 0); stageB(0, 1);
    stageB(1, 0); stageB(1, 1);
    asm volatile("s_waitcnt vmcnt(2)");
    __builtin_amdgcn_sched_barrier(0);
    __builtin_amdgcn_s_barrier();

    for (int kt = 0; kt < NT; ++kt) {
        const int ab = (kt & 1) ? 24576 : 0;
        #pragma unroll
        for (int p = 0; p < 2; ++p) {
            bf16x8 afrag[2][2];
            #pragma unroll
            for (int ii = 0; ii < 2; ++ii)
                #pragma unroll
                for (int ks = 0; ks < 2; ++ks) {
                    int fi = 2 * p + ii;
                    int sA = (wr4 * 4 + fi) * 2 + ks;
                    afrag[ii][ks] = *(const bf16x8*)&L[ab + (sA << 9) + cterm];
                }
            if (p == 0) {
                #pragma unroll
                for (int fj = 0; fj < 4; ++fj)
                    #pragma unroll
                    for (int ks = 0; ks < 2; ++ks) {
                        int sB = (wc2 * 4 + fj) * 2 + ks;
                        bfrag[fj][ks] = *(const bf16x8*)&L[ab + 16384 + (sB << 9) + cterm];
                    }
                stageA(kt + 1, 0); stageA(kt + 1, 1); stageA(kt + 1, 2);
            } else {
                stageA(kt + 1, 3); stageB(kt + 2, 0); stageB(kt + 2, 1);
            }

            __builtin_amdgcn_s_barrier();
            asm volatile("s_waitcnt lgkmcnt(0)");
            __builtin_amdgcn_sched_barrier(0);
            __builtin_amdgcn_s_setprio(1);
            #pragma unroll
            for (int ii = 0; ii < 2; ++ii)
                #pragma unroll
                for (int fj = 0; fj < 4; ++fj)
                    #pragma unroll
                    for (int ks = 0; ks < 2; ++ks)
                        acc[2 * p + ii][fj] = __builtin_amdgcn_mfma_f32_16x16x32_bf16(
                            afrag[ii][ks], bfrag[fj][ks], acc[2 * p + ii][fj], 0, 0, 0);
            __builtin_amdgcn_s_setprio(0);
            if (p == 1) {
                if (kt < NT - 2) asm volatile("s_waitcnt vmcnt(2)");
                else             asm volatile("s_waitcnt vmcnt(0)");
                __builtin_amdgcn_sched_barrier(0);
            }
            __builtin_amdgcn_s_barrier();
        }
    }

    // C/D layout (m89): col = lane&15, row = (lane>>4)*4 + reg
    if constexpr (EPI == 1) {
        ush*   Pb  = Pout + bz * 2048L * 512;
        float* mlb = ml + bz * 2048L * 1024;
        #pragma unroll
        for (int fi = 0; fi < 4; ++fi) {
            #pragma unroll
            for (int q = 0; q < 4; ++q) {
                long grow = brow + wr4 * 64 + fi * 16 + (kg << 2) + q;
                float m = mlb[grow * 1024];
                float rs = 0.f;
                #pragma unroll
                for (int fj = 0; fj < 4; ++fj) {
                    float pv = __expf(acc[fi][fj][q] - m);
                    rs += pv;
                    Pb[grow * 512 + bcol + wc2 * 64 + fj * 16 + fr] = f2bf_rne(pv);
                }
                rs += __shfl_xor(rs, 1); rs += __shfl_xor(rs, 2);
                rs += __shfl_xor(rs, 4); rs += __shfl_xor(rs, 8);
                if (fr == 0) atomicAdd(&mlb[grow * 1024 + 1], rs);
            }
        }
    } else {
        float* Cb = C + bz * 2048L * 1024;
        #pragma unroll
        for (int fi = 0; fi < 4; ++fi)
            #pragma unroll
            for (int q = 0; q < 4; ++q) {
                long grow = brow + wr4 * 64 + fi * 16 + (kg << 2) + q;
                float scale = 1.0f;
                if constexpr (EPI == 3)
                    scale = 1.0f / (ml + bz * 2048L * 1024)[grow * 1024 + 1];
                float* cr = Cb + grow * (long)ldc + bcol + wc2 * 64 + fr;
                #pragma unroll
                for (int fj = 0; fj < 4; ++fj) {
                    if constexpr (EPI == 2)      cr[fj << 4] = cr[fj << 4] + acc[fi][fj][q];
                    else if constexpr (EPI == 3) cr[fj << 4] = (cr[fj << 4] + acc[fi][fj][q]) * scale;
                    else                         cr[fj << 4] = acc[fi][fj][q];
                }
            }
    }
}

// ---------- bias + LayerNorm + ReLU; OUT: 0=fp32, 1=hi/lo bf16, 2=bf16 ----------
template<int NC, int OUT>
__global__ void ln_relu_kernel(const float* __restrict__ Y, int ldy,
                               const float* __restrict__ bias,
                               const float* __restrict__ g, const float* __restrict__ beta,
                               float* __restrict__ outf, ush* __restrict__ oh,
                               ush* __restrict__ ol, int ldo)
{
    constexpr int PER = NC / 256;
    long row = blockIdx.x;
    const float* yr = Y + row * (long)ldy;
    int t = threadIdx.x;
    float v[PER]; float s = 0.f, s2 = 0.f;
    #pragma unroll
    for (int i = 0; i < PER; ++i) {
        int c = t + (i << 8);
        float x = yr[c] + bias[c];
        v[i] = x; s += x; s2 += x * x;
    }
    s = wave_sum(s); s2 = wave_sum(s2);
    __shared__ float ra[4], rb[4];
    int w = t >> 6, l = t & 63;
    if (!l) { ra[w] = s; rb[w] = s2; }
    __syncthreads();
    s  = ra[0] + ra[1] + ra[2] + ra[3];
    s2 = rb[0] + rb[1] + rb[2] + rb[3];
    float mu  = s * (1.0f / NC);
    float var = s2 * (1.0f / NC) - mu * mu;
    float inv = rsqrtf(var + 1e-5f);
    #pragma unroll
    for (int i = 0; i < PER; ++i) {
        int c = t + (i << 8);
        float x = (v[i] - mu) * inv * g[c] + beta[c];
        x = fmaxf(x, 0.0f);
        if constexpr (OUT == 1) {
            ush h = f2bf_rne(x);
            ush lo = f2bf_rne(x - __uint_as_float((unsigned)h << 16));
            oh[row * (long)ldo + c] = h;
            ol[row * (long)ldo + c] = lo;
        } else if constexpr (OUT == 2) {
            oh[row * (long)ldo + c] = f2bf_rne(x);
        } else {
            outf[row * (long)ldo + c] = x;
        }
    }
}

// ---------- fp32 -> hi/lo bf16 split (flat) ----------
__global__ void split_kernel(const float* __restrict__ in, ush* __restrict__ h,
                             ush* __restrict__ l, long n)
{
    long i = ((long)blockIdx.x * 256 + threadIdx.x) * 4;
    if (i >= n) return;
    float4 v = *(const float4*)(in + i);
    ushort4 hh, ll;
    hh.x = f2bf_rne(v.x); ll.x = f2bf_rne(v.x - __uint_as_float((unsigned)hh.x << 16));
    hh.y = f2bf_rne(v.y); ll.y = f2bf_rne(v.y - __uint_as_float((unsigned)hh.y << 16));
    hh.z = f2bf_rne(v.z); ll.z = f2bf_rne(v.z - __uint_as_float((unsigned)hh.z << 16));
    hh.w = f2bf_rne(v.w); ll.w = f2bf_rne(v.w - __uint_as_float((unsigned)hh.w << 16));
    *(ushort4*)(h + i) = hh;
    *(ushort4*)(l + i) = ll;
}

// ---------- per-batch transpose [2048,512] -> [512,2048], single bf16 ----------
__global__ void transpose_split_kernel(const float* __restrict__ in,
                                       ush* __restrict__ oh)
{
    __shared__ float tile[32][33];
    long bz = blockIdx.z;
    const float* I = in + bz * (long)NN * HH;
    ush* OH = oh + bz * (long)HH * NN;
    int c0 = blockIdx.x << 5, r0 = blockIdx.y << 5;
    int tx = threadIdx.x & 31, ty = threadIdx.x >> 5;   // 32 x 8
    #pragma unroll
    for (int i = 0; i < 32; i += 8)
        tile[ty + i][tx] = I[(long)(r0 + ty + i) * HH + c0 + tx];
    __syncthreads();
    #pragma unroll
    for (int i = 0; i < 32; i += 8) {
        float x = tile[tx][ty + i];
        long o = (long)(c0 + ty + i) * NN + r0 + tx;
        OH[o] = f2bf_rne(x);
    }
}

// ---------- exp pass over slab-0 scores (S at out[:,0:512], ml at cols 0,1) ----------
__global__ void exp_pass_kernel(float* __restrict__ ml, ush* __restrict__ P)
{
    long row = blockIdx.x;               // 0..16383
    float* sr = ml + row * 1024;
    int t = threadIdx.x;
    float s0 = sr[t], s1 = sr[t + 256];
    float m = fmaxf(s0, s1);
    m = wave_max(m);
    __shared__ float ra[4], rb[4];
    int w = t >> 6, l = t & 63;
    if (!l) ra[w] = m;
    __syncthreads();
    m = fmaxf(fmaxf(ra[0], ra[1]), fmaxf(ra[2], ra[3]));
    float p0 = __expf(s0 - m), p1 = __expf(s1 - m);
    ush h0 = f2bf_rne(p0), h1 = f2bf_rne(p1);
    P[row * 512 + t] = h0;
    P[row * 512 + t + 256] = h1;
    float ls = bf2f(h0) + bf2f(h1);
    ls = wave_sum(ls);
    if (!l) rb[w] = ls;
    __syncthreads();
    if (t == 0) {
        sr[0] = m;
        sr[1] = rb[0] + rb[1] + rb[2] + rb[3];
    }
}

// ---------- expand parked v2 bf16 -> out[:, 0:512] fp32 ----------
__global__ void expand_v2_kernel(const ush* __restrict__ v2b, float* __restrict__ o)
{
    long row = blockIdx.x;
    const ush* s = v2b + row * 512;
    float* d = o + row * 1024;
    int t = threadIdx.x;
    d[t] = bf2f(s[t]);
    d[t + 256] = bf2f(s[t + 256]);
}

// ---------- launch ----------
extern "C" void kernel_launch(void* const* d_in, const int* in_sizes, int n_in,
                              void* d_out, int out_size, void* d_ws, size_t ws_size,
                              hipStream_t stream)
{
    const float* sgm   = (const float*)d_in[0];
    const float* velo  = (const float*)d_in[1];
    const float* Wq    = (const float*)d_in[2];
    const float* bq    = (const float*)d_in[3];
    const float* gq    = (const float*)d_in[4];
    const float* betaq = (const float*)d_in[5];
    const float* Wk    = (const float*)d_in[6];
    const float* bk    = (const float*)d_in[7];
    const float* gk    = (const float*)d_in[8];
    const float* betak = (const float*)d_in[9];
    const float* Wv1   = (const float*)d_in[10];
    const float* bv1   = (const float*)d_in[11];
    const float* gv1   = (const float*)d_in[12];
    const float* betav1= (const float*)d_in[13];
    const float* Wv2   = (const float*)d_in[14];
    const float* bv2   = (const float*)d_in[15];
    const float* gv2   = (const float*)d_in[16];
    const float* betav2= (const float*)d_in[17];
    float* out = (float*)d_out;
    char*  wsb = (char*)d_ws;

    if (ws_size < 176 * MiB) return;   // proven >= 176 MiB in round 3

    // ws layout: x/q 64 | k 64 | v1t 16 | v2b 16 | {W splits 12 -> P 16}
    ush* xh   = (ush*)wsb;
    ush* xl   = (ush*)(wsb + 32 * MiB);
    ush* kh   = (ush*)(wsb + 64 * MiB);
    ush* kl   = (ush*)(wsb + 96 * MiB);
    ush* v1th = (ush*)(wsb + 128 * MiB);
    ush* v2b  = (ush*)(wsb + 144 * MiB);
    ush* Wqh  = (ush*)(wsb + 160 * MiB);
    ush* Wql  = (ush*)(wsb + 162 * MiB);
    ush* Wkh  = (ush*)(wsb + 164 * MiB);
    ush* Wkl  = (ush*)(wsb + 166 * MiB);
    ush* Wv1h = (ush*)(wsb + 168 * MiB);
    ush* Wv1l = (ush*)(wsb + 169 * MiB);
    ush* Wv2h = (ush*)(wsb + 170 * MiB);
    ush* Wv2l = (ush*)(wsb + 171 * MiB);
    ush* P    = (ush*)(wsb + 160 * MiB);
    float* v1f = out + 8388608L;       // out bytes [32..64) MiB

    dim3 blk(256);
    const long SQ = 2048L * 1024;      // q/k batch stride
    const long SP = 2048L * 512;       // P / v1t batch stride

    split_kernel<<<1024, blk, 0, stream>>>(Wq,  Wqh,  Wql,  (long)CC_*DD);
    split_kernel<<<1024, blk, 0, stream>>>(Wk,  Wkh,  Wkl,  (long)CC_*DD);
    split_kernel<<<512,  blk, 0, stream>>>(Wv1, Wv1h, Wv1l, (long)HH*DD);
    split_kernel<<<512,  blk, 0, stream>>>(Wv2, Wv2h, Wv2l, (long)HH*DD);

    // --- velo-derived: k, v1 ---
    split_kernel<<<16384, blk, 0, stream>>>(velo, xh, xl, (long)RR*DD);
    gemm8q_kernel<0,2><<<dim3(8, 64, 1), dim3(512), 0, stream>>>(
        xh, nullptr, Wkh, Wkl, out, nullptr, nullptr, CC_, 1024, 1024, SQ, SQ);
    ln_relu_kernel<1024,1><<<RR, blk, 0, stream>>>(out, CC_, bk, gk, betak, nullptr, kh, kl, CC_);
    gemm8q_kernel<0,2><<<dim3(4, 64, 1), dim3(512), 0, stream>>>(
        xh, nullptr, Wv1h, Wv1l, out, nullptr, nullptr, HH, 1024, 1024, SQ, SQ);
    ln_relu_kernel<512,0><<<RR, blk, 0, stream>>>(out, HH, bv1, gv1, betav1, v1f, nullptr, nullptr, HH);
    transpose_split_kernel<<<dim3(16,64,BB), blk, 0, stream>>>(v1f, v1th);

    // --- sgm-derived: v2 (parked bf16), then q ---
    split_kernel<<<16384, blk, 0, stream>>>(sgm, xh, xl, (long)RR*DD);
    gemm8q_kernel<0,2><<<dim3(4, 64, 1), dim3(512), 0, stream>>>(
        xh, nullptr, Wv2h, Wv2l, out, nullptr, nullptr, HH, 1024, 1024, SQ, SQ);
    ln_relu_kernel<512,2><<<RR, blk, 0, stream>>>(out, HH, bv2, gv2, betav2, nullptr, v2b, nullptr, HH);
    gemm8q_kernel<0,2><<<dim3(8, 64, 1), dim3(512), 0, stream>>>(
        xh, nullptr, Wqh, Wql, out, nullptr, nullptr, CC_, 1024, 1024, SQ, SQ);
    ln_relu_kernel<1024,1><<<RR, blk, 0, stream>>>(out, CC_, bq, gq, betaq, nullptr, xh, xl, CC_);

    // --- attention (4 key-slabs of 512); S-slab0 + ml in out[:, 0:512] ---
    gemm8q_kernel<0,0><<<dim3(4, 8, 8), dim3(512), 0, stream>>>(
        xh, xl, kh, kl, out, nullptr, nullptr, 1024, 1024, 1024, SQ, SQ);
    exp_pass_kernel<<<RR, blk, 0, stream>>>(out, P);
    gemm8q_kernel<0,1><<<dim3(4, 8, 8), dim3(512), 0, stream>>>(
        P, nullptr, v1th, nullptr, out + HH, nullptr, nullptr,
        1024, 512, 2048, SP, SP);
    for (int s = 1; s < 4; ++s) {
        gemm8q_kernel<1,0><<<dim3(4, 8, 8), dim3(512), 0, stream>>>(
            xh, xl, kh + (long)s*512*1024, kl + (long)s*512*1024,
            nullptr, P, out, 0, 1024, 1024, SQ, SQ);
        if (s < 3)
            gemm8q_kernel<2,1><<<dim3(4, 8, 8), dim3(512), 0, stream>>>(
                P, nullptr, v1th + s*512, nullptr, out + HH, nullptr, nullptr,
                1024, 512, 2048, SP, SP);
        else
            gemm8q_kernel<3,1><<<dim3(4, 8, 8), dim3(512), 0, stream>>>(
                P, nullptr, v1th + s*512, nullptr, out + HH, nullptr, out,
                1024, 512, 2048, SP, SP);
    }

    // --- v2 expand into out[:, 0:512] (after PV-3 consumed ml) ---
    expand_v2_kernel<<<RR, blk, 0, stream>>>(v2b, out);
}